// Round 13
// baseline (409.810 us; speedup 1.0000x reference)
//
#include <hip/hip_runtime.h>
#include <hip/hip_bf16.h>

#define NN 50000
#define FIN 256
#define F1 256      // HEADS*HID
#define HEADS 4
#define HID 64
#define NC 40
#define NE 1600000
#define SLOPE 0.2f
#define LOG2E 1.44269504f
#define CHUNK 128
#define NB2 98      // coarse dst buckets (512 nodes each)
#define BSH 9
#define BCAP2 18000 // per-bucket capacity (mean 16327, +13 sigma)
#define TILE 2048   // edges per k_bin block

typedef unsigned int u32;
typedef unsigned short u16;
typedef unsigned char u8;
typedef __attribute__((ext_vector_type(8))) short bf16x8;
typedef __attribute__((ext_vector_type(4))) float f32x4;

__device__ __forceinline__ float us2f(u32 u){ u32 b = u << 16; return __uint_as_float(b); }
__device__ __forceinline__ u16 f2bf(float f){
  u32 b = __float_as_uint(f);
  u32 r = (b + 0x7fffu + ((b >> 16) & 1u)) >> 16;
  return (u16)r;
}

// ---- streaming prep: x split (0..6249) + W1 transpose/split (6250..6505) + W2 transpose/split (6506..6553)
__global__ __launch_bounds__(256) void k_prep(const float* __restrict__ x, u16* __restrict__ xh, u16* __restrict__ xl,
      const float* __restrict__ W1, u16* __restrict__ w1h, u16* __restrict__ w1l,
      const float* __restrict__ W2, u16* __restrict__ w2h, u16* __restrict__ w2l){
  int bid = blockIdx.x, tid = threadIdx.x;
  if(bid < 6250){
    int i = (bid*256 + tid) * 8;
    float4 a = *(const float4*)(x+i);
    float4 b4 = *(const float4*)(x+i+4);
    float v[8] = {a.x,a.y,a.z,a.w,b4.x,b4.y,b4.z,b4.w};
    u16 hi[8], lo[8];
    #pragma unroll
    for(int j=0;j<8;j++){
      u32 u = __float_as_uint(v[j]);
      hi[j] = (u16)(u >> 16);                      // truncate hi
      float hf = __uint_as_float(u & 0xffff0000u);
      lo[j] = (u16)(__float_as_uint(v[j] - hf) >> 16);
    }
    *(ushort4*)&xh[i]   = make_ushort4(hi[0],hi[1],hi[2],hi[3]);
    *(ushort4*)&xh[i+4] = make_ushort4(hi[4],hi[5],hi[6],hi[7]);
    *(ushort4*)&xl[i]   = make_ushort4(lo[0],lo[1],lo[2],lo[3]);
    *(ushort4*)&xl[i+4] = make_ushort4(lo[4],lo[5],lo[6],lo[7]);
  } else if(bid < 6506){
    int id = (bid-6250)*256 + tid;               // 65536 total
    int n = id & 255, k = id >> 8;
    float v = W1[k*F1 + n];
    u16 h = f2bf(v);
    w1h[n*FIN + k] = h;
    w1l[n*FIN + k] = f2bf(v - us2f(h));
  } else {
    int id = (bid-6506)*256 + tid;               // 12288 total: col 0..47, k 0..255
    int col = id >> 8, k = id & 255;
    float v = (col < NC) ? W2[k*NC + col] : 0.f;
    u16 h = f2bf(v);
    w2h[col*F1 + k] = h;
    w2l[col*F1 + k] = f2bf(v - us2f(h));
  }
}

// ---- LDS-staged edge binning (int-width detection inlined per tile)
__global__ __launch_bounds__(256) void k_bin(const int* __restrict__ ei,
                                             int* __restrict__ cnt, u32* __restrict__ bin){
  __shared__ int hcnt[NB2], hoff[NB2], gbase[NB2], hcur[NB2];
  __shared__ u32 staged[TILE];
  __shared__ u8  sbk[TILE];
  __shared__ int ci;
  int tid = threadIdx.x;
  int e0 = blockIdx.x * TILE;
  int nn = min(TILE, NE - e0);
  if(tid==0) ci = 0;
  for(int b=tid;b<NB2;b+=256) hcnt[b] = 0;
  __syncthreads();
  if(ei[2*(e0+tid)+1] != 0) atomicAdd(&ci, 1);   // int64: odd words all 0; int32: ~all nonzero
  __syncthreads();
  int i64 = (ci == 0);
  u32 val[TILE/256]; int bk[TILE/256];
  #pragma unroll
  for(int j=0;j<TILE/256;j++){
    int t = tid + j*256;
    if(t < nn){
      int i = e0 + t;
      int src = i64 ? ei[2*i] : ei[i];
      int dst = i64 ? ei[2*(NE+i)] : ei[NE+i];
      bk[j] = dst >> BSH;
      val[j] = (u32)src | ((u32)(dst & 511) << 16);
      atomicAdd(&hcnt[bk[j]], 1);
    } else bk[j] = -1;
  }
  __syncthreads();
  if(tid == 0){
    int run = 0;
    for(int b=0;b<NB2;b++){ hoff[b] = run; hcur[b] = run; run += hcnt[b]; }
  }
  __syncthreads();
  if(tid < NB2 && hcnt[tid] > 0) gbase[tid] = atomicAdd(&cnt[tid], hcnt[tid]);
  __syncthreads();
  #pragma unroll
  for(int j=0;j<TILE/256;j++){
    if(bk[j] >= 0){
      int pos = atomicAdd(&hcur[bk[j]], 1);
      staged[pos] = val[j];
      sbk[pos] = (u8)bk[j];
    }
  }
  __syncthreads();
  for(int s=tid; s<nn; s+=256){
    int b = sbk[s];
    int local = gbase[b] + (s - hoff[b]);
    if(local < BCAP2) bin[(size_t)b*BCAP2 + local] = staged[s];
  }
}

// ---- per-bucket degree histogram + 512-entry LDS exclusive scan
__global__ __launch_bounds__(256) void k_hist(const int* __restrict__ cnt, const u32* __restrict__ bin,
                                              int* __restrict__ rloc, int* __restrict__ bsum){
  __shared__ int dl[512], s1[512], s2[512];
  int b = blockIdx.x, tid = threadIdx.x;
  for(int i=tid;i<512;i+=256) dl[i] = 0;
  __syncthreads();
  int n = min(cnt[b], BCAP2);
  const u32* bp = bin + (size_t)b*BCAP2;
  for(int i=tid;i<n;i+=256) atomicAdd(&dl[(bp[i]>>16)&511], 1);
  __syncthreads();
  for(int i=tid;i<512;i+=256) s1[i] = dl[i];
  __syncthreads();
  int* src = s1; int* dst = s2;
  for(int off=1; off<512; off<<=1){
    for(int i=tid;i<512;i+=256) dst[i] = src[i] + (i>=off ? src[i-off] : 0);
    __syncthreads();
    int* t = src; src = dst; dst = t;
  }
  for(int i=tid;i<512;i+=256) rloc[b*512+i] = src[i] - dl[i];
  if(tid==0) bsum[b] = src[511];
}

// ---- tiny serial scan over 98 bucket totals
__global__ void k_scanb(const int* __restrict__ bsum, int* __restrict__ bbase, int* __restrict__ rowptr){
  if(threadIdx.x==0){
    int run = 0;
    for(int b=0;b<NB2;b++){ bbase[b] = run; run += bsum[b]; }
    rowptr[NN] = run;
  }
}

// ---- per-bucket scatter into contiguous adj window; materializes final rowptr
__global__ __launch_bounds__(256) void k_fill2(const int* __restrict__ cnt, const u32* __restrict__ bin,
                                               const int* __restrict__ rloc, const int* __restrict__ bbase,
                                               int* __restrict__ rowptr, int* __restrict__ adj){
  __shared__ int cur[512];
  int b = blockIdx.x, tid = threadIdx.x;
  int base = bbase[b];
  for(int i=tid;i<512;i+=256){
    int d = b*512 + i;
    int v = base + rloc[b*512+i];
    cur[i] = v;
    if(d < NN) rowptr[d] = v;
  }
  __syncthreads();
  int n = min(cnt[b], BCAP2);
  const u32* bp = bin + (size_t)b*BCAP2;
  for(int i=tid;i<n;i+=256){
    u32 v = bp[i];
    int p = atomicAdd(&cur[(v>>16)&511], 1);
    adj[p] = (int)(v & 0xffffu);
  }
}

// ---- GEMM1 (MFMA bf16x3) + fused attention dots.
__global__ __launch_bounds__(256) void k_gemm1(const short* __restrict__ xh, const short* __restrict__ xl,
                                               const short* __restrict__ wh, const short* __restrict__ wl,
                                               const float* __restrict__ as1, const float* __restrict__ ad1,
                                               u16* __restrict__ h1b,
                                               float* __restrict__ aS, float* __restrict__ aD){
  int w = threadIdx.x >> 6, lane = threadIdx.x & 63;
  int lo = lane & 15, hi = lane >> 4;
  int rowbase = blockIdx.x*64;
  f32x4 acc[4][4];                       // [rg][tt]
  #pragma unroll
  for(int rg=0;rg<4;rg++)
    #pragma unroll
    for(int tt=0;tt<4;tt++) acc[rg][tt] = (f32x4){0.f,0.f,0.f,0.f};
  size_t aoff[4];
  #pragma unroll
  for(int rg=0;rg<4;rg++){
    int r = rowbase + rg*16 + lo; if(r >= NN) r = NN-1;
    aoff[rg] = (size_t)r*FIN + 8*hi;
  }
  const short* wph = wh + (size_t)(w*64+lo)*FIN + 8*hi;
  const short* wpl = wl + (size_t)(w*64+lo)*FIN + 8*hi;
  for(int k0=0; k0<FIN; k0+=32){
    bf16x8 ah[4], al[4], bh[4], bl[4];
    #pragma unroll
    for(int rg=0;rg<4;rg++){
      ah[rg] = *(const bf16x8*)(xh + aoff[rg] + k0);
      al[rg] = *(const bf16x8*)(xl + aoff[rg] + k0);
    }
    #pragma unroll
    for(int tt=0;tt<4;tt++){
      bh[tt] = *(const bf16x8*)(wph + (size_t)tt*16*FIN + k0);
      bl[tt] = *(const bf16x8*)(wpl + (size_t)tt*16*FIN + k0);
    }
    #pragma unroll
    for(int rg=0;rg<4;rg++){
      #pragma unroll
      for(int tt=0;tt<4;tt++){
        acc[rg][tt] = __builtin_amdgcn_mfma_f32_16x16x32_bf16(ah[rg], bh[tt], acc[rg][tt], 0, 0, 0);
        acc[rg][tt] = __builtin_amdgcn_mfma_f32_16x16x32_bf16(al[rg], bh[tt], acc[rg][tt], 0, 0, 0);
        acc[rg][tt] = __builtin_amdgcn_mfma_f32_16x16x32_bf16(ah[rg], bl[tt], acc[rg][tt], 0, 0, 0);
      }
    }
  }
  #pragma unroll
  for(int rg=0;rg<4;rg++){
    #pragma unroll
    for(int tt=0;tt<4;tt++){
      #pragma unroll
      for(int r=0;r<4;r++){
        int row = rowbase + rg*16 + hi*4 + r;
        if(row < NN) h1b[(size_t)row*F1 + w*64 + tt*16 + lo] = f2bf(acc[rg][tt][r]);
      }
    }
  }
  // fused attention dots for head w (prescaled by log2 e)
  float ps[4][4], pd[4][4];              // [rg][r]
  #pragma unroll
  for(int rg=0;rg<4;rg++)
    #pragma unroll
    for(int r=0;r<4;r++){ ps[rg][r]=0.f; pd[rg][r]=0.f; }
  #pragma unroll
  for(int tt=0;tt<4;tt++){
    float sv = as1[w*64+tt*16+lo]*LOG2E, dv = ad1[w*64+tt*16+lo]*LOG2E;
    #pragma unroll
    for(int rg=0;rg<4;rg++)
      #pragma unroll
      for(int r=0;r<4;r++){ ps[rg][r] += acc[rg][tt][r]*sv; pd[rg][r] += acc[rg][tt][r]*dv; }
  }
  #pragma unroll
  for(int off=1; off<16; off<<=1){
    #pragma unroll
    for(int rg=0;rg<4;rg++)
      #pragma unroll
      for(int r=0;r<4;r++){
        ps[rg][r] += __shfl_xor(ps[rg][r], off, 64);
        pd[rg][r] += __shfl_xor(pd[rg][r], off, 64);
      }
  }
  if(lo == 0){
    #pragma unroll
    for(int rg=0;rg<4;rg++)
      #pragma unroll
      for(int r=0;r<4;r++){
        int row = rowbase + rg*16 + hi*4 + r;
        if(row < NN){ aS[row*HEADS+w] = ps[rg][r]; aD[row*HEADS+w] = pd[rg][r]; }
      }
  }
}

// ---- layer-1 aggregation + bias + BN + ELU -> h2 (f32), one wave per node.
// Phase B widened: 2 edges/iter, 32 lanes x 16B per edge (8 channels/lane).
__global__ __launch_bounds__(256) void k_agg1(const u16* __restrict__ h1b,
  const float* __restrict__ aS, const float* __restrict__ aD,
  const int* __restrict__ rowptr, const int* __restrict__ adj,
  const float* __restrict__ b1, const float* __restrict__ g1, const float* __restrict__ be1,
  const float* __restrict__ mn1, const float* __restrict__ vr1,
  float* __restrict__ h2){
  __shared__ float lw[4][CHUNK*4];   // [wave][i*4+head]
  __shared__ int   lsrc[4][CHUNK];
  int w = threadIdx.x >> 6, lane = threadIdx.x & 63;
  int node = blockIdx.x*4 + w;
  int g = lane >> 5, li = lane & 31;
  int hb = li >> 3;                  // head of this lane's 8-channel block
  int beg = rowptr[node], end = rowptr[node+1];
  float4 ad4 = *(const float4*)&aD[node*HEADS];
  float den[4] = {0.f,0.f,0.f,0.f};
  float acc[8] = {0.f,0.f,0.f,0.f,0.f,0.f,0.f,0.f};
  int total = end - beg + 1;                  // + self loop
  for(int c0=0; c0<total; c0+=CHUNK){
    int n = min(CHUNK, total - c0);
    for(int i=lane; i<n; i+=64){
      int e = beg + c0 + i;
      int src = (e < end) ? adj[e] : node;
      float4 s4 = *(const float4*)&aS[src*HEADS];
      float w0 = s4.x + ad4.x; w0 = w0>0.f?w0:SLOPE*w0; w0 = exp2f(fminf(w0,110.f));
      float w1 = s4.y + ad4.y; w1 = w1>0.f?w1:SLOPE*w1; w1 = exp2f(fminf(w1,110.f));
      float w2 = s4.z + ad4.z; w2 = w2>0.f?w2:SLOPE*w2; w2 = exp2f(fminf(w2,110.f));
      float w3 = s4.w + ad4.w; w3 = w3>0.f?w3:SLOPE*w3; w3 = exp2f(fminf(w3,110.f));
      lsrc[w][i] = src;
      *(float4*)&lw[w][i*4] = make_float4(w0,w1,w2,w3);
      den[0]+=w0; den[1]+=w1; den[2]+=w2; den[3]+=w3;
    }
    asm volatile("s_waitcnt lgkmcnt(0)" ::: "memory");
    #pragma unroll 2
    for(int i=0; i<n; i+=2){
      int e = i + g;
      bool ok = e < n;
      int src = ok ? lsrc[w][e] : node;
      float wg = ok ? lw[w][e*4 + hb] : 0.f;
      uint4 pv = *(const uint4*)&h1b[(size_t)src*F1 + li*8];
      acc[0] += wg*__uint_as_float(pv.x << 16);  acc[1] += wg*__uint_as_float(pv.x & 0xffff0000u);
      acc[2] += wg*__uint_as_float(pv.y << 16);  acc[3] += wg*__uint_as_float(pv.y & 0xffff0000u);
      acc[4] += wg*__uint_as_float(pv.z << 16);  acc[5] += wg*__uint_as_float(pv.z & 0xffff0000u);
      acc[6] += wg*__uint_as_float(pv.w << 16);  acc[7] += wg*__uint_as_float(pv.w & 0xffff0000u);
    }
  }
  #pragma unroll
  for(int off=1; off<64; off<<=1){
    #pragma unroll
    for(int q=0;q<4;q++) den[q] += __shfl_xor(den[q], off, 64);
  }
  #pragma unroll
  for(int k=0;k<8;k++) acc[k] += __shfl_xor(acc[k], 32, 64);
  if(lane < 32){
    float dsel = hb==0 ? den[0] : (hb==1 ? den[1] : (hb==2 ? den[2] : den[3]));
    float inv = 1.f/(dsel + 1e-16f);
    int c = li*8;
    float o[8];
    #pragma unroll
    for(int j=0;j<8;j++){
      float v = acc[j]*inv + b1[c+j];
      v = (v - mn1[c+j]) * rsqrtf(vr1[c+j] + 1e-5f) * g1[c+j] + be1[c+j];
      o[j] = v > 0.f ? v : (__expf(v) - 1.f);   // ELU
    }
    *(float4*)&h2[(size_t)node*F1 + c]     = make_float4(o[0],o[1],o[2],o[3]);
    *(float4*)&h2[(size_t)node*F1 + c + 4] = make_float4(o[4],o[5],o[6],o[7]);
  }
}

// ---- GEMM2 (MFMA bf16x3, on-the-fly h2 split) + fused attention dots layer 2.
__global__ __launch_bounds__(256) void k_gemm2(const float* __restrict__ h2,
    const short* __restrict__ w2h, const short* __restrict__ w2l,
    const float* __restrict__ as2, const float* __restrict__ ad2,
    float* __restrict__ h2p, float* __restrict__ aS2, float* __restrict__ aD2){
  int w = threadIdx.x >> 6, lane = threadIdx.x & 63;
  int lo = lane & 15, hi = lane >> 4;
  int rowbase = blockIdx.x*64 + w*16;
  int arow = rowbase + lo; if(arow >= NN) arow = NN-1;
  f32x4 acc[3];
  #pragma unroll
  for(int tt=0;tt<3;tt++) acc[tt] = (f32x4){0.f,0.f,0.f,0.f};
  const float* xp = h2 + (size_t)arow*F1 + 8*hi;
  const short* bph = w2h + (size_t)lo*F1 + 8*hi;
  const short* bpl = w2l + (size_t)lo*F1 + 8*hi;
  for(int k0=0; k0<F1; k0+=32){
    float4 va = *(const float4*)(xp + k0);
    float4 vb = *(const float4*)(xp + k0 + 4);
    float v[8] = {va.x,va.y,va.z,va.w,vb.x,vb.y,vb.z,vb.w};
    bf16x8 ah, al;
    #pragma unroll
    for(int j=0;j<8;j++){
      u32 u = __float_as_uint(v[j]);
      ah[j] = (short)(u >> 16);
      float hf = __uint_as_float(u & 0xffff0000u);
      al[j] = (short)(__float_as_uint(v[j] - hf) >> 16);
    }
    #pragma unroll
    for(int tt=0;tt<3;tt++){
      bf16x8 bh = *(const bf16x8*)(bph + (size_t)tt*16*F1 + k0);
      bf16x8 bl = *(const bf16x8*)(bpl + (size_t)tt*16*F1 + k0);
      acc[tt] = __builtin_amdgcn_mfma_f32_16x16x32_bf16(ah, bh, acc[tt], 0, 0, 0);
      acc[tt] = __builtin_amdgcn_mfma_f32_16x16x32_bf16(al, bh, acc[tt], 0, 0, 0);
      acc[tt] = __builtin_amdgcn_mfma_f32_16x16x32_bf16(ah, bl, acc[tt], 0, 0, 0);
    }
  }
  float ps[4] = {0.f,0.f,0.f,0.f}, pd[4] = {0.f,0.f,0.f,0.f};
  #pragma unroll
  for(int tt=0;tt<3;tt++){
    int col = tt*16 + lo;
    float sv = (col < NC) ? as2[col]*LOG2E : 0.f;
    float dv = (col < NC) ? ad2[col]*LOG2E : 0.f;
    #pragma unroll
    for(int r=0;r<4;r++){
      int row = rowbase + hi*4 + r;
      if(row < NN && col < NC) h2p[(size_t)row*NC + col] = acc[tt][r];
      ps[r] += acc[tt][r]*sv; pd[r] += acc[tt][r]*dv;
    }
  }
  #pragma unroll
  for(int off=1; off<16; off<<=1){
    #pragma unroll
    for(int r=0;r<4;r++){ ps[r] += __shfl_xor(ps[r], off, 64); pd[r] += __shfl_xor(pd[r], off, 64); }
  }
  if(lo == 0){
    #pragma unroll
    for(int r=0;r<4;r++){
      int row = rowbase + hi*4 + r;
      if(row < NN){ aS2[row] = ps[r]; aD2[row] = pd[r]; }
    }
  }
}

// ---- layer-2 aggregation -> output (f32), no max pass, LDS weights
__global__ __launch_bounds__(256) void k_agg2(const float* __restrict__ h2p,
  const float* __restrict__ aS2, const float* __restrict__ aD2,
  const int* __restrict__ rowptr, const int* __restrict__ adj,
  const float* __restrict__ b2, float* __restrict__ out){
  __shared__ float lw[4][CHUNK];
  __shared__ int   lsrc[4][CHUNK];
  int w = threadIdx.x >> 6, lane = threadIdx.x & 63;
  int node = blockIdx.x*4 + w;
  int beg = rowptr[node], end = rowptr[node+1];
  float adv = aD2[node];
  float den = 0.f, acc = 0.f;
  int total = end - beg + 1;
  for(int c0=0; c0<total; c0+=CHUNK){
    int n = min(CHUNK, total - c0);
    for(int i=lane; i<n; i+=64){
      int e = beg + c0 + i;
      int src = (e < end) ? adj[e] : node;
      float ev = aS2[src] + adv; ev = ev>0.f?ev:SLOPE*ev;
      float wg = exp2f(fminf(ev,110.f));
      lsrc[w][i] = src;
      lw[w][i] = wg;
      den += wg;
    }
    asm volatile("s_waitcnt lgkmcnt(0)" ::: "memory");
    #pragma unroll 2
    for(int i=0;i<n;i++){
      int s = lsrc[w][i];
      float wg = lw[w][i];
      if(lane < NC) acc += wg * h2p[(size_t)s*NC + lane];
    }
  }
  #pragma unroll
  for(int off=1; off<64; off<<=1) den += __shfl_xor(den, off, 64);
  if(lane < NC) out[(size_t)node*NC + lane] = acc/(den + 1e-16f) + b2[lane];
}

extern "C" void kernel_launch(void* const* d_in, const int* in_sizes, int n_in,
                              void* d_out, int out_size, void* d_ws, size_t ws_size,
                              hipStream_t stream){
  (void)in_sizes; (void)n_in; (void)out_size; (void)ws_size;
  const float* x   = (const float*)d_in[0];
  const int*   ei  = (const int*)d_in[1];
  const float* W1  = (const float*)d_in[2];
  const float* as1 = (const float*)d_in[3];
  const float* ad1 = (const float*)d_in[4];
  const float* b1  = (const float*)d_in[5];
  const float* g1  = (const float*)d_in[6];
  const float* be1 = (const float*)d_in[7];
  const float* mn1 = (const float*)d_in[8];
  const float* vr1 = (const float*)d_in[9];
  const float* W2  = (const float*)d_in[10];
  const float* as2 = (const float*)d_in[11];
  const float* ad2 = (const float*)d_in[12];
  const float* b2  = (const float*)d_in[13];

  char* ws = (char*)d_ws;
  u16*  h1b    = (u16*) (ws + 0);             // 25,600,000 (bf16 h1)
  float* h2    = (float*)(ws + 25600000);     // 51,200,000
  // xh/xl alias h2 (dead once k_gemm1 completes; h2 written later by k_agg1)
  u16*  xh     = (u16*) (ws + 25600000);      // 25,600,000
  u16*  xl     = (u16*) (ws + 51200000);      // 25,600,000
  // w1h/w1l alias h2p (dead before k_gemm2 writes h2p)
  float* h2p   = (float*)(ws + 76800000);     //  8,000,000
  u16*  w1h    = (u16*) (ws + 76800000);      //    131,072
  u16*  w1l    = (u16*) (ws + 76931072);      //    131,072
  float* aS1   = (float*)(ws + 84800000);     //    800,000
  float* aD1   = (float*)(ws + 85600000);     //    800,000
  float* aS2   = (float*)(ws + 86400000);     //    200,000
  float* aD2   = (float*)(ws + 86600000);     //    200,000
  int*  rowptr = (int*)  (ws + 86800000);     //    200,016
  int*  adj    = (int*)  (ws + 87200016);     //  6,400,000
  u32*  bin    = (u32*)  (ws + 93700000);     //  7,056,000 (98*18000*4)
  int*  cnt    = (int*)  (ws + 100800000);    //        392 (98*4)
  int*  rloc   = (int*)  (ws + 100801024);    //    200,704 (98*512*4)
  int*  bsum   = (int*)  (ws + 101002240);    //        392
  int*  bbase  = (int*)  (ws + 101003264);    //        392
  u16*  w2h    = (u16*)  (ws + 101003712);    //     24,576 (48*256*2)
  u16*  w2l    = (u16*)  (ws + 101028288);    //     24,576

  hipMemsetAsync(cnt, 0, NB2*sizeof(int), stream);
  k_prep  <<<6554, 256, 0, stream>>>(x, xh, xl, W1, w1h, w1l, W2, w2h, w2l);
  k_bin   <<<(NE+TILE-1)/TILE, 256, 0, stream>>>(ei, cnt, bin);
  k_hist  <<<NB2, 256, 0, stream>>>(cnt, bin, rloc, bsum);
  k_scanb <<<1, 64, 0, stream>>>(bsum, bbase, rowptr);
  k_fill2 <<<NB2, 256, 0, stream>>>(cnt, bin, rloc, bbase, rowptr, adj);
  k_gemm1 <<<(NN+63)/64, 256, 0, stream>>>((const short*)xh, (const short*)xl,
                                           (const short*)w1h, (const short*)w1l,
                                           as1, ad1, h1b, aS1, aD1);
  k_agg1  <<<NN/4, 256, 0, stream>>>(h1b, aS1, aD1, rowptr, adj, b1, g1, be1, mn1, vr1, h2);
  k_gemm2 <<<(NN+63)/64, 256, 0, stream>>>(h2, (const short*)w2h, (const short*)w2l,
                                           as2, ad2, h2p, aS2, aD2);
  k_agg2  <<<NN/4, 256, 0, stream>>>(h2p, aS2, aD2, rowptr, adj, b2, (float*)d_out);
}

// Round 14
// 390.029 us; speedup vs baseline: 1.0507x; 1.0507x over previous
//
#include <hip/hip_runtime.h>
#include <hip/hip_bf16.h>

#define NN 50000
#define FIN 256
#define F1 256      // HEADS*HID
#define HEADS 4
#define HID 64
#define NC 40
#define NE 1600000
#define SLOPE 0.2f
#define LOG2E 1.44269504f
#define CHUNK 128
#define NB2 98      // coarse dst buckets (512 nodes each)
#define BSH 9
#define BCAP2 18000 // per-bucket capacity (mean 16327, +13 sigma)
#define TILE 2048   // edges per bin block
#define NBIN 782    // bin blocks (782*2048 >= NE)

typedef unsigned int u32;
typedef unsigned short u16;
typedef unsigned char u8;
typedef __attribute__((ext_vector_type(8))) short bf16x8;
typedef __attribute__((ext_vector_type(4))) float f32x4;

__device__ __forceinline__ float us2f(u32 u){ u32 b = u << 16; return __uint_as_float(b); }
__device__ __forceinline__ u16 f2bf(float f){
  u32 b = __float_as_uint(f);
  u32 r = (b + 0x7fffu + ((b >> 16) & 1u)) >> 16;
  return (u16)r;
}

// ---- fused prep: edge binning (blocks 0..781) + x split (782..7031)
//      + W1 transpose/split (7032..7287) + W2 transpose/split (7288..7335)
__global__ __launch_bounds__(256) void k_prep(const int* __restrict__ ei,
      int* __restrict__ cnt, u32* __restrict__ bin,
      const float* __restrict__ x, u16* __restrict__ xh, u16* __restrict__ xl,
      const float* __restrict__ W1, u16* __restrict__ w1h, u16* __restrict__ w1l,
      const float* __restrict__ W2, u16* __restrict__ w2h, u16* __restrict__ w2l){
  __shared__ int hcnt[NB2], hoff[NB2], gbase[NB2], hcur[NB2];
  __shared__ u32 staged[TILE];
  __shared__ u8  sbk[TILE];
  __shared__ int ci;
  int bid = blockIdx.x, tid = threadIdx.x;
  if(bid < NBIN){
    // ---- LDS-staged edge binning (int-width detection inlined per tile)
    int e0 = bid * TILE;
    int nn = min(TILE, NE - e0);
    if(tid==0) ci = 0;
    for(int b=tid;b<NB2;b+=256) hcnt[b] = 0;
    __syncthreads();
    if(ei[2*(e0+tid)+1] != 0) atomicAdd(&ci, 1);   // int64: odd words all 0
    __syncthreads();
    int i64 = (ci == 0);
    u32 val[TILE/256]; int bk[TILE/256];
    #pragma unroll
    for(int j=0;j<TILE/256;j++){
      int t = tid + j*256;
      if(t < nn){
        int i = e0 + t;
        int src = i64 ? ei[2*i] : ei[i];
        int dst = i64 ? ei[2*(NE+i)] : ei[NE+i];
        bk[j] = dst >> BSH;
        val[j] = (u32)src | ((u32)(dst & 511) << 16);
        atomicAdd(&hcnt[bk[j]], 1);
      } else bk[j] = -1;
    }
    __syncthreads();
    if(tid == 0){
      int run = 0;
      for(int b=0;b<NB2;b++){ hoff[b] = run; hcur[b] = run; run += hcnt[b]; }
    }
    __syncthreads();
    if(tid < NB2 && hcnt[tid] > 0) gbase[tid] = atomicAdd(&cnt[tid], hcnt[tid]);
    __syncthreads();
    #pragma unroll
    for(int j=0;j<TILE/256;j++){
      if(bk[j] >= 0){
        int pos = atomicAdd(&hcur[bk[j]], 1);
        staged[pos] = val[j];
        sbk[pos] = (u8)bk[j];
      }
    }
    __syncthreads();
    for(int s=tid; s<nn; s+=256){
      int b = sbk[s];
      int local = gbase[b] + (s - hoff[b]);
      if(local < BCAP2) bin[(size_t)b*BCAP2 + local] = staged[s];
    }
  } else if(bid < 7032){
    int i = ((bid-NBIN)*256 + tid) * 8;
    float4 a = *(const float4*)(x+i);
    float4 b4 = *(const float4*)(x+i+4);
    float v[8] = {a.x,a.y,a.z,a.w,b4.x,b4.y,b4.z,b4.w};
    u16 hi[8], lo[8];
    #pragma unroll
    for(int j=0;j<8;j++){
      u32 u = __float_as_uint(v[j]);
      hi[j] = (u16)(u >> 16);                      // truncate hi
      float hf = __uint_as_float(u & 0xffff0000u);
      lo[j] = (u16)(__float_as_uint(v[j] - hf) >> 16);
    }
    *(ushort4*)&xh[i]   = make_ushort4(hi[0],hi[1],hi[2],hi[3]);
    *(ushort4*)&xh[i+4] = make_ushort4(hi[4],hi[5],hi[6],hi[7]);
    *(ushort4*)&xl[i]   = make_ushort4(lo[0],lo[1],lo[2],lo[3]);
    *(ushort4*)&xl[i+4] = make_ushort4(lo[4],lo[5],lo[6],lo[7]);
  } else if(bid < 7288){
    int id = (bid-7032)*256 + tid;               // 65536 total
    int n = id & 255, k = id >> 8;
    float v = W1[k*F1 + n];
    u16 h = f2bf(v);
    w1h[n*FIN + k] = h;
    w1l[n*FIN + k] = f2bf(v - us2f(h));
  } else {
    int id = (bid-7288)*256 + tid;               // 12288 total: col 0..47, k 0..255
    int col = id >> 8, k = id & 255;
    float v = (col < NC) ? W2[k*NC + col] : 0.f;
    u16 h = f2bf(v);
    w2h[col*F1 + k] = h;
    w2l[col*F1 + k] = f2bf(v - us2f(h));
  }
}

// ---- per-bucket degree histogram + 512-entry LDS exclusive scan
__global__ __launch_bounds__(256) void k_hist(const int* __restrict__ cnt, const u32* __restrict__ bin,
                                              int* __restrict__ rloc, int* __restrict__ bsum){
  __shared__ int dl[512], s1[512], s2[512];
  int b = blockIdx.x, tid = threadIdx.x;
  for(int i=tid;i<512;i+=256) dl[i] = 0;
  __syncthreads();
  int n = min(cnt[b], BCAP2);
  const u32* bp = bin + (size_t)b*BCAP2;
  for(int i=tid;i<n;i+=256) atomicAdd(&dl[(bp[i]>>16)&511], 1);
  __syncthreads();
  for(int i=tid;i<512;i+=256) s1[i] = dl[i];
  __syncthreads();
  int* src = s1; int* dst = s2;
  for(int off=1; off<512; off<<=1){
    for(int i=tid;i<512;i+=256) dst[i] = src[i] + (i>=off ? src[i-off] : 0);
    __syncthreads();
    int* t = src; src = dst; dst = t;
  }
  for(int i=tid;i<512;i+=256) rloc[b*512+i] = src[i] - dl[i];
  if(tid==0) bsum[b] = src[511];
}

// ---- tiny serial scan over 98 bucket totals
__global__ void k_scanb(const int* __restrict__ bsum, int* __restrict__ bbase, int* __restrict__ rowptr){
  if(threadIdx.x==0){
    int run = 0;
    for(int b=0;b<NB2;b++){ bbase[b] = run; run += bsum[b]; }
    rowptr[NN] = run;
  }
}

// ---- per-bucket scatter into contiguous adj window; materializes final rowptr
__global__ __launch_bounds__(256) void k_fill2(const int* __restrict__ cnt, const u32* __restrict__ bin,
                                               const int* __restrict__ rloc, const int* __restrict__ bbase,
                                               int* __restrict__ rowptr, int* __restrict__ adj){
  __shared__ int cur[512];
  int b = blockIdx.x, tid = threadIdx.x;
  int base = bbase[b];
  for(int i=tid;i<512;i+=256){
    int d = b*512 + i;
    int v = base + rloc[b*512+i];
    cur[i] = v;
    if(d < NN) rowptr[d] = v;
  }
  __syncthreads();
  int n = min(cnt[b], BCAP2);
  const u32* bp = bin + (size_t)b*BCAP2;
  for(int i=tid;i<n;i+=256){
    u32 v = bp[i];
    int p = atomicAdd(&cur[(v>>16)&511], 1);
    adj[p] = (int)(v & 0xffffu);
  }
}

// ---- GEMM1 (MFMA bf16x3) + fused attention dots.
__global__ __launch_bounds__(256) void k_gemm1(const short* __restrict__ xh, const short* __restrict__ xl,
                                               const short* __restrict__ wh, const short* __restrict__ wl,
                                               const float* __restrict__ as1, const float* __restrict__ ad1,
                                               u16* __restrict__ h1b,
                                               float* __restrict__ aS, float* __restrict__ aD){
  int w = threadIdx.x >> 6, lane = threadIdx.x & 63;
  int lo = lane & 15, hi = lane >> 4;
  int rowbase = blockIdx.x*64;
  f32x4 acc[4][4];                       // [rg][tt]
  #pragma unroll
  for(int rg=0;rg<4;rg++)
    #pragma unroll
    for(int tt=0;tt<4;tt++) acc[rg][tt] = (f32x4){0.f,0.f,0.f,0.f};
  size_t aoff[4];
  #pragma unroll
  for(int rg=0;rg<4;rg++){
    int r = rowbase + rg*16 + lo; if(r >= NN) r = NN-1;
    aoff[rg] = (size_t)r*FIN + 8*hi;
  }
  const short* wph = wh + (size_t)(w*64+lo)*FIN + 8*hi;
  const short* wpl = wl + (size_t)(w*64+lo)*FIN + 8*hi;
  for(int k0=0; k0<FIN; k0+=32){
    bf16x8 ah[4], al[4], bh[4], bl[4];
    #pragma unroll
    for(int rg=0;rg<4;rg++){
      ah[rg] = *(const bf16x8*)(xh + aoff[rg] + k0);
      al[rg] = *(const bf16x8*)(xl + aoff[rg] + k0);
    }
    #pragma unroll
    for(int tt=0;tt<4;tt++){
      bh[tt] = *(const bf16x8*)(wph + (size_t)tt*16*FIN + k0);
      bl[tt] = *(const bf16x8*)(wpl + (size_t)tt*16*FIN + k0);
    }
    #pragma unroll
    for(int rg=0;rg<4;rg++){
      #pragma unroll
      for(int tt=0;tt<4;tt++){
        acc[rg][tt] = __builtin_amdgcn_mfma_f32_16x16x32_bf16(ah[rg], bh[tt], acc[rg][tt], 0, 0, 0);
        acc[rg][tt] = __builtin_amdgcn_mfma_f32_16x16x32_bf16(al[rg], bh[tt], acc[rg][tt], 0, 0, 0);
        acc[rg][tt] = __builtin_amdgcn_mfma_f32_16x16x32_bf16(ah[rg], bl[tt], acc[rg][tt], 0, 0, 0);
      }
    }
  }
  #pragma unroll
  for(int rg=0;rg<4;rg++){
    #pragma unroll
    for(int tt=0;tt<4;tt++){
      #pragma unroll
      for(int r=0;r<4;r++){
        int row = rowbase + rg*16 + hi*4 + r;
        if(row < NN) h1b[(size_t)row*F1 + w*64 + tt*16 + lo] = f2bf(acc[rg][tt][r]);
      }
    }
  }
  // fused attention dots for head w (prescaled by log2 e)
  float ps[4][4], pd[4][4];              // [rg][r]
  #pragma unroll
  for(int rg=0;rg<4;rg++)
    #pragma unroll
    for(int r=0;r<4;r++){ ps[rg][r]=0.f; pd[rg][r]=0.f; }
  #pragma unroll
  for(int tt=0;tt<4;tt++){
    float sv = as1[w*64+tt*16+lo]*LOG2E, dv = ad1[w*64+tt*16+lo]*LOG2E;
    #pragma unroll
    for(int rg=0;rg<4;rg++)
      #pragma unroll
      for(int r=0;r<4;r++){ ps[rg][r] += acc[rg][tt][r]*sv; pd[rg][r] += acc[rg][tt][r]*dv; }
  }
  #pragma unroll
  for(int off=1; off<16; off<<=1){
    #pragma unroll
    for(int rg=0;rg<4;rg++)
      #pragma unroll
      for(int r=0;r<4;r++){
        ps[rg][r] += __shfl_xor(ps[rg][r], off, 64);
        pd[rg][r] += __shfl_xor(pd[rg][r], off, 64);
      }
  }
  if(lo == 0){
    #pragma unroll
    for(int rg=0;rg<4;rg++)
      #pragma unroll
      for(int r=0;r<4;r++){
        int row = rowbase + rg*16 + hi*4 + r;
        if(row < NN){ aS[row*HEADS+w] = ps[rg][r]; aD[row*HEADS+w] = pd[rg][r]; }
      }
  }
}

// ---- layer-1 aggregation + bias + BN + ELU -> h2 (f32), one wave per node.
// Phase B: 2 edges/iter, 32 lanes x 16B per edge (8 channels/lane).
__global__ __launch_bounds__(256) void k_agg1(const u16* __restrict__ h1b,
  const float* __restrict__ aS, const float* __restrict__ aD,
  const int* __restrict__ rowptr, const int* __restrict__ adj,
  const float* __restrict__ b1, const float* __restrict__ g1, const float* __restrict__ be1,
  const float* __restrict__ mn1, const float* __restrict__ vr1,
  float* __restrict__ h2){
  __shared__ float lw[4][CHUNK*4];   // [wave][i*4+head]
  __shared__ int   lsrc[4][CHUNK];
  int w = threadIdx.x >> 6, lane = threadIdx.x & 63;
  int node = blockIdx.x*4 + w;
  int g = lane >> 5, li = lane & 31;
  int hb = li >> 3;                  // head of this lane's 8-channel block
  int beg = rowptr[node], end = rowptr[node+1];
  float4 ad4 = *(const float4*)&aD[node*HEADS];
  float den[4] = {0.f,0.f,0.f,0.f};
  float acc[8] = {0.f,0.f,0.f,0.f,0.f,0.f,0.f,0.f};
  int total = end - beg + 1;                  // + self loop
  for(int c0=0; c0<total; c0+=CHUNK){
    int n = min(CHUNK, total - c0);
    for(int i=lane; i<n; i+=64){
      int e = beg + c0 + i;
      int src = (e < end) ? adj[e] : node;
      float4 s4 = *(const float4*)&aS[src*HEADS];
      float w0 = s4.x + ad4.x; w0 = w0>0.f?w0:SLOPE*w0; w0 = exp2f(fminf(w0,110.f));
      float w1 = s4.y + ad4.y; w1 = w1>0.f?w1:SLOPE*w1; w1 = exp2f(fminf(w1,110.f));
      float w2 = s4.z + ad4.z; w2 = w2>0.f?w2:SLOPE*w2; w2 = exp2f(fminf(w2,110.f));
      float w3 = s4.w + ad4.w; w3 = w3>0.f?w3:SLOPE*w3; w3 = exp2f(fminf(w3,110.f));
      lsrc[w][i] = src;
      *(float4*)&lw[w][i*4] = make_float4(w0,w1,w2,w3);
      den[0]+=w0; den[1]+=w1; den[2]+=w2; den[3]+=w3;
    }
    asm volatile("s_waitcnt lgkmcnt(0)" ::: "memory");
    #pragma unroll 2
    for(int i=0; i<n; i+=2){
      int e = i + g;
      bool ok = e < n;
      int src = ok ? lsrc[w][e] : node;
      float wg = ok ? lw[w][e*4 + hb] : 0.f;
      uint4 pv = *(const uint4*)&h1b[(size_t)src*F1 + li*8];
      acc[0] += wg*__uint_as_float(pv.x << 16);  acc[1] += wg*__uint_as_float(pv.x & 0xffff0000u);
      acc[2] += wg*__uint_as_float(pv.y << 16);  acc[3] += wg*__uint_as_float(pv.y & 0xffff0000u);
      acc[4] += wg*__uint_as_float(pv.z << 16);  acc[5] += wg*__uint_as_float(pv.z & 0xffff0000u);
      acc[6] += wg*__uint_as_float(pv.w << 16);  acc[7] += wg*__uint_as_float(pv.w & 0xffff0000u);
    }
  }
  #pragma unroll
  for(int off=1; off<64; off<<=1){
    #pragma unroll
    for(int q=0;q<4;q++) den[q] += __shfl_xor(den[q], off, 64);
  }
  #pragma unroll
  for(int k=0;k<8;k++) acc[k] += __shfl_xor(acc[k], 32, 64);
  if(lane < 32){
    float dsel = hb==0 ? den[0] : (hb==1 ? den[1] : (hb==2 ? den[2] : den[3]));
    float inv = 1.f/(dsel + 1e-16f);
    int c = li*8;
    float o[8];
    #pragma unroll
    for(int j=0;j<8;j++){
      float v = acc[j]*inv + b1[c+j];
      v = (v - mn1[c+j]) * rsqrtf(vr1[c+j] + 1e-5f) * g1[c+j] + be1[c+j];
      o[j] = v > 0.f ? v : (__expf(v) - 1.f);   // ELU
    }
    *(float4*)&h2[(size_t)node*F1 + c]     = make_float4(o[0],o[1],o[2],o[3]);
    *(float4*)&h2[(size_t)node*F1 + c + 4] = make_float4(o[4],o[5],o[6],o[7]);
  }
}

// ---- GEMM2 (MFMA bf16x3, on-the-fly h2 split) + fused attention dots layer 2.
// h2p stored bf16 (halves agg2's gather; 4MB -> single-XCD-L2-resident).
__global__ __launch_bounds__(256) void k_gemm2(const float* __restrict__ h2,
    const short* __restrict__ w2h, const short* __restrict__ w2l,
    const float* __restrict__ as2, const float* __restrict__ ad2,
    u16* __restrict__ h2p, float* __restrict__ aS2, float* __restrict__ aD2){
  int w = threadIdx.x >> 6, lane = threadIdx.x & 63;
  int lo = lane & 15, hi = lane >> 4;
  int rowbase = blockIdx.x*64 + w*16;
  int arow = rowbase + lo; if(arow >= NN) arow = NN-1;
  f32x4 acc[3];
  #pragma unroll
  for(int tt=0;tt<3;tt++) acc[tt] = (f32x4){0.f,0.f,0.f,0.f};
  const float* xp = h2 + (size_t)arow*F1 + 8*hi;
  const short* bph = w2h + (size_t)lo*F1 + 8*hi;
  const short* bpl = w2l + (size_t)lo*F1 + 8*hi;
  for(int k0=0; k0<F1; k0+=32){
    float4 va = *(const float4*)(xp + k0);
    float4 vb = *(const float4*)(xp + k0 + 4);
    float v[8] = {va.x,va.y,va.z,va.w,vb.x,vb.y,vb.z,vb.w};
    bf16x8 ah, al;
    #pragma unroll
    for(int j=0;j<8;j++){
      u32 u = __float_as_uint(v[j]);
      ah[j] = (short)(u >> 16);
      float hf = __uint_as_float(u & 0xffff0000u);
      al[j] = (short)(__float_as_uint(v[j] - hf) >> 16);
    }
    #pragma unroll
    for(int tt=0;tt<3;tt++){
      bf16x8 bh = *(const bf16x8*)(bph + (size_t)tt*16*F1 + k0);
      bf16x8 bl = *(const bf16x8*)(bpl + (size_t)tt*16*F1 + k0);
      acc[tt] = __builtin_amdgcn_mfma_f32_16x16x32_bf16(ah, bh, acc[tt], 0, 0, 0);
      acc[tt] = __builtin_amdgcn_mfma_f32_16x16x32_bf16(al, bh, acc[tt], 0, 0, 0);
      acc[tt] = __builtin_amdgcn_mfma_f32_16x16x32_bf16(ah, bl, acc[tt], 0, 0, 0);
    }
  }
  float ps[4] = {0.f,0.f,0.f,0.f}, pd[4] = {0.f,0.f,0.f,0.f};
  #pragma unroll
  for(int tt=0;tt<3;tt++){
    int col = tt*16 + lo;
    float sv = (col < NC) ? as2[col]*LOG2E : 0.f;
    float dv = (col < NC) ? ad2[col]*LOG2E : 0.f;
    #pragma unroll
    for(int r=0;r<4;r++){
      int row = rowbase + hi*4 + r;
      if(row < NN && col < NC) h2p[(size_t)row*NC + col] = f2bf(acc[tt][r]);
      ps[r] += acc[tt][r]*sv; pd[r] += acc[tt][r]*dv;
    }
  }
  #pragma unroll
  for(int off=1; off<16; off<<=1){
    #pragma unroll
    for(int r=0;r<4;r++){ ps[r] += __shfl_xor(ps[r], off, 64); pd[r] += __shfl_xor(pd[r], off, 64); }
  }
  if(lo == 0){
    #pragma unroll
    for(int r=0;r<4;r++){
      int row = rowbase + hi*4 + r;
      if(row < NN){ aS2[row] = ps[r]; aD2[row] = pd[r]; }
    }
  }
}

// ---- layer-2 aggregation -> output (f32), bf16 h2p gather
__global__ __launch_bounds__(256) void k_agg2(const u16* __restrict__ h2p,
  const float* __restrict__ aS2, const float* __restrict__ aD2,
  const int* __restrict__ rowptr, const int* __restrict__ adj,
  const float* __restrict__ b2, float* __restrict__ out){
  __shared__ float lw[4][CHUNK];
  __shared__ int   lsrc[4][CHUNK];
  int w = threadIdx.x >> 6, lane = threadIdx.x & 63;
  int node = blockIdx.x*4 + w;
  int beg = rowptr[node], end = rowptr[node+1];
  float adv = aD2[node];
  float den = 0.f, acc = 0.f;
  int total = end - beg + 1;
  for(int c0=0; c0<total; c0+=CHUNK){
    int n = min(CHUNK, total - c0);
    for(int i=lane; i<n; i+=64){
      int e = beg + c0 + i;
      int src = (e < end) ? adj[e] : node;
      float ev = aS2[src] + adv; ev = ev>0.f?ev:SLOPE*ev;
      float wg = exp2f(fminf(ev,110.f));
      lsrc[w][i] = src;
      lw[w][i] = wg;
      den += wg;
    }
    asm volatile("s_waitcnt lgkmcnt(0)" ::: "memory");
    #pragma unroll 2
    for(int i=0;i<n;i++){
      int s = lsrc[w][i];
      float wg = lw[w][i];
      if(lane < NC) acc += wg * us2f(h2p[(size_t)s*NC + lane]);
    }
  }
  #pragma unroll
  for(int off=1; off<64; off<<=1) den += __shfl_xor(den, off, 64);
  if(lane < NC) out[(size_t)node*NC + lane] = acc/(den + 1e-16f) + b2[lane];
}

extern "C" void kernel_launch(void* const* d_in, const int* in_sizes, int n_in,
                              void* d_out, int out_size, void* d_ws, size_t ws_size,
                              hipStream_t stream){
  (void)in_sizes; (void)n_in; (void)out_size; (void)ws_size;
  const float* x   = (const float*)d_in[0];
  const int*   ei  = (const int*)d_in[1];
  const float* W1  = (const float*)d_in[2];
  const float* as1 = (const float*)d_in[3];
  const float* ad1 = (const float*)d_in[4];
  const float* b1  = (const float*)d_in[5];
  const float* g1  = (const float*)d_in[6];
  const float* be1 = (const float*)d_in[7];
  const float* mn1 = (const float*)d_in[8];
  const float* vr1 = (const float*)d_in[9];
  const float* W2  = (const float*)d_in[10];
  const float* as2 = (const float*)d_in[11];
  const float* ad2 = (const float*)d_in[12];
  const float* b2  = (const float*)d_in[13];

  char* ws = (char*)d_ws;
  u16*  h1b    = (u16*) (ws + 0);             // 25,600,000 (bf16 h1)
  float* h2    = (float*)(ws + 25600000);     // 51,200,000
  // xh/xl alias h2 (dead once k_gemm1 completes; h2 written later by k_agg1)
  u16*  xh     = (u16*) (ws + 25600000);      // 25,600,000
  u16*  xl     = (u16*) (ws + 51200000);      // 25,600,000
  // w1h/w1l alias h2p (dead before k_gemm2 writes h2p)
  u16*  h2p    = (u16*) (ws + 76800000);      //  4,000,000 (bf16)
  u16*  w1h    = (u16*) (ws + 76800000);      //    131,072
  u16*  w1l    = (u16*) (ws + 76931072);      //    131,072
  float* aS1   = (float*)(ws + 84800000);     //    800,000
  float* aD1   = (float*)(ws + 85600000);     //    800,000
  float* aS2   = (float*)(ws + 86400000);     //    200,000
  float* aD2   = (float*)(ws + 86600000);     //    200,000
  int*  rowptr = (int*)  (ws + 86800000);     //    200,016
  int*  adj    = (int*)  (ws + 87200016);     //  6,400,000
  u32*  bin    = (u32*)  (ws + 93700000);     //  7,056,000 (98*18000*4)
  int*  cnt    = (int*)  (ws + 100800000);    //        392 (98*4)
  int*  rloc   = (int*)  (ws + 100801024);    //    200,704 (98*512*4)
  int*  bsum   = (int*)  (ws + 101002240);    //        392
  int*  bbase  = (int*)  (ws + 101003264);    //        392
  u16*  w2h    = (u16*)  (ws + 101003712);    //     24,576 (48*256*2)
  u16*  w2l    = (u16*)  (ws + 101028288);    //     24,576

  hipMemsetAsync(cnt, 0, NB2*sizeof(int), stream);
  k_prep  <<<7336, 256, 0, stream>>>(ei, cnt, bin, x, xh, xl, W1, w1h, w1l, W2, w2h, w2l);
  k_hist  <<<NB2, 256, 0, stream>>>(cnt, bin, rloc, bsum);
  k_scanb <<<1, 64, 0, stream>>>(bsum, bbase, rowptr);
  k_fill2 <<<NB2, 256, 0, stream>>>(cnt, bin, rloc, bbase, rowptr, adj);
  k_gemm1 <<<(NN+63)/64, 256, 0, stream>>>((const short*)xh, (const short*)xl,
                                           (const short*)w1h, (const short*)w1l,
                                           as1, ad1, h1b, aS1, aD1);
  k_agg1  <<<NN/4, 256, 0, stream>>>(h1b, aS1, aD1, rowptr, adj, b1, g1, be1, mn1, vr1, h2);
  k_gemm2 <<<(NN+63)/64, 256, 0, stream>>>(h2, (const short*)w2h, (const short*)w2l,
                                           as2, ad2, h2p, aS2, aD2);
  k_agg2  <<<NN/4, 256, 0, stream>>>(h2p, aS2, aD2, rowptr, adj, b2, (float*)d_out);
}

// Round 15
// 372.940 us; speedup vs baseline: 1.0989x; 1.0458x over previous
//
#include <hip/hip_runtime.h>
#include <hip/hip_bf16.h>

#define NN 50000
#define FIN 256
#define F1 256      // HEADS*HID
#define HEADS 4
#define HID 64
#define NC 40
#define NE 1600000
#define SLOPE 0.2f
#define LOG2E 1.44269504f
#define CHUNK 128
#define NB2 98      // coarse dst buckets (512 nodes each)
#define BSH 9
#define BCAP2 18000 // per-bucket capacity (mean 16327, +13 sigma)
#define TILE 2048   // edges per bin block
#define NBIN 782    // bin blocks (782*2048 >= NE)
#define NG1 782     // gemm1 blocks ((NN+63)/64)

typedef unsigned int u32;
typedef unsigned short u16;
typedef unsigned char u8;
typedef __attribute__((ext_vector_type(8))) short bf16x8;
typedef __attribute__((ext_vector_type(4))) float f32x4;

__device__ __forceinline__ float us2f(u32 u){ u32 b = u << 16; return __uint_as_float(b); }
__device__ __forceinline__ u16 f2bf(float f){
  u32 b = __float_as_uint(f);
  u32 r = (b + 0x7fffu + ((b >> 16) & 1u)) >> 16;
  return (u16)r;
}

// ---- fused prep: edge binning (blocks 0..781) + x split (782..7031)
//      + W1 transpose/split (7032..7287) + W2 transpose/split (7288..7335)
__global__ __launch_bounds__(256) void k_prep(const int* __restrict__ ei,
      int* __restrict__ cnt, u32* __restrict__ bin,
      const float* __restrict__ x, u16* __restrict__ xh, u16* __restrict__ xl,
      const float* __restrict__ W1, u16* __restrict__ w1h, u16* __restrict__ w1l,
      const float* __restrict__ W2, u16* __restrict__ w2h, u16* __restrict__ w2l){
  __shared__ int hcnt[NB2], hoff[NB2], gbase[NB2], hcur[NB2];
  __shared__ u32 staged[TILE];
  __shared__ u8  sbk[TILE];
  __shared__ int ci;
  int bid = blockIdx.x, tid = threadIdx.x;
  if(bid < NBIN){
    int e0 = bid * TILE;
    int nn = min(TILE, NE - e0);
    if(tid==0) ci = 0;
    for(int b=tid;b<NB2;b+=256) hcnt[b] = 0;
    __syncthreads();
    if(ei[2*(e0+tid)+1] != 0) atomicAdd(&ci, 1);   // int64: odd words all 0
    __syncthreads();
    int i64 = (ci == 0);
    u32 val[TILE/256]; int bk[TILE/256];
    #pragma unroll
    for(int j=0;j<TILE/256;j++){
      int t = tid + j*256;
      if(t < nn){
        int i = e0 + t;
        int src = i64 ? ei[2*i] : ei[i];
        int dst = i64 ? ei[2*(NE+i)] : ei[NE+i];
        bk[j] = dst >> BSH;
        val[j] = (u32)src | ((u32)(dst & 511) << 16);
        atomicAdd(&hcnt[bk[j]], 1);
      } else bk[j] = -1;
    }
    __syncthreads();
    if(tid == 0){
      int run = 0;
      for(int b=0;b<NB2;b++){ hoff[b] = run; hcur[b] = run; run += hcnt[b]; }
    }
    __syncthreads();
    if(tid < NB2 && hcnt[tid] > 0) gbase[tid] = atomicAdd(&cnt[tid], hcnt[tid]);
    __syncthreads();
    #pragma unroll
    for(int j=0;j<TILE/256;j++){
      if(bk[j] >= 0){
        int pos = atomicAdd(&hcur[bk[j]], 1);
        staged[pos] = val[j];
        sbk[pos] = (u8)bk[j];
      }
    }
    __syncthreads();
    for(int s=tid; s<nn; s+=256){
      int b = sbk[s];
      int local = gbase[b] + (s - hoff[b]);
      if(local < BCAP2) bin[(size_t)b*BCAP2 + local] = staged[s];
    }
  } else if(bid < 7032){
    int i = ((bid-NBIN)*256 + tid) * 8;
    float4 a = *(const float4*)(x+i);
    float4 b4 = *(const float4*)(x+i+4);
    float v[8] = {a.x,a.y,a.z,a.w,b4.x,b4.y,b4.z,b4.w};
    u16 hi[8], lo[8];
    #pragma unroll
    for(int j=0;j<8;j++){
      u32 u = __float_as_uint(v[j]);
      hi[j] = (u16)(u >> 16);                      // truncate hi
      float hf = __uint_as_float(u & 0xffff0000u);
      lo[j] = (u16)(__float_as_uint(v[j] - hf) >> 16);
    }
    *(ushort4*)&xh[i]   = make_ushort4(hi[0],hi[1],hi[2],hi[3]);
    *(ushort4*)&xh[i+4] = make_ushort4(hi[4],hi[5],hi[6],hi[7]);
    *(ushort4*)&xl[i]   = make_ushort4(lo[0],lo[1],lo[2],lo[3]);
    *(ushort4*)&xl[i+4] = make_ushort4(lo[4],lo[5],lo[6],lo[7]);
  } else if(bid < 7288){
    int id = (bid-7032)*256 + tid;               // 65536 total
    int n = id & 255, k = id >> 8;
    float v = W1[k*F1 + n];
    u16 h = f2bf(v);
    w1h[n*FIN + k] = h;
    w1l[n*FIN + k] = f2bf(v - us2f(h));
  } else {
    int id = (bid-7288)*256 + tid;               // 12288 total: col 0..47, k 0..255
    int col = id >> 8, k = id & 255;
    float v = (col < NC) ? W2[k*NC + col] : 0.f;
    u16 h = f2bf(v);
    w2h[col*F1 + k] = h;
    w2l[col*F1 + k] = f2bf(v - us2f(h));
  }
}

// ---- fused GEMM1 (blocks 0..781) + per-bucket histogram/local-scan (782..879)
__global__ __launch_bounds__(256) void k_g1h(const short* __restrict__ xh, const short* __restrict__ xl,
                                             const short* __restrict__ wh, const short* __restrict__ wl,
                                             const float* __restrict__ as1, const float* __restrict__ ad1,
                                             u16* __restrict__ h1b,
                                             float* __restrict__ aS, float* __restrict__ aD,
                                             const int* __restrict__ cnt, const u32* __restrict__ bin,
                                             int* __restrict__ rloc, int* __restrict__ bsum){
  __shared__ int dl[512], s1[512], s2[512];
  int tid = threadIdx.x;
  if(blockIdx.x >= NG1){
    // ---- histogram + 512-entry LDS exclusive scan for bucket b
    int b = blockIdx.x - NG1;
    for(int i=tid;i<512;i+=256) dl[i] = 0;
    __syncthreads();
    int n = min(cnt[b], BCAP2);
    const u32* bp = bin + (size_t)b*BCAP2;
    for(int i=tid;i<n;i+=256) atomicAdd(&dl[(bp[i]>>16)&511], 1);
    __syncthreads();
    for(int i=tid;i<512;i+=256) s1[i] = dl[i];
    __syncthreads();
    int* src = s1; int* dst = s2;
    for(int off=1; off<512; off<<=1){
      for(int i=tid;i<512;i+=256) dst[i] = src[i] + (i>=off ? src[i-off] : 0);
      __syncthreads();
      int* t = src; src = dst; dst = t;
    }
    for(int i=tid;i<512;i+=256) rloc[b*512+i] = src[i] - dl[i];
    if(tid==0) bsum[b] = src[511];
    return;
  }
  // ---- GEMM1 (MFMA bf16x3) + fused attention dots
  int w = tid >> 6, lane = tid & 63;
  int lo = lane & 15, hi = lane >> 4;
  int rowbase = blockIdx.x*64;
  f32x4 acc[4][4];                       // [rg][tt]
  #pragma unroll
  for(int rg=0;rg<4;rg++)
    #pragma unroll
    for(int tt=0;tt<4;tt++) acc[rg][tt] = (f32x4){0.f,0.f,0.f,0.f};
  size_t aoff[4];
  #pragma unroll
  for(int rg=0;rg<4;rg++){
    int r = rowbase + rg*16 + lo; if(r >= NN) r = NN-1;
    aoff[rg] = (size_t)r*FIN + 8*hi;
  }
  const short* wph = wh + (size_t)(w*64+lo)*FIN + 8*hi;
  const short* wpl = wl + (size_t)(w*64+lo)*FIN + 8*hi;
  for(int k0=0; k0<FIN; k0+=32){
    bf16x8 ah[4], al[4], bh[4], bl[4];
    #pragma unroll
    for(int rg=0;rg<4;rg++){
      ah[rg] = *(const bf16x8*)(xh + aoff[rg] + k0);
      al[rg] = *(const bf16x8*)(xl + aoff[rg] + k0);
    }
    #pragma unroll
    for(int tt=0;tt<4;tt++){
      bh[tt] = *(const bf16x8*)(wph + (size_t)tt*16*FIN + k0);
      bl[tt] = *(const bf16x8*)(wpl + (size_t)tt*16*FIN + k0);
    }
    #pragma unroll
    for(int rg=0;rg<4;rg++){
      #pragma unroll
      for(int tt=0;tt<4;tt++){
        acc[rg][tt] = __builtin_amdgcn_mfma_f32_16x16x32_bf16(ah[rg], bh[tt], acc[rg][tt], 0, 0, 0);
        acc[rg][tt] = __builtin_amdgcn_mfma_f32_16x16x32_bf16(al[rg], bh[tt], acc[rg][tt], 0, 0, 0);
        acc[rg][tt] = __builtin_amdgcn_mfma_f32_16x16x32_bf16(ah[rg], bl[tt], acc[rg][tt], 0, 0, 0);
      }
    }
  }
  #pragma unroll
  for(int rg=0;rg<4;rg++){
    #pragma unroll
    for(int tt=0;tt<4;tt++){
      #pragma unroll
      for(int r=0;r<4;r++){
        int row = rowbase + rg*16 + hi*4 + r;
        if(row < NN) h1b[(size_t)row*F1 + w*64 + tt*16 + lo] = f2bf(acc[rg][tt][r]);
      }
    }
  }
  float ps[4][4], pd[4][4];              // [rg][r]
  #pragma unroll
  for(int rg=0;rg<4;rg++)
    #pragma unroll
    for(int r=0;r<4;r++){ ps[rg][r]=0.f; pd[rg][r]=0.f; }
  #pragma unroll
  for(int tt=0;tt<4;tt++){
    float sv = as1[w*64+tt*16+lo]*LOG2E, dv = ad1[w*64+tt*16+lo]*LOG2E;
    #pragma unroll
    for(int rg=0;rg<4;rg++)
      #pragma unroll
      for(int r=0;r<4;r++){ ps[rg][r] += acc[rg][tt][r]*sv; pd[rg][r] += acc[rg][tt][r]*dv; }
  }
  #pragma unroll
  for(int off=1; off<16; off<<=1){
    #pragma unroll
    for(int rg=0;rg<4;rg++)
      #pragma unroll
      for(int r=0;r<4;r++){
        ps[rg][r] += __shfl_xor(ps[rg][r], off, 64);
        pd[rg][r] += __shfl_xor(pd[rg][r], off, 64);
      }
  }
  if(lo == 0){
    #pragma unroll
    for(int rg=0;rg<4;rg++)
      #pragma unroll
      for(int r=0;r<4;r++){
        int row = rowbase + rg*16 + hi*4 + r;
        if(row < NN){ aS[row*HEADS+w] = ps[rg][r]; aD[row*HEADS+w] = pd[rg][r]; }
      }
  }
}

// ---- per-bucket scatter into contiguous adj window; computes own global base
//      from bsum prefix (k_scanb deleted); materializes final rowptr
__global__ __launch_bounds__(256) void k_fill2(const int* __restrict__ cnt, const u32* __restrict__ bin,
                                               const int* __restrict__ rloc, const int* __restrict__ bsum,
                                               int* __restrict__ rowptr, int* __restrict__ adj){
  __shared__ int cur[512];
  __shared__ int sb[NB2];
  __shared__ int base_s;
  int b = blockIdx.x, tid = threadIdx.x;
  if(tid < NB2) sb[tid] = bsum[tid];
  __syncthreads();
  if(tid == 0){
    int run = 0;
    for(int i=0;i<b;i++) run += sb[i];
    base_s = run;
    if(b == NB2-1) rowptr[NN] = run + sb[b];
  }
  __syncthreads();
  int base = base_s;
  for(int i=tid;i<512;i+=256){
    int d = b*512 + i;
    int v = base + rloc[b*512+i];
    cur[i] = v;
    if(d < NN) rowptr[d] = v;
  }
  __syncthreads();
  int n = min(cnt[b], BCAP2);
  const u32* bp = bin + (size_t)b*BCAP2;
  for(int i=tid;i<n;i+=256){
    u32 v = bp[i];
    int p = atomicAdd(&cur[(v>>16)&511], 1);
    adj[p] = (int)(v & 0xffffu);
  }
}

// ---- layer-1 aggregation + bias + BN + ELU -> h2 (f32), one wave per node.
__global__ __launch_bounds__(256) void k_agg1(const u16* __restrict__ h1b,
  const float* __restrict__ aS, const float* __restrict__ aD,
  const int* __restrict__ rowptr, const int* __restrict__ adj,
  const float* __restrict__ b1, const float* __restrict__ g1, const float* __restrict__ be1,
  const float* __restrict__ mn1, const float* __restrict__ vr1,
  float* __restrict__ h2){
  __shared__ float lw[4][CHUNK*4];   // [wave][i*4+head]
  __shared__ int   lsrc[4][CHUNK];
  int w = threadIdx.x >> 6, lane = threadIdx.x & 63;
  int node = blockIdx.x*4 + w;
  int g = lane >> 5, li = lane & 31;
  int hb = li >> 3;                  // head of this lane's 8-channel block
  int beg = rowptr[node], end = rowptr[node+1];
  float4 ad4 = *(const float4*)&aD[node*HEADS];
  float den[4] = {0.f,0.f,0.f,0.f};
  float acc[8] = {0.f,0.f,0.f,0.f,0.f,0.f,0.f,0.f};
  int total = end - beg + 1;                  // + self loop
  for(int c0=0; c0<total; c0+=CHUNK){
    int n = min(CHUNK, total - c0);
    for(int i=lane; i<n; i+=64){
      int e = beg + c0 + i;
      int src = (e < end) ? adj[e] : node;
      float4 s4 = *(const float4*)&aS[src*HEADS];
      float w0 = s4.x + ad4.x; w0 = w0>0.f?w0:SLOPE*w0; w0 = exp2f(fminf(w0,110.f));
      float w1 = s4.y + ad4.y; w1 = w1>0.f?w1:SLOPE*w1; w1 = exp2f(fminf(w1,110.f));
      float w2 = s4.z + ad4.z; w2 = w2>0.f?w2:SLOPE*w2; w2 = exp2f(fminf(w2,110.f));
      float w3 = s4.w + ad4.w; w3 = w3>0.f?w3:SLOPE*w3; w3 = exp2f(fminf(w3,110.f));
      lsrc[w][i] = src;
      *(float4*)&lw[w][i*4] = make_float4(w0,w1,w2,w3);
      den[0]+=w0; den[1]+=w1; den[2]+=w2; den[3]+=w3;
    }
    asm volatile("s_waitcnt lgkmcnt(0)" ::: "memory");
    #pragma unroll 2
    for(int i=0; i<n; i+=2){
      int e = i + g;
      bool ok = e < n;
      int src = ok ? lsrc[w][e] : node;
      float wg = ok ? lw[w][e*4 + hb] : 0.f;
      uint4 pv = *(const uint4*)&h1b[(size_t)src*F1 + li*8];
      acc[0] += wg*__uint_as_float(pv.x << 16);  acc[1] += wg*__uint_as_float(pv.x & 0xffff0000u);
      acc[2] += wg*__uint_as_float(pv.y << 16);  acc[3] += wg*__uint_as_float(pv.y & 0xffff0000u);
      acc[4] += wg*__uint_as_float(pv.z << 16);  acc[5] += wg*__uint_as_float(pv.z & 0xffff0000u);
      acc[6] += wg*__uint_as_float(pv.w << 16);  acc[7] += wg*__uint_as_float(pv.w & 0xffff0000u);
    }
  }
  #pragma unroll
  for(int off=1; off<64; off<<=1){
    #pragma unroll
    for(int q=0;q<4;q++) den[q] += __shfl_xor(den[q], off, 64);
  }
  #pragma unroll
  for(int k=0;k<8;k++) acc[k] += __shfl_xor(acc[k], 32, 64);
  if(lane < 32){
    float dsel = hb==0 ? den[0] : (hb==1 ? den[1] : (hb==2 ? den[2] : den[3]));
    float inv = 1.f/(dsel + 1e-16f);
    int c = li*8;
    float o[8];
    #pragma unroll
    for(int j=0;j<8;j++){
      float v = acc[j]*inv + b1[c+j];
      v = (v - mn1[c+j]) * rsqrtf(vr1[c+j] + 1e-5f) * g1[c+j] + be1[c+j];
      o[j] = v > 0.f ? v : (__expf(v) - 1.f);   // ELU
    }
    *(float4*)&h2[(size_t)node*F1 + c]     = make_float4(o[0],o[1],o[2],o[3]);
    *(float4*)&h2[(size_t)node*F1 + c + 4] = make_float4(o[4],o[5],o[6],o[7]);
  }
}

// ---- GEMM2 (MFMA bf16x3, on-the-fly h2 split) + fused attention dots layer 2.
// h2p stored bf16 (halves agg2's gather; 4MB -> L2-resident).
__global__ __launch_bounds__(256) void k_gemm2(const float* __restrict__ h2,
    const short* __restrict__ w2h, const short* __restrict__ w2l,
    const float* __restrict__ as2, const float* __restrict__ ad2,
    u16* __restrict__ h2p, float* __restrict__ aS2, float* __restrict__ aD2){
  int w = threadIdx.x >> 6, lane = threadIdx.x & 63;
  int lo = lane & 15, hi = lane >> 4;
  int rowbase = blockIdx.x*64 + w*16;
  int arow = rowbase + lo; if(arow >= NN) arow = NN-1;
  f32x4 acc[3];
  #pragma unroll
  for(int tt=0;tt<3;tt++) acc[tt] = (f32x4){0.f,0.f,0.f,0.f};
  const float* xp = h2 + (size_t)arow*F1 + 8*hi;
  const short* bph = w2h + (size_t)lo*F1 + 8*hi;
  const short* bpl = w2l + (size_t)lo*F1 + 8*hi;
  for(int k0=0; k0<F1; k0+=32){
    float4 va = *(const float4*)(xp + k0);
    float4 vb = *(const float4*)(xp + k0 + 4);
    float v[8] = {va.x,va.y,va.z,va.w,vb.x,vb.y,vb.z,vb.w};
    bf16x8 ah, al;
    #pragma unroll
    for(int j=0;j<8;j++){
      u32 u = __float_as_uint(v[j]);
      ah[j] = (short)(u >> 16);
      float hf = __uint_as_float(u & 0xffff0000u);
      al[j] = (short)(__float_as_uint(v[j] - hf) >> 16);
    }
    #pragma unroll
    for(int tt=0;tt<3;tt++){
      bf16x8 bh = *(const bf16x8*)(bph + (size_t)tt*16*F1 + k0);
      bf16x8 bl = *(const bf16x8*)(bpl + (size_t)tt*16*F1 + k0);
      acc[tt] = __builtin_amdgcn_mfma_f32_16x16x32_bf16(ah, bh, acc[tt], 0, 0, 0);
      acc[tt] = __builtin_amdgcn_mfma_f32_16x16x32_bf16(al, bh, acc[tt], 0, 0, 0);
      acc[tt] = __builtin_amdgcn_mfma_f32_16x16x32_bf16(ah, bl, acc[tt], 0, 0, 0);
    }
  }
  float ps[4] = {0.f,0.f,0.f,0.f}, pd[4] = {0.f,0.f,0.f,0.f};
  #pragma unroll
  for(int tt=0;tt<3;tt++){
    int col = tt*16 + lo;
    float sv = (col < NC) ? as2[col]*LOG2E : 0.f;
    float dv = (col < NC) ? ad2[col]*LOG2E : 0.f;
    #pragma unroll
    for(int r=0;r<4;r++){
      int row = rowbase + hi*4 + r;
      if(row < NN && col < NC) h2p[(size_t)row*NC + col] = f2bf(acc[tt][r]);
      ps[r] += acc[tt][r]*sv; pd[r] += acc[tt][r]*dv;
    }
  }
  #pragma unroll
  for(int off=1; off<16; off<<=1){
    #pragma unroll
    for(int r=0;r<4;r++){ ps[r] += __shfl_xor(ps[r], off, 64); pd[r] += __shfl_xor(pd[r], off, 64); }
  }
  if(lo == 0){
    #pragma unroll
    for(int r=0;r<4;r++){
      int row = rowbase + hi*4 + r;
      if(row < NN){ aS2[row] = ps[r]; aD2[row] = pd[r]; }
    }
  }
}

// ---- layer-2 aggregation -> output (f32), bf16 h2p gather
__global__ __launch_bounds__(256) void k_agg2(const u16* __restrict__ h2p,
  const float* __restrict__ aS2, const float* __restrict__ aD2,
  const int* __restrict__ rowptr, const int* __restrict__ adj,
  const float* __restrict__ b2, float* __restrict__ out){
  __shared__ float lw[4][CHUNK];
  __shared__ int   lsrc[4][CHUNK];
  int w = threadIdx.x >> 6, lane = threadIdx.x & 63;
  int node = blockIdx.x*4 + w;
  int beg = rowptr[node], end = rowptr[node+1];
  float adv = aD2[node];
  float den = 0.f, acc = 0.f;
  int total = end - beg + 1;
  for(int c0=0; c0<total; c0+=CHUNK){
    int n = min(CHUNK, total - c0);
    for(int i=lane; i<n; i+=64){
      int e = beg + c0 + i;
      int src = (e < end) ? adj[e] : node;
      float ev = aS2[src] + adv; ev = ev>0.f?ev:SLOPE*ev;
      float wg = exp2f(fminf(ev,110.f));
      lsrc[w][i] = src;
      lw[w][i] = wg;
      den += wg;
    }
    asm volatile("s_waitcnt lgkmcnt(0)" ::: "memory");
    #pragma unroll 2
    for(int i=0;i<n;i++){
      int s = lsrc[w][i];
      float wg = lw[w][i];
      if(lane < NC) acc += wg * us2f(h2p[(size_t)s*NC + lane]);
    }
  }
  #pragma unroll
  for(int off=1; off<64; off<<=1) den += __shfl_xor(den, off, 64);
  if(lane < NC) out[(size_t)node*NC + lane] = acc/(den + 1e-16f) + b2[lane];
}

extern "C" void kernel_launch(void* const* d_in, const int* in_sizes, int n_in,
                              void* d_out, int out_size, void* d_ws, size_t ws_size,
                              hipStream_t stream){
  (void)in_sizes; (void)n_in; (void)out_size; (void)ws_size;
  const float* x   = (const float*)d_in[0];
  const int*   ei  = (const int*)d_in[1];
  const float* W1  = (const float*)d_in[2];
  const float* as1 = (const float*)d_in[3];
  const float* ad1 = (const float*)d_in[4];
  const float* b1  = (const float*)d_in[5];
  const float* g1  = (const float*)d_in[6];
  const float* be1 = (const float*)d_in[7];
  const float* mn1 = (const float*)d_in[8];
  const float* vr1 = (const float*)d_in[9];
  const float* W2  = (const float*)d_in[10];
  const float* as2 = (const float*)d_in[11];
  const float* ad2 = (const float*)d_in[12];
  const float* b2  = (const float*)d_in[13];

  char* ws = (char*)d_ws;
  u16*  h1b    = (u16*) (ws + 0);             // 25,600,000 (bf16 h1)
  float* h2    = (float*)(ws + 25600000);     // 51,200,000
  // xh/xl alias h2 (dead once k_g1h completes; h2 written later by k_agg1)
  u16*  xh     = (u16*) (ws + 25600000);      // 25,600,000
  u16*  xl     = (u16*) (ws + 51200000);      // 25,600,000
  // w1h/w1l alias h2p (dead before k_gemm2 writes h2p)
  u16*  h2p    = (u16*) (ws + 76800000);      //  4,000,000 (bf16)
  u16*  w1h    = (u16*) (ws + 76800000);      //    131,072
  u16*  w1l    = (u16*) (ws + 76931072);      //    131,072
  float* aS1   = (float*)(ws + 84800000);     //    800,000
  float* aD1   = (float*)(ws + 85600000);     //    800,000
  float* aS2   = (float*)(ws + 86400000);     //    200,000
  float* aD2   = (float*)(ws + 86600000);     //    200,000
  int*  rowptr = (int*)  (ws + 86800000);     //    200,016
  int*  adj    = (int*)  (ws + 87200016);     //  6,400,000
  u32*  bin    = (u32*)  (ws + 93700000);     //  7,056,000 (98*18000*4)
  int*  cnt    = (int*)  (ws + 100800000);    //        392 (98*4)
  int*  rloc   = (int*)  (ws + 100801024);    //    200,704 (98*512*4)
  int*  bsum   = (int*)  (ws + 101002240);    //        392
  u16*  w2h    = (u16*)  (ws + 101003712);    //     24,576 (48*256*2)
  u16*  w2l    = (u16*)  (ws + 101028288);    //     24,576

  hipMemsetAsync(cnt, 0, NB2*sizeof(int), stream);
  k_prep  <<<7336, 256, 0, stream>>>(ei, cnt, bin, x, xh, xl, W1, w1h, w1l, W2, w2h, w2l);
  k_g1h   <<<NG1 + NB2, 256, 0, stream>>>((const short*)xh, (const short*)xl,
                                          (const short*)w1h, (const short*)w1l,
                                          as1, ad1, h1b, aS1, aD1,
                                          cnt, bin, rloc, bsum);
  k_fill2 <<<NB2, 256, 0, stream>>>(cnt, bin, rloc, bsum, rowptr, adj);
  k_agg1  <<<NN/4, 256, 0, stream>>>(h1b, aS1, aD1, rowptr, adj, b1, g1, be1, mn1, vr1, h2);
  k_gemm2 <<<(NN+63)/64, 256, 0, stream>>>(h2, (const short*)w2h, (const short*)w2l,
                                           as2, ad2, h2p, aS2, aD2);
  k_agg2  <<<NN/4, 256, 0, stream>>>(h2p, aS2, aD2, rowptr, adj, b2, (float*)d_out);
}

// Round 16
// 349.426 us; speedup vs baseline: 1.1728x; 1.0673x over previous
//
#include <hip/hip_runtime.h>
#include <hip/hip_bf16.h>

#define NN 50000
#define FIN 256
#define F1 256      // HEADS*HID
#define HEADS 4
#define HID 64
#define NC 40
#define NE 1600000
#define SLOPE 0.2f
#define LOG2E 1.44269504f
#define CHUNK 128
#define NB2 98      // coarse dst buckets (512 nodes each)
#define BSH 9
#define BCAP2 18000 // per-bucket capacity (mean 16327, +13 sigma)
#define TILE 2048   // edges per bin block
#define NBIN 782    // bin blocks (782*2048 >= NE)
#define NG1 782     // gemm1 blocks: 391 row-tiles x 2 col-tiles
#define G1PAD 40    // LDS row pitch in u16 (32 + 8 pad; 80B, 16B-aligned, 2-way max)

typedef unsigned int u32;
typedef unsigned short u16;
typedef unsigned char u8;
typedef __attribute__((ext_vector_type(8))) short bf16x8;
typedef __attribute__((ext_vector_type(4))) float f32x4;

__device__ __forceinline__ float us2f(u32 u){ u32 b = u << 16; return __uint_as_float(b); }
__device__ __forceinline__ u16 f2bf(float f){
  u32 b = __float_as_uint(f);
  u32 r = (b + 0x7fffu + ((b >> 16) & 1u)) >> 16;
  return (u16)r;
}

// ---- fused prep: edge binning (blocks 0..781) + x split (782..7031)
//      + W1 transpose/split (7032..7287) + W2 transpose/split (7288..7335)
__global__ __launch_bounds__(256) void k_prep(const int* __restrict__ ei,
      int* __restrict__ cnt, u32* __restrict__ bin,
      const float* __restrict__ x, u16* __restrict__ xh, u16* __restrict__ xl,
      const float* __restrict__ W1, u16* __restrict__ w1h, u16* __restrict__ w1l,
      const float* __restrict__ W2, u16* __restrict__ w2h, u16* __restrict__ w2l){
  __shared__ int hcnt[NB2], hoff[NB2], gbase[NB2], hcur[NB2];
  __shared__ u32 staged[TILE];
  __shared__ u8  sbk[TILE];
  __shared__ int ci;
  int bid = blockIdx.x, tid = threadIdx.x;
  if(bid < NBIN){
    int e0 = bid * TILE;
    int nn = min(TILE, NE - e0);
    if(tid==0) ci = 0;
    for(int b=tid;b<NB2;b+=256) hcnt[b] = 0;
    __syncthreads();
    if(ei[2*(e0+tid)+1] != 0) atomicAdd(&ci, 1);   // int64: odd words all 0
    __syncthreads();
    int i64 = (ci == 0);
    u32 val[TILE/256]; int bk[TILE/256];
    #pragma unroll
    for(int j=0;j<TILE/256;j++){
      int t = tid + j*256;
      if(t < nn){
        int i = e0 + t;
        int src = i64 ? ei[2*i] : ei[i];
        int dst = i64 ? ei[2*(NE+i)] : ei[NE+i];
        bk[j] = dst >> BSH;
        val[j] = (u32)src | ((u32)(dst & 511) << 16);
        atomicAdd(&hcnt[bk[j]], 1);
      } else bk[j] = -1;
    }
    __syncthreads();
    if(tid == 0){
      int run = 0;
      for(int b=0;b<NB2;b++){ hoff[b] = run; hcur[b] = run; run += hcnt[b]; }
    }
    __syncthreads();
    if(tid < NB2 && hcnt[tid] > 0) gbase[tid] = atomicAdd(&cnt[tid], hcnt[tid]);
    __syncthreads();
    #pragma unroll
    for(int j=0;j<TILE/256;j++){
      if(bk[j] >= 0){
        int pos = atomicAdd(&hcur[bk[j]], 1);
        staged[pos] = val[j];
        sbk[pos] = (u8)bk[j];
      }
    }
    __syncthreads();
    for(int s=tid; s<nn; s+=256){
      int b = sbk[s];
      int local = gbase[b] + (s - hoff[b]);
      if(local < BCAP2) bin[(size_t)b*BCAP2 + local] = staged[s];
    }
  } else if(bid < 7032){
    int i = ((bid-NBIN)*256 + tid) * 8;
    float4 a = *(const float4*)(x+i);
    float4 b4 = *(const float4*)(x+i+4);
    float v[8] = {a.x,a.y,a.z,a.w,b4.x,b4.y,b4.z,b4.w};
    u16 hi[8], lo[8];
    #pragma unroll
    for(int j=0;j<8;j++){
      u32 u = __float_as_uint(v[j]);
      hi[j] = (u16)(u >> 16);                      // truncate hi
      float hf = __uint_as_float(u & 0xffff0000u);
      lo[j] = (u16)(__float_as_uint(v[j] - hf) >> 16);
    }
    *(ushort4*)&xh[i]   = make_ushort4(hi[0],hi[1],hi[2],hi[3]);
    *(ushort4*)&xh[i+4] = make_ushort4(hi[4],hi[5],hi[6],hi[7]);
    *(ushort4*)&xl[i]   = make_ushort4(lo[0],lo[1],lo[2],lo[3]);
    *(ushort4*)&xl[i+4] = make_ushort4(lo[4],lo[5],lo[6],lo[7]);
  } else if(bid < 7288){
    int id = (bid-7032)*256 + tid;               // 65536 total
    int n = id & 255, k = id >> 8;
    float v = W1[k*F1 + n];
    u16 h = f2bf(v);
    w1h[n*FIN + k] = h;
    w1l[n*FIN + k] = f2bf(v - us2f(h));
  } else {
    int id = (bid-7288)*256 + tid;               // 12288 total: col 0..47, k 0..255
    int col = id >> 8, k = id & 255;
    float v = (col < NC) ? W2[k*NC + col] : 0.f;
    u16 h = f2bf(v);
    w2h[col*F1 + k] = h;
    w2l[col*F1 + k] = f2bf(v - us2f(h));
  }
}

// ---- fused GEMM1 (blocks 0..781; 128x128 tile, LDS-staged) + histogram (782..879)
__global__ __launch_bounds__(256) void k_g1h(const short* __restrict__ xh, const short* __restrict__ xl,
                                             const short* __restrict__ wh, const short* __restrict__ wl,
                                             const float* __restrict__ as1, const float* __restrict__ ad1,
                                             u16* __restrict__ h1b,
                                             float* __restrict__ aS, float* __restrict__ aD,
                                             const int* __restrict__ cnt, const u32* __restrict__ bin,
                                             int* __restrict__ rloc, int* __restrict__ bsum){
  __shared__ char smem[4*128*G1PAD*2];   // 40,960 B
  int tid = threadIdx.x;
  if(blockIdx.x >= NG1){
    // ---- histogram + 512-entry LDS exclusive scan for bucket b
    int* dl = (int*)smem; int* s1 = dl + 512; int* s2 = s1 + 512;
    int b = blockIdx.x - NG1;
    for(int i=tid;i<512;i+=256) dl[i] = 0;
    __syncthreads();
    int n = min(cnt[b], BCAP2);
    const u32* bp = bin + (size_t)b*BCAP2;
    for(int i=tid;i<n;i+=256) atomicAdd(&dl[(bp[i]>>16)&511], 1);
    __syncthreads();
    for(int i=tid;i<512;i+=256) s1[i] = dl[i];
    __syncthreads();
    int* src = s1; int* dst = s2;
    for(int off=1; off<512; off<<=1){
      for(int i=tid;i<512;i+=256) dst[i] = src[i] + (i>=off ? src[i-off] : 0);
      __syncthreads();
      int* t = src; src = dst; dst = t;
    }
    for(int i=tid;i<512;i+=256) rloc[b*512+i] = src[i] - dl[i];
    if(tid==0) bsum[b] = src[511];
    return;
  }
  // ---- GEMM1: block = 128 rows x 128 cols; wave = 64x64 quadrant
  u16* Ah = (u16*)smem;
  u16* Al = Ah + 128*G1PAD;
  u16* Bh = Al + 128*G1PAD;
  u16* Bl = Bh + 128*G1PAD;
  int w = tid >> 6, lane = tid & 63;
  int lo = lane & 15, hi = lane >> 4;
  int bidm = blockIdx.x >> 1, bidn = blockIdx.x & 1;
  int rowbase = bidm*128, colbase = bidn*128;
  int wr = w >> 1, wc = w & 1;
  // staging assignment: thread stages rows r0 and r0+64, chunk ch (8 bf16) of all 4 arrays
  int r0 = tid >> 2, ch = tid & 3;
  int arow0 = rowbase + r0;      if(arow0 >= NN) arow0 = NN-1;
  int arow1 = rowbase + r0 + 64; if(arow1 >= NN) arow1 = NN-1;
  const short* pA0h = xh + (size_t)arow0*FIN + ch*8;
  const short* pA1h = xh + (size_t)arow1*FIN + ch*8;
  const short* pA0l = xl + (size_t)arow0*FIN + ch*8;
  const short* pA1l = xl + (size_t)arow1*FIN + ch*8;
  const short* pB0h = wh + (size_t)(colbase + r0)*FIN + ch*8;
  const short* pB1h = wh + (size_t)(colbase + r0 + 64)*FIN + ch*8;
  const short* pB0l = wl + (size_t)(colbase + r0)*FIN + ch*8;
  const short* pB1l = wl + (size_t)(colbase + r0 + 64)*FIN + ch*8;
  int so0 = r0*G1PAD + ch*8, so1 = (r0+64)*G1PAD + ch*8;
  f32x4 acc[4][4];                       // [rg][tt]
  #pragma unroll
  for(int rg=0;rg<4;rg++)
    #pragma unroll
    for(int tt=0;tt<4;tt++) acc[rg][tt] = (f32x4){0.f,0.f,0.f,0.f};
  for(int k0=0; k0<FIN; k0+=32){
    // issue global loads early (independent of LDS state)
    bf16x8 va0 = *(const bf16x8*)(pA0h + k0);
    bf16x8 va1 = *(const bf16x8*)(pA1h + k0);
    bf16x8 va2 = *(const bf16x8*)(pA0l + k0);
    bf16x8 va3 = *(const bf16x8*)(pA1l + k0);
    bf16x8 vb0 = *(const bf16x8*)(pB0h + k0);
    bf16x8 vb1 = *(const bf16x8*)(pB1h + k0);
    bf16x8 vb2 = *(const bf16x8*)(pB0l + k0);
    bf16x8 vb3 = *(const bf16x8*)(pB1l + k0);
    __syncthreads();                      // previous iter's reads complete
    *(bf16x8*)&Ah[so0] = va0; *(bf16x8*)&Ah[so1] = va1;
    *(bf16x8*)&Al[so0] = va2; *(bf16x8*)&Al[so1] = va3;
    *(bf16x8*)&Bh[so0] = vb0; *(bf16x8*)&Bh[so1] = vb1;
    *(bf16x8*)&Bl[so0] = vb2; *(bf16x8*)&Bl[so1] = vb3;
    __syncthreads();                      // staging visible
    bf16x8 ah[4], al[4];
    #pragma unroll
    for(int rg=0;rg<4;rg++){
      int ar = wr*64 + rg*16 + lo;
      ah[rg] = *(const bf16x8*)&Ah[ar*G1PAD + hi*8];
      al[rg] = *(const bf16x8*)&Al[ar*G1PAD + hi*8];
    }
    #pragma unroll
    for(int tt=0;tt<4;tt++){
      int bc = wc*64 + tt*16 + lo;
      bf16x8 bh = *(const bf16x8*)&Bh[bc*G1PAD + hi*8];
      bf16x8 bl = *(const bf16x8*)&Bl[bc*G1PAD + hi*8];
      #pragma unroll
      for(int rg=0;rg<4;rg++){
        acc[rg][tt] = __builtin_amdgcn_mfma_f32_16x16x32_bf16(ah[rg], bh, acc[rg][tt], 0, 0, 0);
        acc[rg][tt] = __builtin_amdgcn_mfma_f32_16x16x32_bf16(al[rg], bh, acc[rg][tt], 0, 0, 0);
        acc[rg][tt] = __builtin_amdgcn_mfma_f32_16x16x32_bf16(ah[rg], bl, acc[rg][tt], 0, 0, 0);
      }
    }
  }
  // h1b store: row = rowbase + wr*64 + rg*16 + hi*4 + r; col = colbase + wc*64 + tt*16 + lo
  #pragma unroll
  for(int rg=0;rg<4;rg++){
    #pragma unroll
    for(int tt=0;tt<4;tt++){
      #pragma unroll
      for(int r=0;r<4;r++){
        int row = rowbase + wr*64 + rg*16 + hi*4 + r;
        if(row < NN) h1b[(size_t)row*F1 + colbase + wc*64 + tt*16 + lo] = f2bf(acc[rg][tt][r]);
      }
    }
  }
  // fused attention dots for head (colbase+wc*64)/64 (prescaled by log2 e)
  int head = bidn*2 + wc;
  float ps[4][4], pd[4][4];              // [rg][r]
  #pragma unroll
  for(int rg=0;rg<4;rg++)
    #pragma unroll
    for(int r=0;r<4;r++){ ps[rg][r]=0.f; pd[rg][r]=0.f; }
  #pragma unroll
  for(int tt=0;tt<4;tt++){
    int col = colbase + wc*64 + tt*16 + lo;
    float sv = as1[col]*LOG2E, dv = ad1[col]*LOG2E;
    #pragma unroll
    for(int rg=0;rg<4;rg++)
      #pragma unroll
      for(int r=0;r<4;r++){ ps[rg][r] += acc[rg][tt][r]*sv; pd[rg][r] += acc[rg][tt][r]*dv; }
  }
  #pragma unroll
  for(int off=1; off<16; off<<=1){
    #pragma unroll
    for(int rg=0;rg<4;rg++)
      #pragma unroll
      for(int r=0;r<4;r++){
        ps[rg][r] += __shfl_xor(ps[rg][r], off, 64);
        pd[rg][r] += __shfl_xor(pd[rg][r], off, 64);
      }
  }
  if(lo == 0){
    #pragma unroll
    for(int rg=0;rg<4;rg++)
      #pragma unroll
      for(int r=0;r<4;r++){
        int row = rowbase + wr*64 + rg*16 + hi*4 + r;
        if(row < NN){ aS[row*HEADS+head] = ps[rg][r]; aD[row*HEADS+head] = pd[rg][r]; }
      }
  }
}

// ---- per-bucket scatter into contiguous adj window; computes own global base
__global__ __launch_bounds__(256) void k_fill2(const int* __restrict__ cnt, const u32* __restrict__ bin,
                                               const int* __restrict__ rloc, const int* __restrict__ bsum,
                                               int* __restrict__ rowptr, int* __restrict__ adj){
  __shared__ int cur[512];
  __shared__ int sb[NB2];
  __shared__ int base_s;
  int b = blockIdx.x, tid = threadIdx.x;
  if(tid < NB2) sb[tid] = bsum[tid];
  __syncthreads();
  if(tid == 0){
    int run = 0;
    for(int i=0;i<b;i++) run += sb[i];
    base_s = run;
    if(b == NB2-1) rowptr[NN] = run + sb[b];
  }
  __syncthreads();
  int base = base_s;
  for(int i=tid;i<512;i+=256){
    int d = b*512 + i;
    int v = base + rloc[b*512+i];
    cur[i] = v;
    if(d < NN) rowptr[d] = v;
  }
  __syncthreads();
  int n = min(cnt[b], BCAP2);
  const u32* bp = bin + (size_t)b*BCAP2;
  for(int i=tid;i<n;i+=256){
    u32 v = bp[i];
    int p = atomicAdd(&cur[(v>>16)&511], 1);
    adj[p] = (int)(v & 0xffffu);
  }
}

// ---- layer-1 aggregation + bias + BN + ELU -> h2 (f32), one wave per node.
__global__ __launch_bounds__(256) void k_agg1(const u16* __restrict__ h1b,
  const float* __restrict__ aS, const float* __restrict__ aD,
  const int* __restrict__ rowptr, const int* __restrict__ adj,
  const float* __restrict__ b1, const float* __restrict__ g1, const float* __restrict__ be1,
  const float* __restrict__ mn1, const float* __restrict__ vr1,
  float* __restrict__ h2){
  __shared__ float lw[4][CHUNK*4];   // [wave][i*4+head]
  __shared__ int   lsrc[4][CHUNK];
  int w = threadIdx.x >> 6, lane = threadIdx.x & 63;
  int node = blockIdx.x*4 + w;
  int g = lane >> 5, li = lane & 31;
  int hb = li >> 3;                  // head of this lane's 8-channel block
  int beg = rowptr[node], end = rowptr[node+1];
  float4 ad4 = *(const float4*)&aD[node*HEADS];
  float den[4] = {0.f,0.f,0.f,0.f};
  float acc[8] = {0.f,0.f,0.f,0.f,0.f,0.f,0.f,0.f};
  int total = end - beg + 1;                  // + self loop
  for(int c0=0; c0<total; c0+=CHUNK){
    int n = min(CHUNK, total - c0);
    for(int i=lane; i<n; i+=64){
      int e = beg + c0 + i;
      int src = (e < end) ? adj[e] : node;
      float4 s4 = *(const float4*)&aS[src*HEADS];
      float w0 = s4.x + ad4.x; w0 = w0>0.f?w0:SLOPE*w0; w0 = exp2f(fminf(w0,110.f));
      float w1 = s4.y + ad4.y; w1 = w1>0.f?w1:SLOPE*w1; w1 = exp2f(fminf(w1,110.f));
      float w2 = s4.z + ad4.z; w2 = w2>0.f?w2:SLOPE*w2; w2 = exp2f(fminf(w2,110.f));
      float w3 = s4.w + ad4.w; w3 = w3>0.f?w3:SLOPE*w3; w3 = exp2f(fminf(w3,110.f));
      lsrc[w][i] = src;
      *(float4*)&lw[w][i*4] = make_float4(w0,w1,w2,w3);
      den[0]+=w0; den[1]+=w1; den[2]+=w2; den[3]+=w3;
    }
    asm volatile("s_waitcnt lgkmcnt(0)" ::: "memory");
    #pragma unroll 2
    for(int i=0; i<n; i+=2){
      int e = i + g;
      bool ok = e < n;
      int src = ok ? lsrc[w][e] : node;
      float wg = ok ? lw[w][e*4 + hb] : 0.f;
      uint4 pv = *(const uint4*)&h1b[(size_t)src*F1 + li*8];
      acc[0] += wg*__uint_as_float(pv.x << 16);  acc[1] += wg*__uint_as_float(pv.x & 0xffff0000u);
      acc[2] += wg*__uint_as_float(pv.y << 16);  acc[3] += wg*__uint_as_float(pv.y & 0xffff0000u);
      acc[4] += wg*__uint_as_float(pv.z << 16);  acc[5] += wg*__uint_as_float(pv.z & 0xffff0000u);
      acc[6] += wg*__uint_as_float(pv.w << 16);  acc[7] += wg*__uint_as_float(pv.w & 0xffff0000u);
    }
  }
  #pragma unroll
  for(int off=1; off<64; off<<=1){
    #pragma unroll
    for(int q=0;q<4;q++) den[q] += __shfl_xor(den[q], off, 64);
  }
  #pragma unroll
  for(int k=0;k<8;k++) acc[k] += __shfl_xor(acc[k], 32, 64);
  if(lane < 32){
    float dsel = hb==0 ? den[0] : (hb==1 ? den[1] : (hb==2 ? den[2] : den[3]));
    float inv = 1.f/(dsel + 1e-16f);
    int c = li*8;
    float o[8];
    #pragma unroll
    for(int j=0;j<8;j++){
      float v = acc[j]*inv + b1[c+j];
      v = (v - mn1[c+j]) * rsqrtf(vr1[c+j] + 1e-5f) * g1[c+j] + be1[c+j];
      o[j] = v > 0.f ? v : (__expf(v) - 1.f);   // ELU
    }
    *(float4*)&h2[(size_t)node*F1 + c]     = make_float4(o[0],o[1],o[2],o[3]);
    *(float4*)&h2[(size_t)node*F1 + c + 4] = make_float4(o[4],o[5],o[6],o[7]);
  }
}

// ---- GEMM2 (MFMA bf16x3, on-the-fly h2 split) + fused attention dots layer 2.
__global__ __launch_bounds__(256) void k_gemm2(const float* __restrict__ h2,
    const short* __restrict__ w2h, const short* __restrict__ w2l,
    const float* __restrict__ as2, const float* __restrict__ ad2,
    u16* __restrict__ h2p, float* __restrict__ aS2, float* __restrict__ aD2){
  int w = threadIdx.x >> 6, lane = threadIdx.x & 63;
  int lo = lane & 15, hi = lane >> 4;
  int rowbase = blockIdx.x*64 + w*16;
  int arow = rowbase + lo; if(arow >= NN) arow = NN-1;
  f32x4 acc[3];
  #pragma unroll
  for(int tt=0;tt<3;tt++) acc[tt] = (f32x4){0.f,0.f,0.f,0.f};
  const float* xp = h2 + (size_t)arow*F1 + 8*hi;
  const short* bph = w2h + (size_t)lo*F1 + 8*hi;
  const short* bpl = w2l + (size_t)lo*F1 + 8*hi;
  for(int k0=0; k0<F1; k0+=32){
    float4 va = *(const float4*)(xp + k0);
    float4 vb = *(const float4*)(xp + k0 + 4);
    float v[8] = {va.x,va.y,va.z,va.w,vb.x,vb.y,vb.z,vb.w};
    bf16x8 ah, al;
    #pragma unroll
    for(int j=0;j<8;j++){
      u32 u = __float_as_uint(v[j]);
      ah[j] = (short)(u >> 16);
      float hf = __uint_as_float(u & 0xffff0000u);
      al[j] = (short)(__float_as_uint(v[j] - hf) >> 16);
    }
    #pragma unroll
    for(int tt=0;tt<3;tt++){
      bf16x8 bh = *(const bf16x8*)(bph + (size_t)tt*16*F1 + k0);
      bf16x8 bl = *(const bf16x8*)(bpl + (size_t)tt*16*F1 + k0);
      acc[tt] = __builtin_amdgcn_mfma_f32_16x16x32_bf16(ah, bh, acc[tt], 0, 0, 0);
      acc[tt] = __builtin_amdgcn_mfma_f32_16x16x32_bf16(al, bh, acc[tt], 0, 0, 0);
      acc[tt] = __builtin_amdgcn_mfma_f32_16x16x32_bf16(ah, bl, acc[tt], 0, 0, 0);
    }
  }
  float ps[4] = {0.f,0.f,0.f,0.f}, pd[4] = {0.f,0.f,0.f,0.f};
  #pragma unroll
  for(int tt=0;tt<3;tt++){
    int col = tt*16 + lo;
    float sv = (col < NC) ? as2[col]*LOG2E : 0.f;
    float dv = (col < NC) ? ad2[col]*LOG2E : 0.f;
    #pragma unroll
    for(int r=0;r<4;r++){
      int row = rowbase + hi*4 + r;
      if(row < NN && col < NC) h2p[(size_t)row*NC + col] = f2bf(acc[tt][r]);
      ps[r] += acc[tt][r]*sv; pd[r] += acc[tt][r]*dv;
    }
  }
  #pragma unroll
  for(int off=1; off<16; off<<=1){
    #pragma unroll
    for(int r=0;r<4;r++){ ps[r] += __shfl_xor(ps[r], off, 64); pd[r] += __shfl_xor(pd[r], off, 64); }
  }
  if(lo == 0){
    #pragma unroll
    for(int r=0;r<4;r++){
      int row = rowbase + hi*4 + r;
      if(row < NN){ aS2[row] = ps[r]; aD2[row] = pd[r]; }
    }
  }
}

// ---- layer-2 aggregation -> output (f32), bf16 h2p gather
__global__ __launch_bounds__(256) void k_agg2(const u16* __restrict__ h2p,
  const float* __restrict__ aS2, const float* __restrict__ aD2,
  const int* __restrict__ rowptr, const int* __restrict__ adj,
  const float* __restrict__ b2, float* __restrict__ out){
  __shared__ float lw[4][CHUNK];
  __shared__ int   lsrc[4][CHUNK];
  int w = threadIdx.x >> 6, lane = threadIdx.x & 63;
  int node = blockIdx.x*4 + w;
  int beg = rowptr[node], end = rowptr[node+1];
  float adv = aD2[node];
  float den = 0.f, acc = 0.f;
  int total = end - beg + 1;
  for(int c0=0; c0<total; c0+=CHUNK){
    int n = min(CHUNK, total - c0);
    for(int i=lane; i<n; i+=64){
      int e = beg + c0 + i;
      int src = (e < end) ? adj[e] : node;
      float ev = aS2[src] + adv; ev = ev>0.f?ev:SLOPE*ev;
      float wg = exp2f(fminf(ev,110.f));
      lsrc[w][i] = src;
      lw[w][i] = wg;
      den += wg;
    }
    asm volatile("s_waitcnt lgkmcnt(0)" ::: "memory");
    #pragma unroll 2
    for(int i=0;i<n;i++){
      int s = lsrc[w][i];
      float wg = lw[w][i];
      if(lane < NC) acc += wg * us2f(h2p[(size_t)s*NC + lane]);
    }
  }
  #pragma unroll
  for(int off=1; off<64; off<<=1) den += __shfl_xor(den, off, 64);
  if(lane < NC) out[(size_t)node*NC + lane] = acc/(den + 1e-16f) + b2[lane];
}

extern "C" void kernel_launch(void* const* d_in, const int* in_sizes, int n_in,
                              void* d_out, int out_size, void* d_ws, size_t ws_size,
                              hipStream_t stream){
  (void)in_sizes; (void)n_in; (void)out_size; (void)ws_size;
  const float* x   = (const float*)d_in[0];
  const int*   ei  = (const int*)d_in[1];
  const float* W1  = (const float*)d_in[2];
  const float* as1 = (const float*)d_in[3];
  const float* ad1 = (const float*)d_in[4];
  const float* b1  = (const float*)d_in[5];
  const float* g1  = (const float*)d_in[6];
  const float* be1 = (const float*)d_in[7];
  const float* mn1 = (const float*)d_in[8];
  const float* vr1 = (const float*)d_in[9];
  const float* W2  = (const float*)d_in[10];
  const float* as2 = (const float*)d_in[11];
  const float* ad2 = (const float*)d_in[12];
  const float* b2  = (const float*)d_in[13];

  char* ws = (char*)d_ws;
  u16*  h1b    = (u16*) (ws + 0);             // 25,600,000 (bf16 h1)
  float* h2    = (float*)(ws + 25600000);     // 51,200,000
  // xh/xl alias h2 (dead once k_g1h completes; h2 written later by k_agg1)
  u16*  xh     = (u16*) (ws + 25600000);      // 25,600,000
  u16*  xl     = (u16*) (ws + 51200000);      // 25,600,000
  // w1h/w1l alias h2p (dead before k_gemm2 writes h2p)
  u16*  h2p    = (u16*) (ws + 76800000);      //  4,000,000 (bf16)
  u16*  w1h    = (u16*) (ws + 76800000);      //    131,072
  u16*  w1l    = (u16*) (ws + 76931072);      //    131,072
  float* aS1   = (float*)(ws + 84800000);     //    800,000
  float* aD1   = (float*)(ws + 85600000);     //    800,000
  float* aS2   = (float*)(ws + 86400000);     //    200,000
  float* aD2   = (float*)(ws + 86600000);     //    200,000
  int*  rowptr = (int*)  (ws + 86800000);     //    200,016
  int*  adj    = (int*)  (ws + 87200016);     //  6,400,000
  u32*  bin    = (u32*)  (ws + 93700000);     //  7,056,000 (98*18000*4)
  int*  cnt    = (int*)  (ws + 100800000);    //        392 (98*4)
  int*  rloc   = (int*)  (ws + 100801024);    //    200,704 (98*512*4)
  int*  bsum   = (int*)  (ws + 101002240);    //        392
  u16*  w2h    = (u16*)  (ws + 101003712);    //     24,576 (48*256*2)
  u16*  w2l    = (u16*)  (ws + 101028288);    //     24,576

  hipMemsetAsync(cnt, 0, NB2*sizeof(int), stream);
  k_prep  <<<7336, 256, 0, stream>>>(ei, cnt, bin, x, xh, xl, W1, w1h, w1l, W2, w2h, w2l);
  k_g1h   <<<NG1 + NB2, 256, 0, stream>>>((const short*)xh, (const short*)xl,
                                          (const short*)w1h, (const short*)w1l,
                                          as1, ad1, h1b, aS1, aD1,
                                          cnt, bin, rloc, bsum);
  k_fill2 <<<NB2, 256, 0, stream>>>(cnt, bin, rloc, bsum, rowptr, adj);
  k_agg1  <<<NN/4, 256, 0, stream>>>(h1b, aS1, aD1, rowptr, adj, b1, g1, be1, mn1, vr1, h2);
  k_gemm2 <<<(NN+63)/64, 256, 0, stream>>>(h2, (const short*)w2h, (const short*)w2l,
                                           as2, ad2, h2p, aS2, aD2);
  k_agg2  <<<NN/4, 256, 0, stream>>>(h2p, aS2, aD2, rowptr, adj, b2, (float*)d_out);
}

// Round 17
// 339.547 us; speedup vs baseline: 1.2069x; 1.0291x over previous
//
#include <hip/hip_runtime.h>
#include <hip/hip_bf16.h>

#define NN 50000
#define FIN 256
#define F1 256      // HEADS*HID
#define HEADS 4
#define HID 64
#define NC 40
#define NE 1600000
#define SLOPE 0.2f
#define LOG2E 1.44269504f
#define CHUNK 128
#define NB2 98      // coarse dst buckets (512 nodes each)
#define BSH 9
#define BCAP2 18000 // per-bucket capacity (mean 16327, +13 sigma)
#define TILE 2048   // edges per bin block
#define NBIN 782    // bin blocks (782*2048 >= NE)
#define NG1 782     // gemm1 blocks: 391 row-tiles x 2 col-tiles
#define G1PAD 40    // LDS row pitch in u16 (32 + 8 pad; 80B, 16B-aligned, 2-way max)

typedef unsigned int u32;
typedef unsigned short u16;
typedef unsigned char u8;
typedef __attribute__((ext_vector_type(8))) short bf16x8;
typedef __attribute__((ext_vector_type(4))) float f32x4;

__device__ __forceinline__ float us2f(u32 u){ u32 b = u << 16; return __uint_as_float(b); }
__device__ __forceinline__ u16 f2bf(float f){
  u32 b = __float_as_uint(f);
  u32 r = (b + 0x7fffu + ((b >> 16) & 1u)) >> 16;
  return (u16)r;
}

// ---- fused prep: edge binning (blocks 0..781) + W1 transpose/split (782..1037)
//      + W2 transpose/split (1038..1085).  [x hi/lo split moved into k_g1h]
__global__ __launch_bounds__(256) void k_prep(const int* __restrict__ ei,
      int* __restrict__ cnt, u32* __restrict__ bin,
      const float* __restrict__ W1, u16* __restrict__ w1h, u16* __restrict__ w1l,
      const float* __restrict__ W2, u16* __restrict__ w2h, u16* __restrict__ w2l){
  __shared__ int hcnt[NB2], hoff[NB2], gbase[NB2], hcur[NB2];
  __shared__ u32 staged[TILE];
  __shared__ u8  sbk[TILE];
  __shared__ int ci;
  int bid = blockIdx.x, tid = threadIdx.x;
  if(bid < NBIN){
    int e0 = bid * TILE;
    int nn = min(TILE, NE - e0);
    if(tid==0) ci = 0;
    for(int b=tid;b<NB2;b+=256) hcnt[b] = 0;
    __syncthreads();
    if(ei[2*(e0+tid)+1] != 0) atomicAdd(&ci, 1);   // int64: odd words all 0
    __syncthreads();
    int i64 = (ci == 0);
    u32 val[TILE/256]; int bk[TILE/256];
    #pragma unroll
    for(int j=0;j<TILE/256;j++){
      int t = tid + j*256;
      if(t < nn){
        int i = e0 + t;
        int src = i64 ? ei[2*i] : ei[i];
        int dst = i64 ? ei[2*(NE+i)] : ei[NE+i];
        bk[j] = dst >> BSH;
        val[j] = (u32)src | ((u32)(dst & 511) << 16);
        atomicAdd(&hcnt[bk[j]], 1);
      } else bk[j] = -1;
    }
    __syncthreads();
    if(tid == 0){
      int run = 0;
      for(int b=0;b<NB2;b++){ hoff[b] = run; hcur[b] = run; run += hcnt[b]; }
    }
    __syncthreads();
    if(tid < NB2 && hcnt[tid] > 0) gbase[tid] = atomicAdd(&cnt[tid], hcnt[tid]);
    __syncthreads();
    #pragma unroll
    for(int j=0;j<TILE/256;j++){
      if(bk[j] >= 0){
        int pos = atomicAdd(&hcur[bk[j]], 1);
        staged[pos] = val[j];
        sbk[pos] = (u8)bk[j];
      }
    }
    __syncthreads();
    for(int s=tid; s<nn; s+=256){
      int b = sbk[s];
      int local = gbase[b] + (s - hoff[b]);
      if(local < BCAP2) bin[(size_t)b*BCAP2 + local] = staged[s];
    }
  } else if(bid < NBIN+256){
    int id = (bid-NBIN)*256 + tid;               // 65536 total
    int n = id & 255, k = id >> 8;
    float v = W1[k*F1 + n];
    u16 h = f2bf(v);
    w1h[n*FIN + k] = h;
    w1l[n*FIN + k] = f2bf(v - us2f(h));
  } else {
    int id = (bid-(NBIN+256))*256 + tid;         // 12288 total: col 0..47, k 0..255
    int col = id >> 8, k = id & 255;
    float v = (col < NC) ? W2[k*NC + col] : 0.f;
    u16 h = f2bf(v);
    w2h[col*F1 + k] = h;
    w2l[col*F1 + k] = f2bf(v - us2f(h));
  }
}

// ---- fused GEMM1 (blocks 0..781; 128x128 tile, LDS-staged, on-the-fly x split)
//      + histogram (782..879)
__global__ __launch_bounds__(256) void k_g1h(const float* __restrict__ x,
                                             const short* __restrict__ wh, const short* __restrict__ wl,
                                             const float* __restrict__ as1, const float* __restrict__ ad1,
                                             u16* __restrict__ h1b,
                                             float* __restrict__ aS, float* __restrict__ aD,
                                             const int* __restrict__ cnt, const u32* __restrict__ bin,
                                             int* __restrict__ rloc, int* __restrict__ bsum){
  __shared__ char smem[4*128*G1PAD*2];   // 40,960 B
  int tid = threadIdx.x;
  if(blockIdx.x >= NG1){
    // ---- histogram + 512-entry LDS exclusive scan for bucket b
    int* dl = (int*)smem; int* s1 = dl + 512; int* s2 = s1 + 512;
    int b = blockIdx.x - NG1;
    for(int i=tid;i<512;i+=256) dl[i] = 0;
    __syncthreads();
    int n = min(cnt[b], BCAP2);
    const u32* bp = bin + (size_t)b*BCAP2;
    for(int i=tid;i<n;i+=256) atomicAdd(&dl[(bp[i]>>16)&511], 1);
    __syncthreads();
    for(int i=tid;i<512;i+=256) s1[i] = dl[i];
    __syncthreads();
    int* src = s1; int* dst = s2;
    for(int off=1; off<512; off<<=1){
      for(int i=tid;i<512;i+=256) dst[i] = src[i] + (i>=off ? src[i-off] : 0);
      __syncthreads();
      int* t = src; src = dst; dst = t;
    }
    for(int i=tid;i<512;i+=256) rloc[b*512+i] = src[i] - dl[i];
    if(tid==0) bsum[b] = src[511];
    return;
  }
  // ---- GEMM1: block = 128 rows x 128 cols; wave = 64x64 quadrant
  u16* Ah = (u16*)smem;
  u16* Al = Ah + 128*G1PAD;
  u16* Bh = Al + 128*G1PAD;
  u16* Bl = Bh + 128*G1PAD;
  int w = tid >> 6, lane = tid & 63;
  int lo = lane & 15, hi = lane >> 4;
  int bidm = blockIdx.x >> 1, bidn = blockIdx.x & 1;
  int rowbase = bidm*128, colbase = bidn*128;
  int wr = w >> 1, wc = w & 1;
  // staging assignment: thread stages rows r0 and r0+64, chunk ch (8 elems) of A(hi/lo from x) and B(hi/lo)
  int r0 = tid >> 2, ch = tid & 3;
  int arow0 = rowbase + r0;      if(arow0 >= NN) arow0 = NN-1;
  int arow1 = rowbase + r0 + 64; if(arow1 >= NN) arow1 = NN-1;
  const float* pX0 = x + (size_t)arow0*FIN + ch*8;
  const float* pX1 = x + (size_t)arow1*FIN + ch*8;
  const short* pB0h = wh + (size_t)(colbase + r0)*FIN + ch*8;
  const short* pB1h = wh + (size_t)(colbase + r0 + 64)*FIN + ch*8;
  const short* pB0l = wl + (size_t)(colbase + r0)*FIN + ch*8;
  const short* pB1l = wl + (size_t)(colbase + r0 + 64)*FIN + ch*8;
  int so0 = r0*G1PAD + ch*8, so1 = (r0+64)*G1PAD + ch*8;
  f32x4 acc[4][4];                       // [rg][tt]
  #pragma unroll
  for(int rg=0;rg<4;rg++)
    #pragma unroll
    for(int tt=0;tt<4;tt++) acc[rg][tt] = (f32x4){0.f,0.f,0.f,0.f};
  for(int k0=0; k0<FIN; k0+=32){
    // issue global loads early (independent of LDS state)
    float4 xa0 = *(const float4*)(pX0 + k0);
    float4 xa1 = *(const float4*)(pX0 + k0 + 4);
    float4 xb0 = *(const float4*)(pX1 + k0);
    float4 xb1 = *(const float4*)(pX1 + k0 + 4);
    bf16x8 vb0 = *(const bf16x8*)(pB0h + k0);
    bf16x8 vb1 = *(const bf16x8*)(pB1h + k0);
    bf16x8 vb2 = *(const bf16x8*)(pB0l + k0);
    bf16x8 vb3 = *(const bf16x8*)(pB1l + k0);
    // split x -> hi/lo (identical bit-ops to old k_prep split: truncate hi, truncate lo)
    float v0[8] = {xa0.x,xa0.y,xa0.z,xa0.w,xa1.x,xa1.y,xa1.z,xa1.w};
    float v1[8] = {xb0.x,xb0.y,xb0.z,xb0.w,xb1.x,xb1.y,xb1.z,xb1.w};
    bf16x8 a0h, a0l, a1h, a1l;
    #pragma unroll
    for(int j=0;j<8;j++){
      u32 u = __float_as_uint(v0[j]);
      a0h[j] = (short)(u >> 16);
      float hf = __uint_as_float(u & 0xffff0000u);
      a0l[j] = (short)(__float_as_uint(v0[j] - hf) >> 16);
      u32 u2 = __float_as_uint(v1[j]);
      a1h[j] = (short)(u2 >> 16);
      float hf2 = __uint_as_float(u2 & 0xffff0000u);
      a1l[j] = (short)(__float_as_uint(v1[j] - hf2) >> 16);
    }
    __syncthreads();                      // previous iter's reads complete
    *(bf16x8*)&Ah[so0] = a0h; *(bf16x8*)&Ah[so1] = a1h;
    *(bf16x8*)&Al[so0] = a0l; *(bf16x8*)&Al[so1] = a1l;
    *(bf16x8*)&Bh[so0] = vb0; *(bf16x8*)&Bh[so1] = vb1;
    *(bf16x8*)&Bl[so0] = vb2; *(bf16x8*)&Bl[so1] = vb3;
    __syncthreads();                      // staging visible
    bf16x8 ah[4], al[4];
    #pragma unroll
    for(int rg=0;rg<4;rg++){
      int ar = wr*64 + rg*16 + lo;
      ah[rg] = *(const bf16x8*)&Ah[ar*G1PAD + hi*8];
      al[rg] = *(const bf16x8*)&Al[ar*G1PAD + hi*8];
    }
    #pragma unroll
    for(int tt=0;tt<4;tt++){
      int bc = wc*64 + tt*16 + lo;
      bf16x8 bh = *(const bf16x8*)&Bh[bc*G1PAD + hi*8];
      bf16x8 bl = *(const bf16x8*)&Bl[bc*G1PAD + hi*8];
      #pragma unroll
      for(int rg=0;rg<4;rg++){
        acc[rg][tt] = __builtin_amdgcn_mfma_f32_16x16x32_bf16(ah[rg], bh, acc[rg][tt], 0, 0, 0);
        acc[rg][tt] = __builtin_amdgcn_mfma_f32_16x16x32_bf16(al[rg], bh, acc[rg][tt], 0, 0, 0);
        acc[rg][tt] = __builtin_amdgcn_mfma_f32_16x16x32_bf16(ah[rg], bl, acc[rg][tt], 0, 0, 0);
      }
    }
  }
  // h1b store: row = rowbase + wr*64 + rg*16 + hi*4 + r; col = colbase + wc*64 + tt*16 + lo
  #pragma unroll
  for(int rg=0;rg<4;rg++){
    #pragma unroll
    for(int tt=0;tt<4;tt++){
      #pragma unroll
      for(int r=0;r<4;r++){
        int row = rowbase + wr*64 + rg*16 + hi*4 + r;
        if(row < NN) h1b[(size_t)row*F1 + colbase + wc*64 + tt*16 + lo] = f2bf(acc[rg][tt][r]);
      }
    }
  }
  // fused attention dots for head bidn*2+wc (prescaled by log2 e)
  int head = bidn*2 + wc;
  float ps[4][4], pd[4][4];              // [rg][r]
  #pragma unroll
  for(int rg=0;rg<4;rg++)
    #pragma unroll
    for(int r=0;r<4;r++){ ps[rg][r]=0.f; pd[rg][r]=0.f; }
  #pragma unroll
  for(int tt=0;tt<4;tt++){
    int col = colbase + wc*64 + tt*16 + lo;
    float sv = as1[col]*LOG2E, dv = ad1[col]*LOG2E;
    #pragma unroll
    for(int rg=0;rg<4;rg++)
      #pragma unroll
      for(int r=0;r<4;r++){ ps[rg][r] += acc[rg][tt][r]*sv; pd[rg][r] += acc[rg][tt][r]*dv; }
  }
  #pragma unroll
  for(int off=1; off<16; off<<=1){
    #pragma unroll
    for(int rg=0;rg<4;rg++)
      #pragma unroll
      for(int r=0;r<4;r++){
        ps[rg][r] += __shfl_xor(ps[rg][r], off, 64);
        pd[rg][r] += __shfl_xor(pd[rg][r], off, 64);
      }
  }
  if(lo == 0){
    #pragma unroll
    for(int rg=0;rg<4;rg++)
      #pragma unroll
      for(int r=0;r<4;r++){
        int row = rowbase + wr*64 + rg*16 + hi*4 + r;
        if(row < NN){ aS[row*HEADS+head] = ps[rg][r]; aD[row*HEADS+head] = pd[rg][r]; }
      }
  }
}

// ---- per-bucket scatter into contiguous adj window; computes own global base
__global__ __launch_bounds__(256) void k_fill2(const int* __restrict__ cnt, const u32* __restrict__ bin,
                                               const int* __restrict__ rloc, const int* __restrict__ bsum,
                                               int* __restrict__ rowptr, int* __restrict__ adj){
  __shared__ int cur[512];
  __shared__ int sb[NB2];
  __shared__ int base_s;
  int b = blockIdx.x, tid = threadIdx.x;
  if(tid < NB2) sb[tid] = bsum[tid];
  __syncthreads();
  if(tid == 0){
    int run = 0;
    for(int i=0;i<b;i++) run += sb[i];
    base_s = run;
    if(b == NB2-1) rowptr[NN] = run + sb[b];
  }
  __syncthreads();
  int base = base_s;
  for(int i=tid;i<512;i+=256){
    int d = b*512 + i;
    int v = base + rloc[b*512+i];
    cur[i] = v;
    if(d < NN) rowptr[d] = v;
  }
  __syncthreads();
  int n = min(cnt[b], BCAP2);
  const u32* bp = bin + (size_t)b*BCAP2;
  for(int i=tid;i<n;i+=256){
    u32 v = bp[i];
    int p = atomicAdd(&cur[(v>>16)&511], 1);
    adj[p] = (int)(v & 0xffffu);
  }
}

// ---- layer-1 aggregation + bias + BN + ELU -> h2 (f32), one wave per node.
__global__ __launch_bounds__(256) void k_agg1(const u16* __restrict__ h1b,
  const float* __restrict__ aS, const float* __restrict__ aD,
  const int* __restrict__ rowptr, const int* __restrict__ adj,
  const float* __restrict__ b1, const float* __restrict__ g1, const float* __restrict__ be1,
  const float* __restrict__ mn1, const float* __restrict__ vr1,
  float* __restrict__ h2){
  __shared__ float lw[4][CHUNK*4];   // [wave][i*4+head]
  __shared__ int   lsrc[4][CHUNK];
  int w = threadIdx.x >> 6, lane = threadIdx.x & 63;
  int node = blockIdx.x*4 + w;
  int g = lane >> 5, li = lane & 31;
  int hb = li >> 3;                  // head of this lane's 8-channel block
  int beg = rowptr[node], end = rowptr[node+1];
  float4 ad4 = *(const float4*)&aD[node*HEADS];
  float den[4] = {0.f,0.f,0.f,0.f};
  float acc[8] = {0.f,0.f,0.f,0.f,0.f,0.f,0.f,0.f};
  int total = end - beg + 1;                  // + self loop
  for(int c0=0; c0<total; c0+=CHUNK){
    int n = min(CHUNK, total - c0);
    for(int i=lane; i<n; i+=64){
      int e = beg + c0 + i;
      int src = (e < end) ? adj[e] : node;
      float4 s4 = *(const float4*)&aS[src*HEADS];
      float w0 = s4.x + ad4.x; w0 = w0>0.f?w0:SLOPE*w0; w0 = exp2f(fminf(w0,110.f));
      float w1 = s4.y + ad4.y; w1 = w1>0.f?w1:SLOPE*w1; w1 = exp2f(fminf(w1,110.f));
      float w2 = s4.z + ad4.z; w2 = w2>0.f?w2:SLOPE*w2; w2 = exp2f(fminf(w2,110.f));
      float w3 = s4.w + ad4.w; w3 = w3>0.f?w3:SLOPE*w3; w3 = exp2f(fminf(w3,110.f));
      lsrc[w][i] = src;
      *(float4*)&lw[w][i*4] = make_float4(w0,w1,w2,w3);
      den[0]+=w0; den[1]+=w1; den[2]+=w2; den[3]+=w3;
    }
    asm volatile("s_waitcnt lgkmcnt(0)" ::: "memory");
    #pragma unroll 2
    for(int i=0; i<n; i+=2){
      int e = i + g;
      bool ok = e < n;
      int src = ok ? lsrc[w][e] : node;
      float wg = ok ? lw[w][e*4 + hb] : 0.f;
      uint4 pv = *(const uint4*)&h1b[(size_t)src*F1 + li*8];
      acc[0] += wg*__uint_as_float(pv.x << 16);  acc[1] += wg*__uint_as_float(pv.x & 0xffff0000u);
      acc[2] += wg*__uint_as_float(pv.y << 16);  acc[3] += wg*__uint_as_float(pv.y & 0xffff0000u);
      acc[4] += wg*__uint_as_float(pv.z << 16);  acc[5] += wg*__uint_as_float(pv.z & 0xffff0000u);
      acc[6] += wg*__uint_as_float(pv.w << 16);  acc[7] += wg*__uint_as_float(pv.w & 0xffff0000u);
    }
  }
  #pragma unroll
  for(int off=1; off<64; off<<=1){
    #pragma unroll
    for(int q=0;q<4;q++) den[q] += __shfl_xor(den[q], off, 64);
  }
  #pragma unroll
  for(int k=0;k<8;k++) acc[k] += __shfl_xor(acc[k], 32, 64);
  if(lane < 32){
    float dsel = hb==0 ? den[0] : (hb==1 ? den[1] : (hb==2 ? den[2] : den[3]));
    float inv = 1.f/(dsel + 1e-16f);
    int c = li*8;
    float o[8];
    #pragma unroll
    for(int j=0;j<8;j++){
      float v = acc[j]*inv + b1[c+j];
      v = (v - mn1[c+j]) * rsqrtf(vr1[c+j] + 1e-5f) * g1[c+j] + be1[c+j];
      o[j] = v > 0.f ? v : (__expf(v) - 1.f);   // ELU
    }
    *(float4*)&h2[(size_t)node*F1 + c]     = make_float4(o[0],o[1],o[2],o[3]);
    *(float4*)&h2[(size_t)node*F1 + c + 4] = make_float4(o[4],o[5],o[6],o[7]);
  }
}

// ---- GEMM2 (MFMA bf16x3, on-the-fly h2 split) + fused attention dots layer 2.
__global__ __launch_bounds__(256) void k_gemm2(const float* __restrict__ h2,
    const short* __restrict__ w2h, const short* __restrict__ w2l,
    const float* __restrict__ as2, const float* __restrict__ ad2,
    u16* __restrict__ h2p, float* __restrict__ aS2, float* __restrict__ aD2){
  int w = threadIdx.x >> 6, lane = threadIdx.x & 63;
  int lo = lane & 15, hi = lane >> 4;
  int rowbase = blockIdx.x*64 + w*16;
  int arow = rowbase + lo; if(arow >= NN) arow = NN-1;
  f32x4 acc[3];
  #pragma unroll
  for(int tt=0;tt<3;tt++) acc[tt] = (f32x4){0.f,0.f,0.f,0.f};
  const float* xp = h2 + (size_t)arow*F1 + 8*hi;
  const short* bph = w2h + (size_t)lo*F1 + 8*hi;
  const short* bpl = w2l + (size_t)lo*F1 + 8*hi;
  for(int k0=0; k0<F1; k0+=32){
    float4 va = *(const float4*)(xp + k0);
    float4 vb = *(const float4*)(xp + k0 + 4);
    float v[8] = {va.x,va.y,va.z,va.w,vb.x,vb.y,vb.z,vb.w};
    bf16x8 ah, al;
    #pragma unroll
    for(int j=0;j<8;j++){
      u32 u = __float_as_uint(v[j]);
      ah[j] = (short)(u >> 16);
      float hf = __uint_as_float(u & 0xffff0000u);
      al[j] = (short)(__float_as_uint(v[j] - hf) >> 16);
    }
    #pragma unroll
    for(int tt=0;tt<3;tt++){
      bf16x8 bh = *(const bf16x8*)(bph + (size_t)tt*16*F1 + k0);
      bf16x8 bl = *(const bf16x8*)(bpl + (size_t)tt*16*F1 + k0);
      acc[tt] = __builtin_amdgcn_mfma_f32_16x16x32_bf16(ah, bh, acc[tt], 0, 0, 0);
      acc[tt] = __builtin_amdgcn_mfma_f32_16x16x32_bf16(al, bh, acc[tt], 0, 0, 0);
      acc[tt] = __builtin_amdgcn_mfma_f32_16x16x32_bf16(ah, bl, acc[tt], 0, 0, 0);
    }
  }
  float ps[4] = {0.f,0.f,0.f,0.f}, pd[4] = {0.f,0.f,0.f,0.f};
  #pragma unroll
  for(int tt=0;tt<3;tt++){
    int col = tt*16 + lo;
    float sv = (col < NC) ? as2[col]*LOG2E : 0.f;
    float dv = (col < NC) ? ad2[col]*LOG2E : 0.f;
    #pragma unroll
    for(int r=0;r<4;r++){
      int row = rowbase + hi*4 + r;
      if(row < NN && col < NC) h2p[(size_t)row*NC + col] = f2bf(acc[tt][r]);
      ps[r] += acc[tt][r]*sv; pd[r] += acc[tt][r]*dv;
    }
  }
  #pragma unroll
  for(int off=1; off<16; off<<=1){
    #pragma unroll
    for(int r=0;r<4;r++){ ps[r] += __shfl_xor(ps[r], off, 64); pd[r] += __shfl_xor(pd[r], off, 64); }
  }
  if(lo == 0){
    #pragma unroll
    for(int r=0;r<4;r++){
      int row = rowbase + hi*4 + r;
      if(row < NN){ aS2[row] = ps[r]; aD2[row] = pd[r]; }
    }
  }
}

// ---- layer-2 aggregation -> output (f32), bf16 h2p gather
__global__ __launch_bounds__(256) void k_agg2(const u16* __restrict__ h2p,
  const float* __restrict__ aS2, const float* __restrict__ aD2,
  const int* __restrict__ rowptr, const int* __restrict__ adj,
  const float* __restrict__ b2, float* __restrict__ out){
  __shared__ float lw[4][CHUNK];
  __shared__ int   lsrc[4][CHUNK];
  int w = threadIdx.x >> 6, lane = threadIdx.x & 63;
  int node = blockIdx.x*4 + w;
  int beg = rowptr[node], end = rowptr[node+1];
  float adv = aD2[node];
  float den = 0.f, acc = 0.f;
  int total = end - beg + 1;
  for(int c0=0; c0<total; c0+=CHUNK){
    int n = min(CHUNK, total - c0);
    for(int i=lane; i<n; i+=64){
      int e = beg + c0 + i;
      int src = (e < end) ? adj[e] : node;
      float ev = aS2[src] + adv; ev = ev>0.f?ev:SLOPE*ev;
      float wg = exp2f(fminf(ev,110.f));
      lsrc[w][i] = src;
      lw[w][i] = wg;
      den += wg;
    }
    asm volatile("s_waitcnt lgkmcnt(0)" ::: "memory");
    #pragma unroll 2
    for(int i=0;i<n;i++){
      int s = lsrc[w][i];
      float wg = lw[w][i];
      if(lane < NC) acc += wg * us2f(h2p[(size_t)s*NC + lane]);
    }
  }
  #pragma unroll
  for(int off=1; off<64; off<<=1) den += __shfl_xor(den, off, 64);
  if(lane < NC) out[(size_t)node*NC + lane] = acc/(den + 1e-16f) + b2[lane];
}

extern "C" void kernel_launch(void* const* d_in, const int* in_sizes, int n_in,
                              void* d_out, int out_size, void* d_ws, size_t ws_size,
                              hipStream_t stream){
  (void)in_sizes; (void)n_in; (void)out_size; (void)ws_size;
  const float* x   = (const float*)d_in[0];
  const int*   ei  = (const int*)d_in[1];
  const float* W1  = (const float*)d_in[2];
  const float* as1 = (const float*)d_in[3];
  const float* ad1 = (const float*)d_in[4];
  const float* b1  = (const float*)d_in[5];
  const float* g1  = (const float*)d_in[6];
  const float* be1 = (const float*)d_in[7];
  const float* mn1 = (const float*)d_in[8];
  const float* vr1 = (const float*)d_in[9];
  const float* W2  = (const float*)d_in[10];
  const float* as2 = (const float*)d_in[11];
  const float* ad2 = (const float*)d_in[12];
  const float* b2  = (const float*)d_in[13];

  char* ws = (char*)d_ws;
  u16*  h1b    = (u16*) (ws + 0);             // 25,600,000 (bf16 h1)
  float* h2    = (float*)(ws + 25600000);     // 51,200,000
  // w1h/w1l alias h2p (dead before k_gemm2 writes h2p)
  u16*  h2p    = (u16*) (ws + 76800000);      //  4,000,000 (bf16)
  u16*  w1h    = (u16*) (ws + 76800000);      //    131,072
  u16*  w1l    = (u16*) (ws + 76931072);      //    131,072
  float* aS1   = (float*)(ws + 84800000);     //    800,000
  float* aD1   = (float*)(ws + 85600000);     //    800,000
  float* aS2   = (float*)(ws + 86400000);     //    200,000
  float* aD2   = (float*)(ws + 86600000);     //    200,000
  int*  rowptr = (int*)  (ws + 86800000);     //    200,016
  int*  adj    = (int*)  (ws + 87200016);     //  6,400,000
  u32*  bin    = (u32*)  (ws + 93700000);     //  7,056,000 (98*18000*4)
  int*  cnt    = (int*)  (ws + 100800000);    //        392 (98*4)
  int*  rloc   = (int*)  (ws + 100801024);    //    200,704 (98*512*4)
  int*  bsum   = (int*)  (ws + 101002240);    //        392
  u16*  w2h    = (u16*)  (ws + 101003712);    //     24,576 (48*256*2)
  u16*  w2l    = (u16*)  (ws + 101028288);    //     24,576

  hipMemsetAsync(cnt, 0, NB2*sizeof(int), stream);
  k_prep  <<<NBIN+256+48, 256, 0, stream>>>(ei, cnt, bin, W1, w1h, w1l, W2, w2h, w2l);
  k_g1h   <<<NG1 + NB2, 256, 0, stream>>>(x, (const short*)w1h, (const short*)w1l,
                                          as1, ad1, h1b, aS1, aD1,
                                          cnt, bin, rloc, bsum);
  k_fill2 <<<NB2, 256, 0, stream>>>(cnt, bin, rloc, bsum, rowptr, adj);
  k_agg1  <<<NN/4, 256, 0, stream>>>(h1b, aS1, aD1, rowptr, adj, b1, g1, be1, mn1, vr1, h2);
  k_gemm2 <<<(NN+63)/64, 256, 0, stream>>>(h2, (const short*)w2h, (const short*)w2l,
                                           as2, ad2, h2p, aS2, aD2);
  k_agg2  <<<NN/4, 256, 0, stream>>>(h2p, aS2, aD2, rowptr, adj, b2, (float*)d_out);
}

// Round 18
// 338.129 us; speedup vs baseline: 1.2120x; 1.0042x over previous
//
#include <hip/hip_runtime.h>
#include <hip/hip_bf16.h>

#define NN 50000
#define FIN 256
#define F1 256      // HEADS*HID
#define HEADS 4
#define HID 64
#define NC 40
#define NE 1600000
#define SLOPE 0.2f
#define LOG2E 1.44269504f
#define CHUNK 128
#define NB2 98      // coarse dst buckets (512 nodes each)
#define BSH 9
#define BCAP2 18000 // per-bucket capacity (mean 16327, +13 sigma)
#define TILE 2048   // edges per bin block
#define NBIN 782    // bin blocks (782*2048 >= NE)
#define NG1 782     // gemm1 blocks: 391 row-tiles x 2 col-tiles
#define G1PAD 40    // LDS row pitch in u16 (32 + 8 pad; 80B, 16B-aligned, 2-way max)

typedef unsigned int u32;
typedef unsigned short u16;
typedef unsigned char u8;
typedef __attribute__((ext_vector_type(8))) short bf16x8;
typedef __attribute__((ext_vector_type(4))) float f32x4;

__device__ __forceinline__ float us2f(u32 u){ u32 b = u << 16; return __uint_as_float(b); }
__device__ __forceinline__ u16 f2bf(float f){
  u32 b = __float_as_uint(f);
  u32 r = (b + 0x7fffu + ((b >> 16) & 1u)) >> 16;
  return (u16)r;
}

// ---- fused prep: edge binning (blocks 0..781) + W1 transpose/split (782..1037)
//      + W2 transpose/split (1038..1085)
__global__ __launch_bounds__(256) void k_prep(const int* __restrict__ ei,
      int* __restrict__ cnt, u32* __restrict__ bin,
      const float* __restrict__ W1, u16* __restrict__ w1h, u16* __restrict__ w1l,
      const float* __restrict__ W2, u16* __restrict__ w2h, u16* __restrict__ w2l){
  __shared__ int hcnt[NB2], hoff[NB2], gbase[NB2], hcur[NB2];
  __shared__ u32 staged[TILE];
  __shared__ u8  sbk[TILE];
  __shared__ int ci;
  int bid = blockIdx.x, tid = threadIdx.x;
  if(bid < NBIN){
    int e0 = bid * TILE;
    int nn = min(TILE, NE - e0);
    if(tid==0) ci = 0;
    for(int b=tid;b<NB2;b+=256) hcnt[b] = 0;
    __syncthreads();
    if(ei[2*(e0+tid)+1] != 0) atomicAdd(&ci, 1);   // int64: odd words all 0
    __syncthreads();
    int i64 = (ci == 0);
    u32 val[TILE/256]; int bk[TILE/256];
    #pragma unroll
    for(int j=0;j<TILE/256;j++){
      int t = tid + j*256;
      if(t < nn){
        int i = e0 + t;
        int src = i64 ? ei[2*i] : ei[i];
        int dst = i64 ? ei[2*(NE+i)] : ei[NE+i];
        bk[j] = dst >> BSH;
        val[j] = (u32)src | ((u32)(dst & 511) << 16);
        atomicAdd(&hcnt[bk[j]], 1);
      } else bk[j] = -1;
    }
    __syncthreads();
    if(tid == 0){
      int run = 0;
      for(int b=0;b<NB2;b++){ hoff[b] = run; hcur[b] = run; run += hcnt[b]; }
    }
    __syncthreads();
    if(tid < NB2 && hcnt[tid] > 0) gbase[tid] = atomicAdd(&cnt[tid], hcnt[tid]);
    __syncthreads();
    #pragma unroll
    for(int j=0;j<TILE/256;j++){
      if(bk[j] >= 0){
        int pos = atomicAdd(&hcur[bk[j]], 1);
        staged[pos] = val[j];
        sbk[pos] = (u8)bk[j];
      }
    }
    __syncthreads();
    for(int s=tid; s<nn; s+=256){
      int b = sbk[s];
      int local = gbase[b] + (s - hoff[b]);
      if(local < BCAP2) bin[(size_t)b*BCAP2 + local] = staged[s];
    }
  } else if(bid < NBIN+256){
    int id = (bid-NBIN)*256 + tid;               // 65536 total
    int n = id & 255, k = id >> 8;
    float v = W1[k*F1 + n];
    u16 h = f2bf(v);
    w1h[n*FIN + k] = h;
    w1l[n*FIN + k] = f2bf(v - us2f(h));
  } else {
    int id = (bid-(NBIN+256))*256 + tid;         // 12288 total: col 0..47, k 0..255
    int col = id >> 8, k = id & 255;
    float v = (col < NC) ? W2[k*NC + col] : 0.f;
    u16 h = f2bf(v);
    w2h[col*F1 + k] = h;
    w2l[col*F1 + k] = f2bf(v - us2f(h));
  }
}

// ---- fused GEMM1 (blocks 0..781; 128x128 tile, LDS-staged, on-the-fly x split)
//      + per-bucket histogram/scan/scatter (782..879; fixed bucket base b*BCAP2,
//        rides in the gemm blocks' occupancy shadow — fill2 kernel deleted)
__global__ __launch_bounds__(256) void k_g1h(const float* __restrict__ x,
                                             const short* __restrict__ wh, const short* __restrict__ wl,
                                             const float* __restrict__ as1, const float* __restrict__ ad1,
                                             u16* __restrict__ h1b,
                                             float* __restrict__ aS, float* __restrict__ aD,
                                             const int* __restrict__ cnt, const u32* __restrict__ bin,
                                             int* __restrict__ rowptr, int* __restrict__ rend,
                                             int* __restrict__ adj){
  __shared__ char smem[4*128*G1PAD*2];   // 40,960 B
  int tid = threadIdx.x;
  if(blockIdx.x >= NG1){
    // ---- histogram + 512-entry LDS exclusive scan + in-place scatter for bucket b
    int* dl = (int*)smem; int* s1 = dl + 512; int* s2 = s1 + 512;
    int b = blockIdx.x - NG1;
    int base = b * BCAP2;
    for(int i=tid;i<512;i+=256) dl[i] = 0;
    __syncthreads();
    int n = min(cnt[b], BCAP2);
    const u32* bp = bin + (size_t)b*BCAP2;
    for(int i=tid;i<n;i+=256) atomicAdd(&dl[(bp[i]>>16)&511], 1);
    __syncthreads();
    for(int i=tid;i<512;i+=256) s1[i] = dl[i];
    __syncthreads();
    int* src = s1; int* dst = s2;
    for(int off=1; off<512; off<<=1){
      for(int i=tid;i<512;i+=256) dst[i] = src[i] + (i>=off ? src[i-off] : 0);
      __syncthreads();
      int* t = src; src = dst; dst = t;
    }
    // src = inclusive scan; emit rowptr/rend, seed cursors (reuse dl)
    for(int i=tid;i<512;i+=256){
      int d = b*512 + i;
      int excl = src[i] - dl[i];
      if(d < NN){ rowptr[d] = base + excl; rend[d] = base + src[i]; }
      dl[i] = base + excl;
    }
    __syncthreads();
    for(int i=tid;i<n;i+=256){
      u32 v = bp[i];
      int p = atomicAdd(&dl[(v>>16)&511], 1);
      adj[p] = (int)(v & 0xffffu);
    }
    return;
  }
  // ---- GEMM1: block = 128 rows x 128 cols; wave = 64x64 quadrant
  u16* Ah = (u16*)smem;
  u16* Al = Ah + 128*G1PAD;
  u16* Bh = Al + 128*G1PAD;
  u16* Bl = Bh + 128*G1PAD;
  int w = tid >> 6, lane = tid & 63;
  int lo = lane & 15, hi = lane >> 4;
  int bidm = blockIdx.x >> 1, bidn = blockIdx.x & 1;
  int rowbase = bidm*128, colbase = bidn*128;
  int wr = w >> 1, wc = w & 1;
  int r0 = tid >> 2, ch = tid & 3;
  int arow0 = rowbase + r0;      if(arow0 >= NN) arow0 = NN-1;
  int arow1 = rowbase + r0 + 64; if(arow1 >= NN) arow1 = NN-1;
  const float* pX0 = x + (size_t)arow0*FIN + ch*8;
  const float* pX1 = x + (size_t)arow1*FIN + ch*8;
  const short* pB0h = wh + (size_t)(colbase + r0)*FIN + ch*8;
  const short* pB1h = wh + (size_t)(colbase + r0 + 64)*FIN + ch*8;
  const short* pB0l = wl + (size_t)(colbase + r0)*FIN + ch*8;
  const short* pB1l = wl + (size_t)(colbase + r0 + 64)*FIN + ch*8;
  int so0 = r0*G1PAD + ch*8, so1 = (r0+64)*G1PAD + ch*8;
  f32x4 acc[4][4];                       // [rg][tt]
  #pragma unroll
  for(int rg=0;rg<4;rg++)
    #pragma unroll
    for(int tt=0;tt<4;tt++) acc[rg][tt] = (f32x4){0.f,0.f,0.f,0.f};
  for(int k0=0; k0<FIN; k0+=32){
    float4 xa0 = *(const float4*)(pX0 + k0);
    float4 xa1 = *(const float4*)(pX0 + k0 + 4);
    float4 xb0 = *(const float4*)(pX1 + k0);
    float4 xb1 = *(const float4*)(pX1 + k0 + 4);
    bf16x8 vb0 = *(const bf16x8*)(pB0h + k0);
    bf16x8 vb1 = *(const bf16x8*)(pB1h + k0);
    bf16x8 vb2 = *(const bf16x8*)(pB0l + k0);
    bf16x8 vb3 = *(const bf16x8*)(pB1l + k0);
    float v0[8] = {xa0.x,xa0.y,xa0.z,xa0.w,xa1.x,xa1.y,xa1.z,xa1.w};
    float v1[8] = {xb0.x,xb0.y,xb0.z,xb0.w,xb1.x,xb1.y,xb1.z,xb1.w};
    bf16x8 a0h, a0l, a1h, a1l;
    #pragma unroll
    for(int j=0;j<8;j++){
      u32 u = __float_as_uint(v0[j]);
      a0h[j] = (short)(u >> 16);
      float hf = __uint_as_float(u & 0xffff0000u);
      a0l[j] = (short)(__float_as_uint(v0[j] - hf) >> 16);
      u32 u2 = __float_as_uint(v1[j]);
      a1h[j] = (short)(u2 >> 16);
      float hf2 = __uint_as_float(u2 & 0xffff0000u);
      a1l[j] = (short)(__float_as_uint(v1[j] - hf2) >> 16);
    }
    __syncthreads();                      // previous iter's reads complete
    *(bf16x8*)&Ah[so0] = a0h; *(bf16x8*)&Ah[so1] = a1h;
    *(bf16x8*)&Al[so0] = a0l; *(bf16x8*)&Al[so1] = a1l;
    *(bf16x8*)&Bh[so0] = vb0; *(bf16x8*)&Bh[so1] = vb1;
    *(bf16x8*)&Bl[so0] = vb2; *(bf16x8*)&Bl[so1] = vb3;
    __syncthreads();                      // staging visible
    bf16x8 ah[4], al[4];
    #pragma unroll
    for(int rg=0;rg<4;rg++){
      int ar = wr*64 + rg*16 + lo;
      ah[rg] = *(const bf16x8*)&Ah[ar*G1PAD + hi*8];
      al[rg] = *(const bf16x8*)&Al[ar*G1PAD + hi*8];
    }
    #pragma unroll
    for(int tt=0;tt<4;tt++){
      int bc = wc*64 + tt*16 + lo;
      bf16x8 bh = *(const bf16x8*)&Bh[bc*G1PAD + hi*8];
      bf16x8 bl = *(const bf16x8*)&Bl[bc*G1PAD + hi*8];
      #pragma unroll
      for(int rg=0;rg<4;rg++){
        acc[rg][tt] = __builtin_amdgcn_mfma_f32_16x16x32_bf16(ah[rg], bh, acc[rg][tt], 0, 0, 0);
        acc[rg][tt] = __builtin_amdgcn_mfma_f32_16x16x32_bf16(al[rg], bh, acc[rg][tt], 0, 0, 0);
        acc[rg][tt] = __builtin_amdgcn_mfma_f32_16x16x32_bf16(ah[rg], bl, acc[rg][tt], 0, 0, 0);
      }
    }
  }
  #pragma unroll
  for(int rg=0;rg<4;rg++){
    #pragma unroll
    for(int tt=0;tt<4;tt++){
      #pragma unroll
      for(int r=0;r<4;r++){
        int row = rowbase + wr*64 + rg*16 + hi*4 + r;
        if(row < NN) h1b[(size_t)row*F1 + colbase + wc*64 + tt*16 + lo] = f2bf(acc[rg][tt][r]);
      }
    }
  }
  // fused attention dots for head bidn*2+wc (prescaled by log2 e)
  int head = bidn*2 + wc;
  float ps[4][4], pd[4][4];              // [rg][r]
  #pragma unroll
  for(int rg=0;rg<4;rg++)
    #pragma unroll
    for(int r=0;r<4;r++){ ps[rg][r]=0.f; pd[rg][r]=0.f; }
  #pragma unroll
  for(int tt=0;tt<4;tt++){
    int col = colbase + wc*64 + tt*16 + lo;
    float sv = as1[col]*LOG2E, dv = ad1[col]*LOG2E;
    #pragma unroll
    for(int rg=0;rg<4;rg++)
      #pragma unroll
      for(int r=0;r<4;r++){ ps[rg][r] += acc[rg][tt][r]*sv; pd[rg][r] += acc[rg][tt][r]*dv; }
  }
  #pragma unroll
  for(int off=1; off<16; off<<=1){
    #pragma unroll
    for(int rg=0;rg<4;rg++)
      #pragma unroll
      for(int r=0;r<4;r++){
        ps[rg][r] += __shfl_xor(ps[rg][r], off, 64);
        pd[rg][r] += __shfl_xor(pd[rg][r], off, 64);
      }
  }
  if(lo == 0){
    #pragma unroll
    for(int rg=0;rg<4;rg++)
      #pragma unroll
      for(int r=0;r<4;r++){
        int row = rowbase + wr*64 + rg*16 + hi*4 + r;
        if(row < NN){ aS[row*HEADS+head] = ps[rg][r]; aD[row*HEADS+head] = pd[rg][r]; }
      }
  }
}

// ---- layer-1 aggregation + bias + BN + ELU -> h2 (f32), one wave per node.
__global__ __launch_bounds__(256) void k_agg1(const u16* __restrict__ h1b,
  const float* __restrict__ aS, const float* __restrict__ aD,
  const int* __restrict__ rowptr, const int* __restrict__ rend, const int* __restrict__ adj,
  const float* __restrict__ b1, const float* __restrict__ g1, const float* __restrict__ be1,
  const float* __restrict__ mn1, const float* __restrict__ vr1,
  float* __restrict__ h2){
  __shared__ float lw[4][CHUNK*4];   // [wave][i*4+head]
  __shared__ int   lsrc[4][CHUNK];
  int w = threadIdx.x >> 6, lane = threadIdx.x & 63;
  int node = blockIdx.x*4 + w;
  int g = lane >> 5, li = lane & 31;
  int hb = li >> 3;                  // head of this lane's 8-channel block
  int beg = rowptr[node], end = rend[node];
  float4 ad4 = *(const float4*)&aD[node*HEADS];
  float den[4] = {0.f,0.f,0.f,0.f};
  float acc[8] = {0.f,0.f,0.f,0.f,0.f,0.f,0.f,0.f};
  int total = end - beg + 1;                  // + self loop
  for(int c0=0; c0<total; c0+=CHUNK){
    int n = min(CHUNK, total - c0);
    for(int i=lane; i<n; i+=64){
      int e = beg + c0 + i;
      int src = (e < end) ? adj[e] : node;
      float4 s4 = *(const float4*)&aS[src*HEADS];
      float w0 = s4.x + ad4.x; w0 = w0>0.f?w0:SLOPE*w0; w0 = exp2f(fminf(w0,110.f));
      float w1 = s4.y + ad4.y; w1 = w1>0.f?w1:SLOPE*w1; w1 = exp2f(fminf(w1,110.f));
      float w2 = s4.z + ad4.z; w2 = w2>0.f?w2:SLOPE*w2; w2 = exp2f(fminf(w2,110.f));
      float w3 = s4.w + ad4.w; w3 = w3>0.f?w3:SLOPE*w3; w3 = exp2f(fminf(w3,110.f));
      lsrc[w][i] = src;
      *(float4*)&lw[w][i*4] = make_float4(w0,w1,w2,w3);
      den[0]+=w0; den[1]+=w1; den[2]+=w2; den[3]+=w3;
    }
    asm volatile("s_waitcnt lgkmcnt(0)" ::: "memory");
    #pragma unroll 2
    for(int i=0; i<n; i+=2){
      int e = i + g;
      bool ok = e < n;
      int src = ok ? lsrc[w][e] : node;
      float wg = ok ? lw[w][e*4 + hb] : 0.f;
      uint4 pv = *(const uint4*)&h1b[(size_t)src*F1 + li*8];
      acc[0] += wg*__uint_as_float(pv.x << 16);  acc[1] += wg*__uint_as_float(pv.x & 0xffff0000u);
      acc[2] += wg*__uint_as_float(pv.y << 16);  acc[3] += wg*__uint_as_float(pv.y & 0xffff0000u);
      acc[4] += wg*__uint_as_float(pv.z << 16);  acc[5] += wg*__uint_as_float(pv.z & 0xffff0000u);
      acc[6] += wg*__uint_as_float(pv.w << 16);  acc[7] += wg*__uint_as_float(pv.w & 0xffff0000u);
    }
  }
  #pragma unroll
  for(int off=1; off<64; off<<=1){
    #pragma unroll
    for(int q=0;q<4;q++) den[q] += __shfl_xor(den[q], off, 64);
  }
  #pragma unroll
  for(int k=0;k<8;k++) acc[k] += __shfl_xor(acc[k], 32, 64);
  if(lane < 32){
    float dsel = hb==0 ? den[0] : (hb==1 ? den[1] : (hb==2 ? den[2] : den[3]));
    float inv = 1.f/(dsel + 1e-16f);
    int c = li*8;
    float o[8];
    #pragma unroll
    for(int j=0;j<8;j++){
      float v = acc[j]*inv + b1[c+j];
      v = (v - mn1[c+j]) * rsqrtf(vr1[c+j] + 1e-5f) * g1[c+j] + be1[c+j];
      o[j] = v > 0.f ? v : (__expf(v) - 1.f);   // ELU
    }
    *(float4*)&h2[(size_t)node*F1 + c]     = make_float4(o[0],o[1],o[2],o[3]);
    *(float4*)&h2[(size_t)node*F1 + c + 4] = make_float4(o[4],o[5],o[6],o[7]);
  }
}

// ---- GEMM2 (MFMA bf16x3, on-the-fly h2 split) + fused attention dots layer 2.
__global__ __launch_bounds__(256) void k_gemm2(const float* __restrict__ h2,
    const short* __restrict__ w2h, const short* __restrict__ w2l,
    const float* __restrict__ as2, const float* __restrict__ ad2,
    u16* __restrict__ h2p, float* __restrict__ aS2, float* __restrict__ aD2){
  int w = threadIdx.x >> 6, lane = threadIdx.x & 63;
  int lo = lane & 15, hi = lane >> 4;
  int rowbase = blockIdx.x*64 + w*16;
  int arow = rowbase + lo; if(arow >= NN) arow = NN-1;
  f32x4 acc[3];
  #pragma unroll
  for(int tt=0;tt<3;tt++) acc[tt] = (f32x4){0.f,0.f,0.f,0.f};
  const float* xp = h2 + (size_t)arow*F1 + 8*hi;
  const short* bph = w2h + (size_t)lo*F1 + 8*hi;
  const short* bpl = w2l + (size_t)lo*F1 + 8*hi;
  for(int k0=0; k0<F1; k0+=32){
    float4 va = *(const float4*)(xp + k0);
    float4 vb = *(const float4*)(xp + k0 + 4);
    float v[8] = {va.x,va.y,va.z,va.w,vb.x,vb.y,vb.z,vb.w};
    bf16x8 ah, al;
    #pragma unroll
    for(int j=0;j<8;j++){
      u32 u = __float_as_uint(v[j]);
      ah[j] = (short)(u >> 16);
      float hf = __uint_as_float(u & 0xffff0000u);
      al[j] = (short)(__float_as_uint(v[j] - hf) >> 16);
    }
    #pragma unroll
    for(int tt=0;tt<3;tt++){
      bf16x8 bh = *(const bf16x8*)(bph + (size_t)tt*16*F1 + k0);
      bf16x8 bl = *(const bf16x8*)(bpl + (size_t)tt*16*F1 + k0);
      acc[tt] = __builtin_amdgcn_mfma_f32_16x16x32_bf16(ah, bh, acc[tt], 0, 0, 0);
      acc[tt] = __builtin_amdgcn_mfma_f32_16x16x32_bf16(al, bh, acc[tt], 0, 0, 0);
      acc[tt] = __builtin_amdgcn_mfma_f32_16x16x32_bf16(ah, bl, acc[tt], 0, 0, 0);
    }
  }
  float ps[4] = {0.f,0.f,0.f,0.f}, pd[4] = {0.f,0.f,0.f,0.f};
  #pragma unroll
  for(int tt=0;tt<3;tt++){
    int col = tt*16 + lo;
    float sv = (col < NC) ? as2[col]*LOG2E : 0.f;
    float dv = (col < NC) ? ad2[col]*LOG2E : 0.f;
    #pragma unroll
    for(int r=0;r<4;r++){
      int row = rowbase + hi*4 + r;
      if(row < NN && col < NC) h2p[(size_t)row*NC + col] = f2bf(acc[tt][r]);
      ps[r] += acc[tt][r]*sv; pd[r] += acc[tt][r]*dv;
    }
  }
  #pragma unroll
  for(int off=1; off<16; off<<=1){
    #pragma unroll
    for(int r=0;r<4;r++){ ps[r] += __shfl_xor(ps[r], off, 64); pd[r] += __shfl_xor(pd[r], off, 64); }
  }
  if(lo == 0){
    #pragma unroll
    for(int r=0;r<4;r++){
      int row = rowbase + hi*4 + r;
      if(row < NN){ aS2[row] = ps[r]; aD2[row] = pd[r]; }
    }
  }
}

// ---- layer-2 aggregation -> output (f32), bf16 h2p gather
__global__ __launch_bounds__(256) void k_agg2(const u16* __restrict__ h2p,
  const float* __restrict__ aS2, const float* __restrict__ aD2,
  const int* __restrict__ rowptr, const int* __restrict__ rend, const int* __restrict__ adj,
  const float* __restrict__ b2, float* __restrict__ out){
  __shared__ float lw[4][CHUNK];
  __shared__ int   lsrc[4][CHUNK];
  int w = threadIdx.x >> 6, lane = threadIdx.x & 63;
  int node = blockIdx.x*4 + w;
  int beg = rowptr[node], end = rend[node];
  float adv = aD2[node];
  float den = 0.f, acc = 0.f;
  int total = end - beg + 1;
  for(int c0=0; c0<total; c0+=CHUNK){
    int n = min(CHUNK, total - c0);
    for(int i=lane; i<n; i+=64){
      int e = beg + c0 + i;
      int src = (e < end) ? adj[e] : node;
      float ev = aS2[src] + adv; ev = ev>0.f?ev:SLOPE*ev;
      float wg = exp2f(fminf(ev,110.f));
      lsrc[w][i] = src;
      lw[w][i] = wg;
      den += wg;
    }
    asm volatile("s_waitcnt lgkmcnt(0)" ::: "memory");
    #pragma unroll 2
    for(int i=0;i<n;i++){
      int s = lsrc[w][i];
      float wg = lw[w][i];
      if(lane < NC) acc += wg * us2f(h2p[(size_t)s*NC + lane]);
    }
  }
  #pragma unroll
  for(int off=1; off<64; off<<=1) den += __shfl_xor(den, off, 64);
  if(lane < NC) out[(size_t)node*NC + lane] = acc/(den + 1e-16f) + b2[lane];
}

extern "C" void kernel_launch(void* const* d_in, const int* in_sizes, int n_in,
                              void* d_out, int out_size, void* d_ws, size_t ws_size,
                              hipStream_t stream){
  (void)in_sizes; (void)n_in; (void)out_size; (void)ws_size;
  const float* x   = (const float*)d_in[0];
  const int*   ei  = (const int*)d_in[1];
  const float* W1  = (const float*)d_in[2];
  const float* as1 = (const float*)d_in[3];
  const float* ad1 = (const float*)d_in[4];
  const float* b1  = (const float*)d_in[5];
  const float* g1  = (const float*)d_in[6];
  const float* be1 = (const float*)d_in[7];
  const float* mn1 = (const float*)d_in[8];
  const float* vr1 = (const float*)d_in[9];
  const float* W2  = (const float*)d_in[10];
  const float* as2 = (const float*)d_in[11];
  const float* ad2 = (const float*)d_in[12];
  const float* b2  = (const float*)d_in[13];

  char* ws = (char*)d_ws;
  u16*  h1b    = (u16*) (ws + 0);             // 25,600,000 (bf16 h1)
  float* h2    = (float*)(ws + 25600000);     // 51,200,000
  // w1h/w1l alias h2p (dead before k_gemm2 writes h2p)
  u16*  h2p    = (u16*) (ws + 76800000);      //  4,000,000 (bf16)
  u16*  w1h    = (u16*) (ws + 76800000);      //    131,072
  u16*  w1l    = (u16*) (ws + 76931072);      //    131,072
  float* aS1   = (float*)(ws + 84800000);     //    800,000
  float* aD1   = (float*)(ws + 85600000);     //    800,000
  float* aS2   = (float*)(ws + 86400000);     //    200,000
  float* aD2   = (float*)(ws + 86600000);     //    200,000
  int*  rowptr = (int*)  (ws + 86800000);     //    200,000
  int*  rend   = (int*)  (ws + 87000016);     //    200,000
  int*  adj    = (int*)  (ws + 87200016);     //  7,056,000 (98*18000*4, fixed windows)
  u32*  bin    = (u32*)  (ws + 94300000);     //  7,056,000
  int*  cnt    = (int*)  (ws + 101356000);    //        392
  u16*  w2h    = (u16*)  (ws + 101357000);    //     24,576
  u16*  w2l    = (u16*)  (ws + 101382000);    //     24,576

  hipMemsetAsync(cnt, 0, NB2*sizeof(int), stream);
  k_prep  <<<NBIN+256+48, 256, 0, stream>>>(ei, cnt, bin, W1, w1h, w1l, W2, w2h, w2l);
  k_g1h   <<<NG1 + NB2, 256, 0, stream>>>(x, (const short*)w1h, (const short*)w1l,
                                          as1, ad1, h1b, aS1, aD1,
                                          cnt, bin, rowptr, rend, adj);
  k_agg1  <<<NN/4, 256, 0, stream>>>(h1b, aS1, aD1, rowptr, rend, adj, b1, g1, be1, mn1, vr1, h2);
  k_gemm2 <<<(NN+63)/64, 256, 0, stream>>>(h2, (const short*)w2h, (const short*)w2l,
                                           as2, ad2, h2p, aS2, aD2);
  k_agg2  <<<NN/4, 256, 0, stream>>>(h2p, aS2, aD2, rowptr, rend, adj, b2, (float*)d_out);
}

// Round 19
// 330.477 us; speedup vs baseline: 1.2401x; 1.0232x over previous
//
#include <hip/hip_runtime.h>
#include <hip/hip_bf16.h>

#define NN 50000
#define FIN 256
#define F1 256      // HEADS*HID
#define HEADS 4
#define HID 64
#define NC 40
#define NE 1600000
#define SLOPE 0.2f
#define LOG2E 1.44269504f
#define CHUNK 128
#define NB2 98      // coarse dst buckets (512 nodes each)
#define BSH 9
#define BCAP2 18000 // per-bucket capacity (mean 16327, +13 sigma)
#define TILE 2048   // edges per bin block
#define NBIN 782    // bin blocks (782*2048 >= NE)
#define NG1 782     // gemm1 blocks: 391 row-tiles x 2 col-tiles
#define G1PAD 40    // LDS row pitch in u16 (32 + 8 pad; 80B, 16B-aligned, 2-way max)

typedef unsigned int u32;
typedef unsigned short u16;
typedef unsigned char u8;
typedef __attribute__((ext_vector_type(8))) short bf16x8;
typedef __attribute__((ext_vector_type(4))) float f32x4;

__device__ __forceinline__ float us2f(u32 u){ u32 b = u << 16; return __uint_as_float(b); }
__device__ __forceinline__ u16 f2bf(float f){
  u32 b = __float_as_uint(f);
  u32 r = (b + 0x7fffu + ((b >> 16) & 1u)) >> 16;
  return (u16)r;
}

// ---- fused prep: edge binning (blocks 0..781) + W1 transpose/split (782..1037)
//      + W2 transpose/split (1038..1085)
__global__ __launch_bounds__(256) void k_prep(const int* __restrict__ ei,
      int* __restrict__ cnt, u32* __restrict__ bin,
      const float* __restrict__ W1, u16* __restrict__ w1h, u16* __restrict__ w1l,
      const float* __restrict__ W2, u16* __restrict__ w2h, u16* __restrict__ w2l){
  __shared__ int hcnt[NB2], hoff[NB2], gbase[NB2], hcur[NB2];
  __shared__ u32 staged[TILE];
  __shared__ u8  sbk[TILE];
  __shared__ int ci;
  int bid = blockIdx.x, tid = threadIdx.x;
  if(bid < NBIN){
    int e0 = bid * TILE;
    int nn = min(TILE, NE - e0);
    if(tid==0) ci = 0;
    for(int b=tid;b<NB2;b+=256) hcnt[b] = 0;
    __syncthreads();
    if(ei[2*(e0+tid)+1] != 0) atomicAdd(&ci, 1);   // int64: odd words all 0
    __syncthreads();
    int i64 = (ci == 0);
    u32 val[TILE/256]; int bk[TILE/256];
    #pragma unroll
    for(int j=0;j<TILE/256;j++){
      int t = tid + j*256;
      if(t < nn){
        int i = e0 + t;
        int src = i64 ? ei[2*i] : ei[i];
        int dst = i64 ? ei[2*(NE+i)] : ei[NE+i];
        bk[j] = dst >> BSH;
        val[j] = (u32)src | ((u32)(dst & 511) << 16);
        atomicAdd(&hcnt[bk[j]], 1);
      } else bk[j] = -1;
    }
    __syncthreads();
    if(tid == 0){
      int run = 0;
      for(int b=0;b<NB2;b++){ hoff[b] = run; hcur[b] = run; run += hcnt[b]; }
    }
    __syncthreads();
    if(tid < NB2 && hcnt[tid] > 0) gbase[tid] = atomicAdd(&cnt[tid], hcnt[tid]);
    __syncthreads();
    #pragma unroll
    for(int j=0;j<TILE/256;j++){
      if(bk[j] >= 0){
        int pos = atomicAdd(&hcur[bk[j]], 1);
        staged[pos] = val[j];
        sbk[pos] = (u8)bk[j];
      }
    }
    __syncthreads();
    for(int s=tid; s<nn; s+=256){
      int b = sbk[s];
      int local = gbase[b] + (s - hoff[b]);
      if(local < BCAP2) bin[(size_t)b*BCAP2 + local] = staged[s];
    }
  } else if(bid < NBIN+256){
    int id = (bid-NBIN)*256 + tid;               // 65536 total
    int n = id & 255, k = id >> 8;
    float v = W1[k*F1 + n];
    u16 h = f2bf(v);
    w1h[n*FIN + k] = h;
    w1l[n*FIN + k] = f2bf(v - us2f(h));
  } else {
    int id = (bid-(NBIN+256))*256 + tid;         // 12288 total: col 0..47, k 0..255
    int col = id >> 8, k = id & 255;
    float v = (col < NC) ? W2[k*NC + col] : 0.f;
    u16 h = f2bf(v);
    w2h[col*F1 + k] = h;
    w2l[col*F1 + k] = f2bf(v - us2f(h));
  }
}

// ---- fused GEMM1 (blocks 0..781; 128x128 tile, LDS-staged, on-the-fly x split)
//      + per-bucket histogram/scan/scatter (782..879)
__global__ __launch_bounds__(256) void k_g1h(const float* __restrict__ x,
                                             const short* __restrict__ wh, const short* __restrict__ wl,
                                             const float* __restrict__ as1, const float* __restrict__ ad1,
                                             u16* __restrict__ h1b,
                                             float* __restrict__ aS, float* __restrict__ aD,
                                             const int* __restrict__ cnt, const u32* __restrict__ bin,
                                             int* __restrict__ rowptr, int* __restrict__ rend,
                                             int* __restrict__ adj){
  __shared__ char smem[4*128*G1PAD*2];   // 40,960 B
  int tid = threadIdx.x;
  if(blockIdx.x >= NG1){
    // ---- histogram + 512-entry LDS exclusive scan + in-place scatter for bucket b
    int* dl = (int*)smem; int* s1 = dl + 512; int* s2 = s1 + 512;
    int b = blockIdx.x - NG1;
    int base = b * BCAP2;
    for(int i=tid;i<512;i+=256) dl[i] = 0;
    __syncthreads();
    int n = min(cnt[b], BCAP2);
    const u32* bp = bin + (size_t)b*BCAP2;
    for(int i=tid;i<n;i+=256) atomicAdd(&dl[(bp[i]>>16)&511], 1);
    __syncthreads();
    for(int i=tid;i<512;i+=256) s1[i] = dl[i];
    __syncthreads();
    int* src = s1; int* dst = s2;
    for(int off=1; off<512; off<<=1){
      for(int i=tid;i<512;i+=256) dst[i] = src[i] + (i>=off ? src[i-off] : 0);
      __syncthreads();
      int* t = src; src = dst; dst = t;
    }
    for(int i=tid;i<512;i+=256){
      int d = b*512 + i;
      int excl = src[i] - dl[i];
      if(d < NN){ rowptr[d] = base + excl; rend[d] = base + src[i]; }
      dl[i] = base + excl;
    }
    __syncthreads();
    for(int i=tid;i<n;i+=256){
      u32 v = bp[i];
      int p = atomicAdd(&dl[(v>>16)&511], 1);
      adj[p] = (int)(v & 0xffffu);
    }
    return;
  }
  // ---- GEMM1: block = 128 rows x 128 cols; wave = 64x64 quadrant
  u16* Ah = (u16*)smem;
  u16* Al = Ah + 128*G1PAD;
  u16* Bh = Al + 128*G1PAD;
  u16* Bl = Bh + 128*G1PAD;
  int w = tid >> 6, lane = tid & 63;
  int lo = lane & 15, hi = lane >> 4;
  int bidm = blockIdx.x >> 1, bidn = blockIdx.x & 1;
  int rowbase = bidm*128, colbase = bidn*128;
  int wr = w >> 1, wc = w & 1;
  int r0 = tid >> 2, ch = tid & 3;
  int arow0 = rowbase + r0;      if(arow0 >= NN) arow0 = NN-1;
  int arow1 = rowbase + r0 + 64; if(arow1 >= NN) arow1 = NN-1;
  const float* pX0 = x + (size_t)arow0*FIN + ch*8;
  const float* pX1 = x + (size_t)arow1*FIN + ch*8;
  const short* pB0h = wh + (size_t)(colbase + r0)*FIN + ch*8;
  const short* pB1h = wh + (size_t)(colbase + r0 + 64)*FIN + ch*8;
  const short* pB0l = wl + (size_t)(colbase + r0)*FIN + ch*8;
  const short* pB1l = wl + (size_t)(colbase + r0 + 64)*FIN + ch*8;
  int so0 = r0*G1PAD + ch*8, so1 = (r0+64)*G1PAD + ch*8;
  f32x4 acc[4][4];                       // [rg][tt]
  #pragma unroll
  for(int rg=0;rg<4;rg++)
    #pragma unroll
    for(int tt=0;tt<4;tt++) acc[rg][tt] = (f32x4){0.f,0.f,0.f,0.f};
  for(int k0=0; k0<FIN; k0+=32){
    float4 xa0 = *(const float4*)(pX0 + k0);
    float4 xa1 = *(const float4*)(pX0 + k0 + 4);
    float4 xb0 = *(const float4*)(pX1 + k0);
    float4 xb1 = *(const float4*)(pX1 + k0 + 4);
    bf16x8 vb0 = *(const bf16x8*)(pB0h + k0);
    bf16x8 vb1 = *(const bf16x8*)(pB1h + k0);
    bf16x8 vb2 = *(const bf16x8*)(pB0l + k0);
    bf16x8 vb3 = *(const bf16x8*)(pB1l + k0);
    float v0[8] = {xa0.x,xa0.y,xa0.z,xa0.w,xa1.x,xa1.y,xa1.z,xa1.w};
    float v1[8] = {xb0.x,xb0.y,xb0.z,xb0.w,xb1.x,xb1.y,xb1.z,xb1.w};
    bf16x8 a0h, a0l, a1h, a1l;
    #pragma unroll
    for(int j=0;j<8;j++){
      u32 u = __float_as_uint(v0[j]);
      a0h[j] = (short)(u >> 16);
      float hf = __uint_as_float(u & 0xffff0000u);
      a0l[j] = (short)(__float_as_uint(v0[j] - hf) >> 16);
      u32 u2 = __float_as_uint(v1[j]);
      a1h[j] = (short)(u2 >> 16);
      float hf2 = __uint_as_float(u2 & 0xffff0000u);
      a1l[j] = (short)(__float_as_uint(v1[j] - hf2) >> 16);
    }
    __syncthreads();                      // previous iter's reads complete
    *(bf16x8*)&Ah[so0] = a0h; *(bf16x8*)&Ah[so1] = a1h;
    *(bf16x8*)&Al[so0] = a0l; *(bf16x8*)&Al[so1] = a1l;
    *(bf16x8*)&Bh[so0] = vb0; *(bf16x8*)&Bh[so1] = vb1;
    *(bf16x8*)&Bl[so0] = vb2; *(bf16x8*)&Bl[so1] = vb3;
    __syncthreads();                      // staging visible
    bf16x8 ah[4], al[4];
    #pragma unroll
    for(int rg=0;rg<4;rg++){
      int ar = wr*64 + rg*16 + lo;
      ah[rg] = *(const bf16x8*)&Ah[ar*G1PAD + hi*8];
      al[rg] = *(const bf16x8*)&Al[ar*G1PAD + hi*8];
    }
    #pragma unroll
    for(int tt=0;tt<4;tt++){
      int bc = wc*64 + tt*16 + lo;
      bf16x8 bh = *(const bf16x8*)&Bh[bc*G1PAD + hi*8];
      bf16x8 bl = *(const bf16x8*)&Bl[bc*G1PAD + hi*8];
      #pragma unroll
      for(int rg=0;rg<4;rg++){
        acc[rg][tt] = __builtin_amdgcn_mfma_f32_16x16x32_bf16(ah[rg], bh, acc[rg][tt], 0, 0, 0);
        acc[rg][tt] = __builtin_amdgcn_mfma_f32_16x16x32_bf16(al[rg], bh, acc[rg][tt], 0, 0, 0);
        acc[rg][tt] = __builtin_amdgcn_mfma_f32_16x16x32_bf16(ah[rg], bl, acc[rg][tt], 0, 0, 0);
      }
    }
  }
  #pragma unroll
  for(int rg=0;rg<4;rg++){
    #pragma unroll
    for(int tt=0;tt<4;tt++){
      #pragma unroll
      for(int r=0;r<4;r++){
        int row = rowbase + wr*64 + rg*16 + hi*4 + r;
        if(row < NN) h1b[(size_t)row*F1 + colbase + wc*64 + tt*16 + lo] = f2bf(acc[rg][tt][r]);
      }
    }
  }
  // fused attention dots for head bidn*2+wc (prescaled by log2 e)
  int head = bidn*2 + wc;
  float ps[4][4], pd[4][4];              // [rg][r]
  #pragma unroll
  for(int rg=0;rg<4;rg++)
    #pragma unroll
    for(int r=0;r<4;r++){ ps[rg][r]=0.f; pd[rg][r]=0.f; }
  #pragma unroll
  for(int tt=0;tt<4;tt++){
    int col = colbase + wc*64 + tt*16 + lo;
    float sv = as1[col]*LOG2E, dv = ad1[col]*LOG2E;
    #pragma unroll
    for(int rg=0;rg<4;rg++)
      #pragma unroll
      for(int r=0;r<4;r++){ ps[rg][r] += acc[rg][tt][r]*sv; pd[rg][r] += acc[rg][tt][r]*dv; }
  }
  #pragma unroll
  for(int off=1; off<16; off<<=1){
    #pragma unroll
    for(int rg=0;rg<4;rg++)
      #pragma unroll
      for(int r=0;r<4;r++){
        ps[rg][r] += __shfl_xor(ps[rg][r], off, 64);
        pd[rg][r] += __shfl_xor(pd[rg][r], off, 64);
      }
  }
  if(lo == 0){
    #pragma unroll
    for(int rg=0;rg<4;rg++)
      #pragma unroll
      for(int r=0;r<4;r++){
        int row = rowbase + wr*64 + rg*16 + hi*4 + r;
        if(row < NN){ aS[row*HEADS+head] = ps[rg][r]; aD[row*HEADS+head] = pd[rg][r]; }
      }
  }
}

// ---- layer-1 aggregation + bias + BN + ELU -> h2 (bf16), one wave per node.
__global__ __launch_bounds__(256) void k_agg1(const u16* __restrict__ h1b,
  const float* __restrict__ aS, const float* __restrict__ aD,
  const int* __restrict__ rowptr, const int* __restrict__ rend, const int* __restrict__ adj,
  const float* __restrict__ b1, const float* __restrict__ g1, const float* __restrict__ be1,
  const float* __restrict__ mn1, const float* __restrict__ vr1,
  u16* __restrict__ h2b){
  __shared__ float lw[4][CHUNK*4];   // [wave][i*4+head]
  __shared__ int   lsrc[4][CHUNK];
  int w = threadIdx.x >> 6, lane = threadIdx.x & 63;
  int node = blockIdx.x*4 + w;
  int g = lane >> 5, li = lane & 31;
  int hb = li >> 3;                  // head of this lane's 8-channel block
  int beg = rowptr[node], end = rend[node];
  float4 ad4 = *(const float4*)&aD[node*HEADS];
  float den[4] = {0.f,0.f,0.f,0.f};
  float acc[8] = {0.f,0.f,0.f,0.f,0.f,0.f,0.f,0.f};
  int total = end - beg + 1;                  // + self loop
  for(int c0=0; c0<total; c0+=CHUNK){
    int n = min(CHUNK, total - c0);
    for(int i=lane; i<n; i+=64){
      int e = beg + c0 + i;
      int src = (e < end) ? adj[e] : node;
      float4 s4 = *(const float4*)&aS[src*HEADS];
      float w0 = s4.x + ad4.x; w0 = w0>0.f?w0:SLOPE*w0; w0 = exp2f(fminf(w0,110.f));
      float w1 = s4.y + ad4.y; w1 = w1>0.f?w1:SLOPE*w1; w1 = exp2f(fminf(w1,110.f));
      float w2 = s4.z + ad4.z; w2 = w2>0.f?w2:SLOPE*w2; w2 = exp2f(fminf(w2,110.f));
      float w3 = s4.w + ad4.w; w3 = w3>0.f?w3:SLOPE*w3; w3 = exp2f(fminf(w3,110.f));
      lsrc[w][i] = src;
      *(float4*)&lw[w][i*4] = make_float4(w0,w1,w2,w3);
      den[0]+=w0; den[1]+=w1; den[2]+=w2; den[3]+=w3;
    }
    asm volatile("s_waitcnt lgkmcnt(0)" ::: "memory");
    #pragma unroll 2
    for(int i=0; i<n; i+=2){
      int e = i + g;
      bool ok = e < n;
      int src = ok ? lsrc[w][e] : node;
      float wg = ok ? lw[w][e*4 + hb] : 0.f;
      uint4 pv = *(const uint4*)&h1b[(size_t)src*F1 + li*8];
      acc[0] += wg*__uint_as_float(pv.x << 16);  acc[1] += wg*__uint_as_float(pv.x & 0xffff0000u);
      acc[2] += wg*__uint_as_float(pv.y << 16);  acc[3] += wg*__uint_as_float(pv.y & 0xffff0000u);
      acc[4] += wg*__uint_as_float(pv.z << 16);  acc[5] += wg*__uint_as_float(pv.z & 0xffff0000u);
      acc[6] += wg*__uint_as_float(pv.w << 16);  acc[7] += wg*__uint_as_float(pv.w & 0xffff0000u);
    }
  }
  #pragma unroll
  for(int off=1; off<64; off<<=1){
    #pragma unroll
    for(int q=0;q<4;q++) den[q] += __shfl_xor(den[q], off, 64);
  }
  #pragma unroll
  for(int k=0;k<8;k++) acc[k] += __shfl_xor(acc[k], 32, 64);
  if(lane < 32){
    float dsel = hb==0 ? den[0] : (hb==1 ? den[1] : (hb==2 ? den[2] : den[3]));
    float inv = 1.f/(dsel + 1e-16f);
    int c = li*8;
    u16 o[8];
    #pragma unroll
    for(int j=0;j<8;j++){
      float v = acc[j]*inv + b1[c+j];
      v = (v - mn1[c+j]) * rsqrtf(vr1[c+j] + 1e-5f) * g1[c+j] + be1[c+j];
      v = v > 0.f ? v : (__expf(v) - 1.f);      // ELU
      o[j] = f2bf(v);
    }
    uint4 pk;
    pk.x = (u32)o[0] | ((u32)o[1] << 16);
    pk.y = (u32)o[2] | ((u32)o[3] << 16);
    pk.z = (u32)o[4] | ((u32)o[5] << 16);
    pk.w = (u32)o[6] | ((u32)o[7] << 16);
    *(uint4*)&h2b[(size_t)node*F1 + c] = pk;
  }
}

// ---- GEMM2 (MFMA bf16x2 — h2 is bf16, no A-lo term) + fused attention dots layer 2.
__global__ __launch_bounds__(256) void k_gemm2(const short* __restrict__ h2b,
    const short* __restrict__ w2h, const short* __restrict__ w2l,
    const float* __restrict__ as2, const float* __restrict__ ad2,
    u16* __restrict__ h2p, float* __restrict__ aS2, float* __restrict__ aD2){
  int w = threadIdx.x >> 6, lane = threadIdx.x & 63;
  int lo = lane & 15, hi = lane >> 4;
  int rowbase = blockIdx.x*64 + w*16;
  int arow = rowbase + lo; if(arow >= NN) arow = NN-1;
  f32x4 acc[3];
  #pragma unroll
  for(int tt=0;tt<3;tt++) acc[tt] = (f32x4){0.f,0.f,0.f,0.f};
  const short* xp = h2b + (size_t)arow*F1 + 8*hi;
  const short* bph = w2h + (size_t)lo*F1 + 8*hi;
  const short* bpl = w2l + (size_t)lo*F1 + 8*hi;
  for(int k0=0; k0<F1; k0+=32){
    bf16x8 ah = *(const bf16x8*)(xp + k0);
    #pragma unroll
    for(int tt=0;tt<3;tt++){
      bf16x8 bh = *(const bf16x8*)(bph + (size_t)tt*16*F1 + k0);
      bf16x8 bl = *(const bf16x8*)(bpl + (size_t)tt*16*F1 + k0);
      acc[tt] = __builtin_amdgcn_mfma_f32_16x16x32_bf16(ah, bh, acc[tt], 0, 0, 0);
      acc[tt] = __builtin_amdgcn_mfma_f32_16x16x32_bf16(ah, bl, acc[tt], 0, 0, 0);
    }
  }
  float ps[4] = {0.f,0.f,0.f,0.f}, pd[4] = {0.f,0.f,0.f,0.f};
  #pragma unroll
  for(int tt=0;tt<3;tt++){
    int col = tt*16 + lo;
    float sv = (col < NC) ? as2[col]*LOG2E : 0.f;
    float dv = (col < NC) ? ad2[col]*LOG2E : 0.f;
    #pragma unroll
    for(int r=0;r<4;r++){
      int row = rowbase + hi*4 + r;
      if(row < NN && col < NC) h2p[(size_t)row*NC + col] = f2bf(acc[tt][r]);
      ps[r] += acc[tt][r]*sv; pd[r] += acc[tt][r]*dv;
    }
  }
  #pragma unroll
  for(int off=1; off<16; off<<=1){
    #pragma unroll
    for(int r=0;r<4;r++){ ps[r] += __shfl_xor(ps[r], off, 64); pd[r] += __shfl_xor(pd[r], off, 64); }
  }
  if(lo == 0){
    #pragma unroll
    for(int r=0;r<4;r++){
      int row = rowbase + hi*4 + r;
      if(row < NN){ aS2[row] = ps[r]; aD2[row] = pd[r]; }
    }
  }
}

// ---- layer-2 aggregation -> output (f32), bf16 h2p gather
__global__ __launch_bounds__(256) void k_agg2(const u16* __restrict__ h2p,
  const float* __restrict__ aS2, const float* __restrict__ aD2,
  const int* __restrict__ rowptr, const int* __restrict__ rend, const int* __restrict__ adj,
  const float* __restrict__ b2, float* __restrict__ out){
  __shared__ float lw[4][CHUNK];
  __shared__ int   lsrc[4][CHUNK];
  int w = threadIdx.x >> 6, lane = threadIdx.x & 63;
  int node = blockIdx.x*4 + w;
  int beg = rowptr[node], end = rend[node];
  float adv = aD2[node];
  float den = 0.f, acc = 0.f;
  int total = end - beg + 1;
  for(int c0=0; c0<total; c0+=CHUNK){
    int n = min(CHUNK, total - c0);
    for(int i=lane; i<n; i+=64){
      int e = beg + c0 + i;
      int src = (e < end) ? adj[e] : node;
      float ev = aS2[src] + adv; ev = ev>0.f?ev:SLOPE*ev;
      float wg = exp2f(fminf(ev,110.f));
      lsrc[w][i] = src;
      lw[w][i] = wg;
      den += wg;
    }
    asm volatile("s_waitcnt lgkmcnt(0)" ::: "memory");
    #pragma unroll 2
    for(int i=0;i<n;i++){
      int s = lsrc[w][i];
      float wg = lw[w][i];
      if(lane < NC) acc += wg * us2f(h2p[(size_t)s*NC + lane]);
    }
  }
  #pragma unroll
  for(int off=1; off<64; off<<=1) den += __shfl_xor(den, off, 64);
  if(lane < NC) out[(size_t)node*NC + lane] = acc/(den + 1e-16f) + b2[lane];
}

extern "C" void kernel_launch(void* const* d_in, const int* in_sizes, int n_in,
                              void* d_out, int out_size, void* d_ws, size_t ws_size,
                              hipStream_t stream){
  (void)in_sizes; (void)n_in; (void)out_size; (void)ws_size;
  const float* x   = (const float*)d_in[0];
  const int*   ei  = (const int*)d_in[1];
  const float* W1  = (const float*)d_in[2];
  const float* as1 = (const float*)d_in[3];
  const float* ad1 = (const float*)d_in[4];
  const float* b1  = (const float*)d_in[5];
  const float* g1  = (const float*)d_in[6];
  const float* be1 = (const float*)d_in[7];
  const float* mn1 = (const float*)d_in[8];
  const float* vr1 = (const float*)d_in[9];
  const float* W2  = (const float*)d_in[10];
  const float* as2 = (const float*)d_in[11];
  const float* ad2 = (const float*)d_in[12];
  const float* b2  = (const float*)d_in[13];

  char* ws = (char*)d_ws;
  u16*  h1b    = (u16*) (ws + 0);             // 25,600,000 (bf16 h1)
  u16*  h2b    = (u16*) (ws + 25600000);      // 25,600,000 (bf16 h2)
  // w1h/w1l alias h2p (dead before k_gemm2 writes h2p)
  u16*  h2p    = (u16*) (ws + 76800000);      //  4,000,000 (bf16)
  u16*  w1h    = (u16*) (ws + 76800000);      //    131,072
  u16*  w1l    = (u16*) (ws + 76931072);      //    131,072
  float* aS1   = (float*)(ws + 84800000);     //    800,000
  float* aD1   = (float*)(ws + 85600000);     //    800,000
  float* aS2   = (float*)(ws + 86400000);     //    200,000
  float* aD2   = (float*)(ws + 86600000);     //    200,000
  int*  rowptr = (int*)  (ws + 86800000);     //    200,000
  int*  rend   = (int*)  (ws + 87000016);     //    200,000
  int*  adj    = (int*)  (ws + 87200016);     //  7,056,000 (98*18000*4, fixed windows)
  u32*  bin    = (u32*)  (ws + 94300000);     //  7,056,000
  int*  cnt    = (int*)  (ws + 101356000);    //        392
  u16*  w2h    = (u16*)  (ws + 101357000);    //     24,576
  u16*  w2l    = (u16*)  (ws + 101382000);    //     24,576

  hipMemsetAsync(cnt, 0, NB2*sizeof(int), stream);
  k_prep  <<<NBIN+256+48, 256, 0, stream>>>(ei, cnt, bin, W1, w1h, w1l, W2, w2h, w2l);
  k_g1h   <<<NG1 + NB2, 256, 0, stream>>>(x, (const short*)w1h, (const short*)w1l,
                                          as1, ad1, h1b, aS1, aD1,
                                          cnt, bin, rowptr, rend, adj);
  k_agg1  <<<NN/4, 256, 0, stream>>>(h1b, aS1, aD1, rowptr, rend, adj, b1, g1, be1, mn1, vr1, h2b);
  k_gemm2 <<<(NN+63)/64, 256, 0, stream>>>((const short*)h2b, (const short*)w2h, (const short*)w2l,
                                           as2, ad2, h2p, aS2, aD2);
  k_agg2  <<<NN/4, 256, 0, stream>>>(h2p, aS2, aD2, rowptr, rend, adj, b2, (float*)d_out);
}

// Round 20
// 310.845 us; speedup vs baseline: 1.3184x; 1.0632x over previous
//
#include <hip/hip_runtime.h>
#include <hip/hip_bf16.h>

#define NN 50000
#define FIN 256
#define F1 256      // HEADS*HID
#define HEADS 4
#define HID 64
#define NC 40
#define NE 1600000
#define SLOPE 0.2f
#define LOG2E 1.44269504f
#define CHUNK 128
#define NB2 98      // coarse dst buckets (512 nodes each)
#define BSH 9
#define BCAP2 18000 // per-bucket capacity (mean 16327, +13 sigma)
#define TILE 4096   // edges per bin block (halved fixed costs vs 2048)
#define NBIN 391    // bin blocks (391*4096 >= NE)
#define NG1 782     // gemm1 blocks: 391 row-tiles x 2 col-tiles
#define G1PAD 40    // LDS row pitch in u16 (32 + 8 pad; 80B, 16B-aligned, 2-way max)

typedef unsigned int u32;
typedef unsigned short u16;
typedef unsigned char u8;
typedef __attribute__((ext_vector_type(8))) short bf16x8;
typedef __attribute__((ext_vector_type(4))) float f32x4;

__device__ __forceinline__ float us2f(u32 u){ u32 b = u << 16; return __uint_as_float(b); }
__device__ __forceinline__ u16 f2bf(float f){
  u32 b = __float_as_uint(f);
  u32 r = (b + 0x7fffu + ((b >> 16) & 1u)) >> 16;
  return (u16)r;
}

// ---- fused prep: edge binning (blocks 0..390) + W1 transpose/split (391..646)
//      + W2 transpose/split (647..694)
__global__ __launch_bounds__(256) void k_prep(const int* __restrict__ ei,
      int* __restrict__ cnt, u32* __restrict__ bin,
      const float* __restrict__ W1, u16* __restrict__ w1h, u16* __restrict__ w1l,
      const float* __restrict__ W2, u16* __restrict__ w2h, u16* __restrict__ w2l){
  __shared__ int hcnt[NB2], hoff[NB2], gbase[NB2], hcur[NB2];
  __shared__ u32 staged[TILE];
  __shared__ u8  sbk[TILE];
  __shared__ int ci;
  int bid = blockIdx.x, tid = threadIdx.x;
  if(bid < NBIN){
    int e0 = bid * TILE;
    int nn = min(TILE, NE - e0);
    if(tid==0) ci = 0;
    for(int b=tid;b<NB2;b+=256) hcnt[b] = 0;
    __syncthreads();
    if(ei[2*(e0+tid)+1] != 0) atomicAdd(&ci, 1);   // int64: odd words all 0
    __syncthreads();
    int i64 = (ci == 0);
    u32 val[TILE/256]; int bk[TILE/256];
    #pragma unroll
    for(int j=0;j<TILE/256;j++){
      int t = tid + j*256;
      if(t < nn){
        int i = e0 + t;
        int src = i64 ? ei[2*i] : ei[i];
        int dst = i64 ? ei[2*(NE+i)] : ei[NE+i];
        bk[j] = dst >> BSH;
        val[j] = (u32)src | ((u32)(dst & 511) << 16);
        atomicAdd(&hcnt[bk[j]], 1);
      } else bk[j] = -1;
    }
    __syncthreads();
    if(tid == 0){
      int run = 0;
      for(int b=0;b<NB2;b++){ hoff[b] = run; hcur[b] = run; run += hcnt[b]; }
    }
    __syncthreads();
    if(tid < NB2 && hcnt[tid] > 0) gbase[tid] = atomicAdd(&cnt[tid], hcnt[tid]);
    __syncthreads();
    #pragma unroll
    for(int j=0;j<TILE/256;j++){
      if(bk[j] >= 0){
        int pos = atomicAdd(&hcur[bk[j]], 1);
        staged[pos] = val[j];
        sbk[pos] = (u8)bk[j];
      }
    }
    __syncthreads();
    for(int s=tid; s<nn; s+=256){
      int b = sbk[s];
      int local = gbase[b] + (s - hoff[b]);
      if(local < BCAP2) bin[(size_t)b*BCAP2 + local] = staged[s];
    }
  } else if(bid < NBIN+256){
    int id = (bid-NBIN)*256 + tid;               // 65536 total
    int n = id & 255, k = id >> 8;
    float v = W1[k*F1 + n];
    u16 h = f2bf(v);
    w1h[n*FIN + k] = h;
    w1l[n*FIN + k] = f2bf(v - us2f(h));
  } else {
    int id = (bid-(NBIN+256))*256 + tid;         // 12288 total: col 0..47, k 0..255
    int col = id >> 8, k = id & 255;
    float v = (col < NC) ? W2[k*NC + col] : 0.f;
    u16 h = f2bf(v);
    w2h[col*F1 + k] = h;
    w2l[col*F1 + k] = f2bf(v - us2f(h));
  }
}

// ---- fused k_g1h: histogram/scan/scatter FIRST (blocks 0..97, start immediately)
//      + GEMM1 (blocks 98..879; 128x128 tile, LDS-staged, on-the-fly x split)
__global__ __launch_bounds__(256) void k_g1h(const float* __restrict__ x,
                                             const short* __restrict__ wh, const short* __restrict__ wl,
                                             const float* __restrict__ as1, const float* __restrict__ ad1,
                                             u16* __restrict__ h1b,
                                             float* __restrict__ aS, float* __restrict__ aD,
                                             const int* __restrict__ cnt, const u32* __restrict__ bin,
                                             int* __restrict__ rowptr, int* __restrict__ rend,
                                             int* __restrict__ adj){
  __shared__ char smem[4*128*G1PAD*2];   // 40,960 B
  int tid = threadIdx.x;
  if(blockIdx.x < NB2){
    // ---- histogram + 512-entry LDS exclusive scan + in-place scatter for bucket b
    int* dl = (int*)smem; int* s1 = dl + 512; int* s2 = s1 + 512;
    int b = blockIdx.x;
    int base = b * BCAP2;
    for(int i=tid;i<512;i+=256) dl[i] = 0;
    __syncthreads();
    int n = min(cnt[b], BCAP2);
    const u32* bp = bin + (size_t)b*BCAP2;
    for(int i=tid;i<n;i+=256) atomicAdd(&dl[(bp[i]>>16)&511], 1);
    __syncthreads();
    for(int i=tid;i<512;i+=256) s1[i] = dl[i];
    __syncthreads();
    int* src = s1; int* dst = s2;
    for(int off=1; off<512; off<<=1){
      for(int i=tid;i<512;i+=256) dst[i] = src[i] + (i>=off ? src[i-off] : 0);
      __syncthreads();
      int* t = src; src = dst; dst = t;
    }
    for(int i=tid;i<512;i+=256){
      int d = b*512 + i;
      int excl = src[i] - dl[i];
      if(d < NN){ rowptr[d] = base + excl; rend[d] = base + src[i]; }
      dl[i] = base + excl;
    }
    __syncthreads();
    for(int i=tid;i<n;i+=256){
      u32 v = bp[i];
      int p = atomicAdd(&dl[(v>>16)&511], 1);
      adj[p] = (int)(v & 0xffffu);
    }
    return;
  }
  // ---- GEMM1: block = 128 rows x 128 cols; wave = 64x64 quadrant
  u16* Ah = (u16*)smem;
  u16* Al = Ah + 128*G1PAD;
  u16* Bh = Al + 128*G1PAD;
  u16* Bl = Bh + 128*G1PAD;
  int gb = blockIdx.x - NB2;
  int w = tid >> 6, lane = tid & 63;
  int lo = lane & 15, hi = lane >> 4;
  int bidm = gb >> 1, bidn = gb & 1;
  int rowbase = bidm*128, colbase = bidn*128;
  int wr = w >> 1, wc = w & 1;
  int r0 = tid >> 2, ch = tid & 3;
  int arow0 = rowbase + r0;      if(arow0 >= NN) arow0 = NN-1;
  int arow1 = rowbase + r0 + 64; if(arow1 >= NN) arow1 = NN-1;
  const float* pX0 = x + (size_t)arow0*FIN + ch*8;
  const float* pX1 = x + (size_t)arow1*FIN + ch*8;
  const short* pB0h = wh + (size_t)(colbase + r0)*FIN + ch*8;
  const short* pB1h = wh + (size_t)(colbase + r0 + 64)*FIN + ch*8;
  const short* pB0l = wl + (size_t)(colbase + r0)*FIN + ch*8;
  const short* pB1l = wl + (size_t)(colbase + r0 + 64)*FIN + ch*8;
  int so0 = r0*G1PAD + ch*8, so1 = (r0+64)*G1PAD + ch*8;
  f32x4 acc[4][4];                       // [rg][tt]
  #pragma unroll
  for(int rg=0;rg<4;rg++)
    #pragma unroll
    for(int tt=0;tt<4;tt++) acc[rg][tt] = (f32x4){0.f,0.f,0.f,0.f};
  for(int k0=0; k0<FIN; k0+=32){
    float4 xa0 = *(const float4*)(pX0 + k0);
    float4 xa1 = *(const float4*)(pX0 + k0 + 4);
    float4 xb0 = *(const float4*)(pX1 + k0);
    float4 xb1 = *(const float4*)(pX1 + k0 + 4);
    bf16x8 vb0 = *(const bf16x8*)(pB0h + k0);
    bf16x8 vb1 = *(const bf16x8*)(pB1h + k0);
    bf16x8 vb2 = *(const bf16x8*)(pB0l + k0);
    bf16x8 vb3 = *(const bf16x8*)(pB1l + k0);
    float v0[8] = {xa0.x,xa0.y,xa0.z,xa0.w,xa1.x,xa1.y,xa1.z,xa1.w};
    float v1[8] = {xb0.x,xb0.y,xb0.z,xb0.w,xb1.x,xb1.y,xb1.z,xb1.w};
    bf16x8 a0h, a0l, a1h, a1l;
    #pragma unroll
    for(int j=0;j<8;j++){
      u32 u = __float_as_uint(v0[j]);
      a0h[j] = (short)(u >> 16);
      float hf = __uint_as_float(u & 0xffff0000u);
      a0l[j] = (short)(__float_as_uint(v0[j] - hf) >> 16);
      u32 u2 = __float_as_uint(v1[j]);
      a1h[j] = (short)(u2 >> 16);
      float hf2 = __uint_as_float(u2 & 0xffff0000u);
      a1l[j] = (short)(__float_as_uint(v1[j] - hf2) >> 16);
    }
    __syncthreads();                      // previous iter's reads complete
    *(bf16x8*)&Ah[so0] = a0h; *(bf16x8*)&Ah[so1] = a1h;
    *(bf16x8*)&Al[so0] = a0l; *(bf16x8*)&Al[so1] = a1l;
    *(bf16x8*)&Bh[so0] = vb0; *(bf16x8*)&Bh[so1] = vb1;
    *(bf16x8*)&Bl[so0] = vb2; *(bf16x8*)&Bl[so1] = vb3;
    __syncthreads();                      // staging visible
    bf16x8 ah[4], al[4];
    #pragma unroll
    for(int rg=0;rg<4;rg++){
      int ar = wr*64 + rg*16 + lo;
      ah[rg] = *(const bf16x8*)&Ah[ar*G1PAD + hi*8];
      al[rg] = *(const bf16x8*)&Al[ar*G1PAD + hi*8];
    }
    #pragma unroll
    for(int tt=0;tt<4;tt++){
      int bc = wc*64 + tt*16 + lo;
      bf16x8 bh = *(const bf16x8*)&Bh[bc*G1PAD + hi*8];
      bf16x8 bl = *(const bf16x8*)&Bl[bc*G1PAD + hi*8];
      #pragma unroll
      for(int rg=0;rg<4;rg++){
        acc[rg][tt] = __builtin_amdgcn_mfma_f32_16x16x32_bf16(ah[rg], bh, acc[rg][tt], 0, 0, 0);
        acc[rg][tt] = __builtin_amdgcn_mfma_f32_16x16x32_bf16(al[rg], bh, acc[rg][tt], 0, 0, 0);
        acc[rg][tt] = __builtin_amdgcn_mfma_f32_16x16x32_bf16(ah[rg], bl, acc[rg][tt], 0, 0, 0);
      }
    }
  }
  #pragma unroll
  for(int rg=0;rg<4;rg++){
    #pragma unroll
    for(int tt=0;tt<4;tt++){
      #pragma unroll
      for(int r=0;r<4;r++){
        int row = rowbase + wr*64 + rg*16 + hi*4 + r;
        if(row < NN) h1b[(size_t)row*F1 + colbase + wc*64 + tt*16 + lo] = f2bf(acc[rg][tt][r]);
      }
    }
  }
  // fused attention dots for head bidn*2+wc (prescaled by log2 e)
  int head = bidn*2 + wc;
  float ps[4][4], pd[4][4];              // [rg][r]
  #pragma unroll
  for(int rg=0;rg<4;rg++)
    #pragma unroll
    for(int r=0;r<4;r++){ ps[rg][r]=0.f; pd[rg][r]=0.f; }
  #pragma unroll
  for(int tt=0;tt<4;tt++){
    int col = colbase + wc*64 + tt*16 + lo;
    float sv = as1[col]*LOG2E, dv = ad1[col]*LOG2E;
    #pragma unroll
    for(int rg=0;rg<4;rg++)
      #pragma unroll
      for(int r=0;r<4;r++){ ps[rg][r] += acc[rg][tt][r]*sv; pd[rg][r] += acc[rg][tt][r]*dv; }
  }
  #pragma unroll
  for(int off=1; off<16; off<<=1){
    #pragma unroll
    for(int rg=0;rg<4;rg++)
      #pragma unroll
      for(int r=0;r<4;r++){
        ps[rg][r] += __shfl_xor(ps[rg][r], off, 64);
        pd[rg][r] += __shfl_xor(pd[rg][r], off, 64);
      }
  }
  if(lo == 0){
    #pragma unroll
    for(int rg=0;rg<4;rg++)
      #pragma unroll
      for(int r=0;r<4;r++){
        int row = rowbase + wr*64 + rg*16 + hi*4 + r;
        if(row < NN){ aS[row*HEADS+head] = ps[rg][r]; aD[row*HEADS+head] = pd[rg][r]; }
      }
  }
}

// ---- layer-1 aggregation + bias + BN + ELU -> h2 (bf16), one wave per node.
__global__ __launch_bounds__(256) void k_agg1(const u16* __restrict__ h1b,
  const float* __restrict__ aS, const float* __restrict__ aD,
  const int* __restrict__ rowptr, const int* __restrict__ rend, const int* __restrict__ adj,
  const float* __restrict__ b1, const float* __restrict__ g1, const float* __restrict__ be1,
  const float* __restrict__ mn1, const float* __restrict__ vr1,
  u16* __restrict__ h2b){
  __shared__ float lw[4][CHUNK*4];   // [wave][i*4+head]
  __shared__ int   lsrc[4][CHUNK];
  int w = threadIdx.x >> 6, lane = threadIdx.x & 63;
  int node = blockIdx.x*4 + w;
  int g = lane >> 5, li = lane & 31;
  int hb = li >> 3;                  // head of this lane's 8-channel block
  int beg = rowptr[node], end = rend[node];
  float4 ad4 = *(const float4*)&aD[node*HEADS];
  float den[4] = {0.f,0.f,0.f,0.f};
  float acc[8] = {0.f,0.f,0.f,0.f,0.f,0.f,0.f,0.f};
  int total = end - beg + 1;                  // + self loop
  for(int c0=0; c0<total; c0+=CHUNK){
    int n = min(CHUNK, total - c0);
    for(int i=lane; i<n; i+=64){
      int e = beg + c0 + i;
      int src = (e < end) ? adj[e] : node;
      float4 s4 = *(const float4*)&aS[src*HEADS];
      float w0 = s4.x + ad4.x; w0 = w0>0.f?w0:SLOPE*w0; w0 = exp2f(fminf(w0,110.f));
      float w1 = s4.y + ad4.y; w1 = w1>0.f?w1:SLOPE*w1; w1 = exp2f(fminf(w1,110.f));
      float w2 = s4.z + ad4.z; w2 = w2>0.f?w2:SLOPE*w2; w2 = exp2f(fminf(w2,110.f));
      float w3 = s4.w + ad4.w; w3 = w3>0.f?w3:SLOPE*w3; w3 = exp2f(fminf(w3,110.f));
      lsrc[w][i] = src;
      *(float4*)&lw[w][i*4] = make_float4(w0,w1,w2,w3);
      den[0]+=w0; den[1]+=w1; den[2]+=w2; den[3]+=w3;
    }
    asm volatile("s_waitcnt lgkmcnt(0)" ::: "memory");
    #pragma unroll 2
    for(int i=0; i<n; i+=2){
      int e = i + g;
      bool ok = e < n;
      int src = ok ? lsrc[w][e] : node;
      float wg = ok ? lw[w][e*4 + hb] : 0.f;
      uint4 pv = *(const uint4*)&h1b[(size_t)src*F1 + li*8];
      acc[0] += wg*__uint_as_float(pv.x << 16);  acc[1] += wg*__uint_as_float(pv.x & 0xffff0000u);
      acc[2] += wg*__uint_as_float(pv.y << 16);  acc[3] += wg*__uint_as_float(pv.y & 0xffff0000u);
      acc[4] += wg*__uint_as_float(pv.z << 16);  acc[5] += wg*__uint_as_float(pv.z & 0xffff0000u);
      acc[6] += wg*__uint_as_float(pv.w << 16);  acc[7] += wg*__uint_as_float(pv.w & 0xffff0000u);
    }
  }
  #pragma unroll
  for(int off=1; off<64; off<<=1){
    #pragma unroll
    for(int q=0;q<4;q++) den[q] += __shfl_xor(den[q], off, 64);
  }
  #pragma unroll
  for(int k=0;k<8;k++) acc[k] += __shfl_xor(acc[k], 32, 64);
  if(lane < 32){
    float dsel = hb==0 ? den[0] : (hb==1 ? den[1] : (hb==2 ? den[2] : den[3]));
    float inv = 1.f/(dsel + 1e-16f);
    int c = li*8;
    u16 o[8];
    #pragma unroll
    for(int j=0;j<8;j++){
      float v = acc[j]*inv + b1[c+j];
      v = (v - mn1[c+j]) * rsqrtf(vr1[c+j] + 1e-5f) * g1[c+j] + be1[c+j];
      v = v > 0.f ? v : (__expf(v) - 1.f);      // ELU
      o[j] = f2bf(v);
    }
    uint4 pk;
    pk.x = (u32)o[0] | ((u32)o[1] << 16);
    pk.y = (u32)o[2] | ((u32)o[3] << 16);
    pk.z = (u32)o[4] | ((u32)o[5] << 16);
    pk.w = (u32)o[6] | ((u32)o[7] << 16);
    *(uint4*)&h2b[(size_t)node*F1 + c] = pk;
  }
}

// ---- GEMM2 (MFMA bf16x2 — h2 is bf16, no A-lo term) + fused attention dots layer 2.
__global__ __launch_bounds__(256) void k_gemm2(const short* __restrict__ h2b,
    const short* __restrict__ w2h, const short* __restrict__ w2l,
    const float* __restrict__ as2, const float* __restrict__ ad2,
    u16* __restrict__ h2p, float* __restrict__ aS2, float* __restrict__ aD2){
  int w = threadIdx.x >> 6, lane = threadIdx.x & 63;
  int lo = lane & 15, hi = lane >> 4;
  int rowbase = blockIdx.x*64 + w*16;
  int arow = rowbase + lo; if(arow >= NN) arow = NN-1;
  f32x4 acc[3];
  #pragma unroll
  for(int tt=0;tt<3;tt++) acc[tt] = (f32x4){0.f,0.f,0.f,0.f};
  const short* xp = h2b + (size_t)arow*F1 + 8*hi;
  const short* bph = w2h + (size_t)lo*F1 + 8*hi;
  const short* bpl = w2l + (size_t)lo*F1 + 8*hi;
  for(int k0=0; k0<F1; k0+=32){
    bf16x8 ah = *(const bf16x8*)(xp + k0);
    #pragma unroll
    for(int tt=0;tt<3;tt++){
      bf16x8 bh = *(const bf16x8*)(bph + (size_t)tt*16*F1 + k0);
      bf16x8 bl = *(const bf16x8*)(bpl + (size_t)tt*16*F1 + k0);
      acc[tt] = __builtin_amdgcn_mfma_f32_16x16x32_bf16(ah, bh, acc[tt], 0, 0, 0);
      acc[tt] = __builtin_amdgcn_mfma_f32_16x16x32_bf16(ah, bl, acc[tt], 0, 0, 0);
    }
  }
  float ps[4] = {0.f,0.f,0.f,0.f}, pd[4] = {0.f,0.f,0.f,0.f};
  #pragma unroll
  for(int tt=0;tt<3;tt++){
    int col = tt*16 + lo;
    float sv = (col < NC) ? as2[col]*LOG2E : 0.f;
    float dv = (col < NC) ? ad2[col]*LOG2E : 0.f;
    #pragma unroll
    for(int r=0;r<4;r++){
      int row = rowbase + hi*4 + r;
      if(row < NN && col < NC) h2p[(size_t)row*NC + col] = f2bf(acc[tt][r]);
      ps[r] += acc[tt][r]*sv; pd[r] += acc[tt][r]*dv;
    }
  }
  #pragma unroll
  for(int off=1; off<16; off<<=1){
    #pragma unroll
    for(int r=0;r<4;r++){ ps[r] += __shfl_xor(ps[r], off, 64); pd[r] += __shfl_xor(pd[r], off, 64); }
  }
  if(lo == 0){
    #pragma unroll
    for(int r=0;r<4;r++){
      int row = rowbase + hi*4 + r;
      if(row < NN){ aS2[row] = ps[r]; aD2[row] = pd[r]; }
    }
  }
}

// ---- layer-2 aggregation -> output (f32), bf16 h2p gather
__global__ __launch_bounds__(256) void k_agg2(const u16* __restrict__ h2p,
  const float* __restrict__ aS2, const float* __restrict__ aD2,
  const int* __restrict__ rowptr, const int* __restrict__ rend, const int* __restrict__ adj,
  const float* __restrict__ b2, float* __restrict__ out){
  __shared__ float lw[4][CHUNK];
  __shared__ int   lsrc[4][CHUNK];
  int w = threadIdx.x >> 6, lane = threadIdx.x & 63;
  int node = blockIdx.x*4 + w;
  int beg = rowptr[node], end = rend[node];
  float adv = aD2[node];
  float den = 0.f, acc = 0.f;
  int total = end - beg + 1;
  for(int c0=0; c0<total; c0+=CHUNK){
    int n = min(CHUNK, total - c0);
    for(int i=lane; i<n; i+=64){
      int e = beg + c0 + i;
      int src = (e < end) ? adj[e] : node;
      float ev = aS2[src] + adv; ev = ev>0.f?ev:SLOPE*ev;
      float wg = exp2f(fminf(ev,110.f));
      lsrc[w][i] = src;
      lw[w][i] = wg;
      den += wg;
    }
    asm volatile("s_waitcnt lgkmcnt(0)" ::: "memory");
    #pragma unroll 4
    for(int i=0;i<n;i++){
      int s = lsrc[w][i];
      float wg = lw[w][i];
      if(lane < NC) acc += wg * us2f(h2p[(size_t)s*NC + lane]);
    }
  }
  #pragma unroll
  for(int off=1; off<64; off<<=1) den += __shfl_xor(den, off, 64);
  if(lane < NC) out[(size_t)node*NC + lane] = acc/(den + 1e-16f) + b2[lane];
}

extern "C" void kernel_launch(void* const* d_in, const int* in_sizes, int n_in,
                              void* d_out, int out_size, void* d_ws, size_t ws_size,
                              hipStream_t stream){
  (void)in_sizes; (void)n_in; (void)out_size; (void)ws_size;
  const float* x   = (const float*)d_in[0];
  const int*   ei  = (const int*)d_in[1];
  const float* W1  = (const float*)d_in[2];
  const float* as1 = (const float*)d_in[3];
  const float* ad1 = (const float*)d_in[4];
  const float* b1  = (const float*)d_in[5];
  const float* g1  = (const float*)d_in[6];
  const float* be1 = (const float*)d_in[7];
  const float* mn1 = (const float*)d_in[8];
  const float* vr1 = (const float*)d_in[9];
  const float* W2  = (const float*)d_in[10];
  const float* as2 = (const float*)d_in[11];
  const float* ad2 = (const float*)d_in[12];
  const float* b2  = (const float*)d_in[13];

  char* ws = (char*)d_ws;
  u16*  h1b    = (u16*) (ws + 0);             // 25,600,000 (bf16 h1)
  u16*  h2b    = (u16*) (ws + 25600000);      // 25,600,000 (bf16 h2)
  // w1h/w1l alias h2p (dead before k_gemm2 writes h2p)
  u16*  h2p    = (u16*) (ws + 76800000);      //  4,000,000 (bf16)
  u16*  w1h    = (u16*) (ws + 76800000);      //    131,072
  u16*  w1l    = (u16*) (ws + 76931072);      //    131,072
  float* aS1   = (float*)(ws + 84800000);     //    800,000
  float* aD1   = (float*)(ws + 85600000);     //    800,000
  float* aS2   = (float*)(ws + 86400000);     //    200,000
  float* aD2   = (float*)(ws + 86600000);     //    200,000
  int*  rowptr = (int*)  (ws + 86800000);     //    200,000
  int*  rend   = (int*)  (ws + 87000016);     //    200,000
  int*  adj    = (int*)  (ws + 87200016);     //  7,056,000 (98*18000*4, fixed windows)
  u32*  bin    = (u32*)  (ws + 94300000);     //  7,056,000
  int*  cnt    = (int*)  (ws + 101356000);    //        392
  u16*  w2h    = (u16*)  (ws + 101357000);    //     24,576
  u16*  w2l    = (u16*)  (ws + 101382000);    //     24,576

  hipMemsetAsync(cnt, 0, NB2*sizeof(int), stream);
  k_prep  <<<NBIN+256+48, 256, 0, stream>>>(ei, cnt, bin, W1, w1h, w1l, W2, w2h, w2l);
  k_g1h   <<<NB2 + NG1, 256, 0, stream>>>(x, (const short*)w1h, (const short*)w1l,
                                          as1, ad1, h1b, aS1, aD1,
                                          cnt, bin, rowptr, rend, adj);
  k_agg1  <<<NN/4, 256, 0, stream>>>(h1b, aS1, aD1, rowptr, rend, adj, b1, g1, be1, mn1, vr1, h2b);
  k_gemm2 <<<(NN+63)/64, 256, 0, stream>>>((const short*)h2b, (const short*)w2h, (const short*)w2l,
                                           as2, ad2, h2p, aS2, aD2);
  k_agg2  <<<NN/4, 256, 0, stream>>>(h2p, aS2, aD2, rowptr, rend, adj, b2, (float*)d_out);
}

// Round 21
// 284.326 us; speedup vs baseline: 1.4413x; 1.0933x over previous
//
#include <hip/hip_runtime.h>
#include <hip/hip_bf16.h>

#define NN 50000
#define FIN 256
#define F1 256      // HEADS*HID
#define HEADS 4
#define HID 64
#define NC 40
#define NE 1600000
#define SLOPE 0.2f
#define LOG2E 1.44269504f
#define CHUNK 128
#define NB2 98      // coarse dst buckets (512 nodes each)
#define BSH 9
#define BCAP2 18000 // per-bucket capacity (mean 16327, +13 sigma)
#define TILE 4096   // edges per bin block
#define NBIN 391    // bin blocks (391*4096 >= NE)
#define NG1 782     // gemm1 blocks: 391 row-tiles x 2 col-tiles
#define G1PAD 40    // LDS row pitch in u16 (32 + 8 pad; 80B, 16B-aligned, 2-way max)

typedef unsigned int u32;
typedef unsigned short u16;
typedef unsigned char u8;
typedef __attribute__((ext_vector_type(8))) short bf16x8;
typedef __attribute__((ext_vector_type(4))) float f32x4;

__device__ __forceinline__ float us2f(u32 u){ u32 b = u << 16; return __uint_as_float(b); }
__device__ __forceinline__ u16 f2bf(float f){
  u32 b = __float_as_uint(f);
  u32 r = (b + 0x7fffu + ((b >> 16) & 1u)) >> 16;
  return (u16)r;
}

// ---- fused prep: edge binning (blocks 0..390) + W1 transpose/split (391..646)
//      + W2 transpose/split (647..694)
__global__ __launch_bounds__(256) void k_prep(const int* __restrict__ ei,
      int* __restrict__ cnt, u32* __restrict__ bin,
      const float* __restrict__ W1, u16* __restrict__ w1h, u16* __restrict__ w1l,
      const float* __restrict__ W2, u16* __restrict__ w2h, u16* __restrict__ w2l){
  __shared__ int hcnt[NB2], hoff[NB2], gbase[NB2], hcur[NB2];
  __shared__ u32 staged[TILE];
  __shared__ u8  sbk[TILE];
  __shared__ int ci;
  int bid = blockIdx.x, tid = threadIdx.x;
  if(bid < NBIN){
    int e0 = bid * TILE;
    int nn = min(TILE, NE - e0);
    if(tid==0) ci = 0;
    for(int b=tid;b<NB2;b+=256) hcnt[b] = 0;
    __syncthreads();
    if(ei[2*(e0+tid)+1] != 0) atomicAdd(&ci, 1);   // int64: odd words all 0
    __syncthreads();
    int i64 = (ci == 0);
    u32 val[TILE/256]; int bk[TILE/256];
    #pragma unroll
    for(int j=0;j<TILE/256;j++){
      int t = tid + j*256;
      if(t < nn){
        int i = e0 + t;
        int src = i64 ? ei[2*i] : ei[i];
        int dst = i64 ? ei[2*(NE+i)] : ei[NE+i];
        bk[j] = dst >> BSH;
        val[j] = (u32)src | ((u32)(dst & 511) << 16);
        atomicAdd(&hcnt[bk[j]], 1);
      } else bk[j] = -1;
    }
    __syncthreads();
    if(tid == 0){
      int run = 0;
      for(int b=0;b<NB2;b++){ hoff[b] = run; hcur[b] = run; run += hcnt[b]; }
    }
    __syncthreads();
    if(tid < NB2 && hcnt[tid] > 0) gbase[tid] = atomicAdd(&cnt[tid], hcnt[tid]);
    __syncthreads();
    #pragma unroll
    for(int j=0;j<TILE/256;j++){
      if(bk[j] >= 0){
        int pos = atomicAdd(&hcur[bk[j]], 1);
        staged[pos] = val[j];
        sbk[pos] = (u8)bk[j];
      }
    }
    __syncthreads();
    for(int s=tid; s<nn; s+=256){
      int b = sbk[s];
      int local = gbase[b] + (s - hoff[b]);
      if(local < BCAP2) bin[(size_t)b*BCAP2 + local] = staged[s];
    }
  } else if(bid < NBIN+256){
    int id = (bid-NBIN)*256 + tid;               // 65536 total
    int n = id & 255, k = id >> 8;
    float v = W1[k*F1 + n];
    u16 h = f2bf(v);
    w1h[n*FIN + k] = h;
    w1l[n*FIN + k] = f2bf(v - us2f(h));
  } else {
    int id = (bid-(NBIN+256))*256 + tid;         // 12288 total: col 0..47, k 0..255
    int col = id >> 8, k = id & 255;
    float v = (col < NC) ? W2[k*NC + col] : 0.f;
    u16 h = f2bf(v);
    w2h[col*F1 + k] = h;
    w2l[col*F1 + k] = f2bf(v - us2f(h));
  }
}

// ---- fused k_g1h: histogram/scan/scatter FIRST (blocks 0..97)
//      + GEMM1 (blocks 98..879; 128x128 tile, LDS-staged, on-the-fly x split)
__global__ __launch_bounds__(256) void k_g1h(const float* __restrict__ x,
                                             const short* __restrict__ wh, const short* __restrict__ wl,
                                             const float* __restrict__ as1, const float* __restrict__ ad1,
                                             u16* __restrict__ h1b,
                                             float* __restrict__ aS, float* __restrict__ aD,
                                             const int* __restrict__ cnt, const u32* __restrict__ bin,
                                             int* __restrict__ rowptr, int* __restrict__ rend,
                                             int* __restrict__ adj){
  __shared__ char smem[4*128*G1PAD*2];   // 40,960 B
  int tid = threadIdx.x;
  if(blockIdx.x < NB2){
    int* dl = (int*)smem; int* s1 = dl + 512; int* s2 = s1 + 512;
    int b = blockIdx.x;
    int base = b * BCAP2;
    for(int i=tid;i<512;i+=256) dl[i] = 0;
    __syncthreads();
    int n = min(cnt[b], BCAP2);
    const u32* bp = bin + (size_t)b*BCAP2;
    for(int i=tid;i<n;i+=256) atomicAdd(&dl[(bp[i]>>16)&511], 1);
    __syncthreads();
    for(int i=tid;i<512;i+=256) s1[i] = dl[i];
    __syncthreads();
    int* src = s1; int* dst = s2;
    for(int off=1; off<512; off<<=1){
      for(int i=tid;i<512;i+=256) dst[i] = src[i] + (i>=off ? src[i-off] : 0);
      __syncthreads();
      int* t = src; src = dst; dst = t;
    }
    for(int i=tid;i<512;i+=256){
      int d = b*512 + i;
      int excl = src[i] - dl[i];
      if(d < NN){ rowptr[d] = base + excl; rend[d] = base + src[i]; }
      dl[i] = base + excl;
    }
    __syncthreads();
    for(int i=tid;i<n;i+=256){
      u32 v = bp[i];
      int p = atomicAdd(&dl[(v>>16)&511], 1);
      adj[p] = (int)(v & 0xffffu);
    }
    return;
  }
  // ---- GEMM1: block = 128 rows x 128 cols; wave = 64x64 quadrant
  u16* Ah = (u16*)smem;
  u16* Al = Ah + 128*G1PAD;
  u16* Bh = Al + 128*G1PAD;
  u16* Bl = Bh + 128*G1PAD;
  int gb = blockIdx.x - NB2;
  int w = tid >> 6, lane = tid & 63;
  int lo = lane & 15, hi = lane >> 4;
  int bidm = gb >> 1, bidn = gb & 1;
  int rowbase = bidm*128, colbase = bidn*128;
  int wr = w >> 1, wc = w & 1;
  int r0 = tid >> 2, ch = tid & 3;
  int arow0 = rowbase + r0;      if(arow0 >= NN) arow0 = NN-1;
  int arow1 = rowbase + r0 + 64; if(arow1 >= NN) arow1 = NN-1;
  const float* pX0 = x + (size_t)arow0*FIN + ch*8;
  const float* pX1 = x + (size_t)arow1*FIN + ch*8;
  const short* pB0h = wh + (size_t)(colbase + r0)*FIN + ch*8;
  const short* pB1h = wh + (size_t)(colbase + r0 + 64)*FIN + ch*8;
  const short* pB0l = wl + (size_t)(colbase + r0)*FIN + ch*8;
  const short* pB1l = wl + (size_t)(colbase + r0 + 64)*FIN + ch*8;
  int so0 = r0*G1PAD + ch*8, so1 = (r0+64)*G1PAD + ch*8;
  f32x4 acc[4][4];                       // [rg][tt]
  #pragma unroll
  for(int rg=0;rg<4;rg++)
    #pragma unroll
    for(int tt=0;tt<4;tt++) acc[rg][tt] = (f32x4){0.f,0.f,0.f,0.f};
  for(int k0=0; k0<FIN; k0+=32){
    float4 xa0 = *(const float4*)(pX0 + k0);
    float4 xa1 = *(const float4*)(pX0 + k0 + 4);
    float4 xb0 = *(const float4*)(pX1 + k0);
    float4 xb1 = *(const float4*)(pX1 + k0 + 4);
    bf16x8 vb0 = *(const bf16x8*)(pB0h + k0);
    bf16x8 vb1 = *(const bf16x8*)(pB1h + k0);
    bf16x8 vb2 = *(const bf16x8*)(pB0l + k0);
    bf16x8 vb3 = *(const bf16x8*)(pB1l + k0);
    float v0[8] = {xa0.x,xa0.y,xa0.z,xa0.w,xa1.x,xa1.y,xa1.z,xa1.w};
    float v1[8] = {xb0.x,xb0.y,xb0.z,xb0.w,xb1.x,xb1.y,xb1.z,xb1.w};
    bf16x8 a0h, a0l, a1h, a1l;
    #pragma unroll
    for(int j=0;j<8;j++){
      u32 u = __float_as_uint(v0[j]);
      a0h[j] = (short)(u >> 16);
      float hf = __uint_as_float(u & 0xffff0000u);
      a0l[j] = (short)(__float_as_uint(v0[j] - hf) >> 16);
      u32 u2 = __float_as_uint(v1[j]);
      a1h[j] = (short)(u2 >> 16);
      float hf2 = __uint_as_float(u2 & 0xffff0000u);
      a1l[j] = (short)(__float_as_uint(v1[j] - hf2) >> 16);
    }
    __syncthreads();                      // previous iter's reads complete
    *(bf16x8*)&Ah[so0] = a0h; *(bf16x8*)&Ah[so1] = a1h;
    *(bf16x8*)&Al[so0] = a0l; *(bf16x8*)&Al[so1] = a1l;
    *(bf16x8*)&Bh[so0] = vb0; *(bf16x8*)&Bh[so1] = vb1;
    *(bf16x8*)&Bl[so0] = vb2; *(bf16x8*)&Bl[so1] = vb3;
    __syncthreads();                      // staging visible
    bf16x8 ah[4], al[4];
    #pragma unroll
    for(int rg=0;rg<4;rg++){
      int ar = wr*64 + rg*16 + lo;
      ah[rg] = *(const bf16x8*)&Ah[ar*G1PAD + hi*8];
      al[rg] = *(const bf16x8*)&Al[ar*G1PAD + hi*8];
    }
    #pragma unroll
    for(int tt=0;tt<4;tt++){
      int bc = wc*64 + tt*16 + lo;
      bf16x8 bh = *(const bf16x8*)&Bh[bc*G1PAD + hi*8];
      bf16x8 bl = *(const bf16x8*)&Bl[bc*G1PAD + hi*8];
      #pragma unroll
      for(int rg=0;rg<4;rg++){
        acc[rg][tt] = __builtin_amdgcn_mfma_f32_16x16x32_bf16(ah[rg], bh, acc[rg][tt], 0, 0, 0);
        acc[rg][tt] = __builtin_amdgcn_mfma_f32_16x16x32_bf16(al[rg], bh, acc[rg][tt], 0, 0, 0);
        acc[rg][tt] = __builtin_amdgcn_mfma_f32_16x16x32_bf16(ah[rg], bl, acc[rg][tt], 0, 0, 0);
      }
    }
  }
  #pragma unroll
  for(int rg=0;rg<4;rg++){
    #pragma unroll
    for(int tt=0;tt<4;tt++){
      #pragma unroll
      for(int r=0;r<4;r++){
        int row = rowbase + wr*64 + rg*16 + hi*4 + r;
        if(row < NN) h1b[(size_t)row*F1 + colbase + wc*64 + tt*16 + lo] = f2bf(acc[rg][tt][r]);
      }
    }
  }
  int head = bidn*2 + wc;
  float ps[4][4], pd[4][4];              // [rg][r]
  #pragma unroll
  for(int rg=0;rg<4;rg++)
    #pragma unroll
    for(int r=0;r<4;r++){ ps[rg][r]=0.f; pd[rg][r]=0.f; }
  #pragma unroll
  for(int tt=0;tt<4;tt++){
    int col = colbase + wc*64 + tt*16 + lo;
    float sv = as1[col]*LOG2E, dv = ad1[col]*LOG2E;
    #pragma unroll
    for(int rg=0;rg<4;rg++)
      #pragma unroll
      for(int r=0;r<4;r++){ ps[rg][r] += acc[rg][tt][r]*sv; pd[rg][r] += acc[rg][tt][r]*dv; }
  }
  #pragma unroll
  for(int off=1; off<16; off<<=1){
    #pragma unroll
    for(int rg=0;rg<4;rg++)
      #pragma unroll
      for(int r=0;r<4;r++){
        ps[rg][r] += __shfl_xor(ps[rg][r], off, 64);
        pd[rg][r] += __shfl_xor(pd[rg][r], off, 64);
      }
  }
  if(lo == 0){
    #pragma unroll
    for(int rg=0;rg<4;rg++)
      #pragma unroll
      for(int r=0;r<4;r++){
        int row = rowbase + wr*64 + rg*16 + hi*4 + r;
        if(row < NN){ aS[row*HEADS+head] = ps[rg][r]; aD[row*HEADS+head] = pd[rg][r]; }
      }
  }
}

// ---- layer-1 aggregation + bias + BN + ELU -> h2 (bf16), one wave per node.
__global__ __launch_bounds__(256) void k_agg1(const u16* __restrict__ h1b,
  const float* __restrict__ aS, const float* __restrict__ aD,
  const int* __restrict__ rowptr, const int* __restrict__ rend, const int* __restrict__ adj,
  const float* __restrict__ b1, const float* __restrict__ g1, const float* __restrict__ be1,
  const float* __restrict__ mn1, const float* __restrict__ vr1,
  u16* __restrict__ h2b){
  __shared__ float lw[4][CHUNK*4];   // [wave][i*4+head]
  __shared__ int   lsrc[4][CHUNK];
  int w = threadIdx.x >> 6, lane = threadIdx.x & 63;
  int node = blockIdx.x*4 + w;
  int g = lane >> 5, li = lane & 31;
  int hb = li >> 3;                  // head of this lane's 8-channel block
  int beg = rowptr[node], end = rend[node];
  float4 ad4 = *(const float4*)&aD[node*HEADS];
  float den[4] = {0.f,0.f,0.f,0.f};
  float acc[8] = {0.f,0.f,0.f,0.f,0.f,0.f,0.f,0.f};
  int total = end - beg + 1;                  // + self loop
  for(int c0=0; c0<total; c0+=CHUNK){
    int n = min(CHUNK, total - c0);
    for(int i=lane; i<n; i+=64){
      int e = beg + c0 + i;
      int src = (e < end) ? adj[e] : node;
      float4 s4 = *(const float4*)&aS[src*HEADS];
      float w0 = s4.x + ad4.x; w0 = w0>0.f?w0:SLOPE*w0; w0 = exp2f(fminf(w0,110.f));
      float w1 = s4.y + ad4.y; w1 = w1>0.f?w1:SLOPE*w1; w1 = exp2f(fminf(w1,110.f));
      float w2 = s4.z + ad4.z; w2 = w2>0.f?w2:SLOPE*w2; w2 = exp2f(fminf(w2,110.f));
      float w3 = s4.w + ad4.w; w3 = w3>0.f?w3:SLOPE*w3; w3 = exp2f(fminf(w3,110.f));
      lsrc[w][i] = src;
      *(float4*)&lw[w][i*4] = make_float4(w0,w1,w2,w3);
      den[0]+=w0; den[1]+=w1; den[2]+=w2; den[3]+=w3;
    }
    asm volatile("s_waitcnt lgkmcnt(0)" ::: "memory");
    #pragma unroll 2
    for(int i=0; i<n; i+=2){
      int e = i + g;
      bool ok = e < n;
      int src = ok ? lsrc[w][e] : node;
      float wg = ok ? lw[w][e*4 + hb] : 0.f;
      uint4 pv = *(const uint4*)&h1b[(size_t)src*F1 + li*8];
      acc[0] += wg*__uint_as_float(pv.x << 16);  acc[1] += wg*__uint_as_float(pv.x & 0xffff0000u);
      acc[2] += wg*__uint_as_float(pv.y << 16);  acc[3] += wg*__uint_as_float(pv.y & 0xffff0000u);
      acc[4] += wg*__uint_as_float(pv.z << 16);  acc[5] += wg*__uint_as_float(pv.z & 0xffff0000u);
      acc[6] += wg*__uint_as_float(pv.w << 16);  acc[7] += wg*__uint_as_float(pv.w & 0xffff0000u);
    }
  }
  #pragma unroll
  for(int off=1; off<64; off<<=1){
    #pragma unroll
    for(int q=0;q<4;q++) den[q] += __shfl_xor(den[q], off, 64);
  }
  #pragma unroll
  for(int k=0;k<8;k++) acc[k] += __shfl_xor(acc[k], 32, 64);
  if(lane < 32){
    float dsel = hb==0 ? den[0] : (hb==1 ? den[1] : (hb==2 ? den[2] : den[3]));
    float inv = 1.f/(dsel + 1e-16f);
    int c = li*8;
    u16 o[8];
    #pragma unroll
    for(int j=0;j<8;j++){
      float v = acc[j]*inv + b1[c+j];
      v = (v - mn1[c+j]) * rsqrtf(vr1[c+j] + 1e-5f) * g1[c+j] + be1[c+j];
      v = v > 0.f ? v : (__expf(v) - 1.f);      // ELU
      o[j] = f2bf(v);
    }
    uint4 pk;
    pk.x = (u32)o[0] | ((u32)o[1] << 16);
    pk.y = (u32)o[2] | ((u32)o[3] << 16);
    pk.z = (u32)o[4] | ((u32)o[5] << 16);
    pk.w = (u32)o[6] | ((u32)o[7] << 16);
    *(uint4*)&h2b[(size_t)node*F1 + c] = pk;
  }
}

// ---- GEMM2 (MFMA bf16x2 — h2 is bf16) + fused attention dots layer 2.
__global__ __launch_bounds__(256) void k_gemm2(const short* __restrict__ h2b,
    const short* __restrict__ w2h, const short* __restrict__ w2l,
    const float* __restrict__ as2, const float* __restrict__ ad2,
    u16* __restrict__ h2p, float* __restrict__ aS2, float* __restrict__ aD2){
  int w = threadIdx.x >> 6, lane = threadIdx.x & 63;
  int lo = lane & 15, hi = lane >> 4;
  int rowbase = blockIdx.x*64 + w*16;
  int arow = rowbase + lo; if(arow >= NN) arow = NN-1;
  f32x4 acc[3];
  #pragma unroll
  for(int tt=0;tt<3;tt++) acc[tt] = (f32x4){0.f,0.f,0.f,0.f};
  const short* xp = h2b + (size_t)arow*F1 + 8*hi;
  const short* bph = w2h + (size_t)lo*F1 + 8*hi;
  const short* bpl = w2l + (size_t)lo*F1 + 8*hi;
  for(int k0=0; k0<F1; k0+=32){
    bf16x8 ah = *(const bf16x8*)(xp + k0);
    #pragma unroll
    for(int tt=0;tt<3;tt++){
      bf16x8 bh = *(const bf16x8*)(bph + (size_t)tt*16*F1 + k0);
      bf16x8 bl = *(const bf16x8*)(bpl + (size_t)tt*16*F1 + k0);
      acc[tt] = __builtin_amdgcn_mfma_f32_16x16x32_bf16(ah, bh, acc[tt], 0, 0, 0);
      acc[tt] = __builtin_amdgcn_mfma_f32_16x16x32_bf16(ah, bl, acc[tt], 0, 0, 0);
    }
  }
  float ps[4] = {0.f,0.f,0.f,0.f}, pd[4] = {0.f,0.f,0.f,0.f};
  #pragma unroll
  for(int tt=0;tt<3;tt++){
    int col = tt*16 + lo;
    float sv = (col < NC) ? as2[col]*LOG2E : 0.f;
    float dv = (col < NC) ? ad2[col]*LOG2E : 0.f;
    #pragma unroll
    for(int r=0;r<4;r++){
      int row = rowbase + hi*4 + r;
      if(row < NN && col < NC) h2p[(size_t)row*NC + col] = f2bf(acc[tt][r]);
      ps[r] += acc[tt][r]*sv; pd[r] += acc[tt][r]*dv;
    }
  }
  #pragma unroll
  for(int off=1; off<16; off<<=1){
    #pragma unroll
    for(int r=0;r<4;r++){ ps[r] += __shfl_xor(ps[r], off, 64); pd[r] += __shfl_xor(pd[r], off, 64); }
  }
  if(lo == 0){
    #pragma unroll
    for(int r=0;r<4;r++){
      int row = rowbase + hi*4 + r;
      if(row < NN){ aS2[row] = ps[r]; aD2[row] = pd[r]; }
    }
  }
}

// ---- layer-2 aggregation -> output (f32), 2 edges/iter (32-lane groups, 20 active x u32)
__global__ __launch_bounds__(256) void k_agg2(const u16* __restrict__ h2p,
  const float* __restrict__ aS2, const float* __restrict__ aD2,
  const int* __restrict__ rowptr, const int* __restrict__ rend, const int* __restrict__ adj,
  const float* __restrict__ b2, float* __restrict__ out){
  __shared__ float lw[4][CHUNK];
  __shared__ int   lsrc[4][CHUNK];
  int w = threadIdx.x >> 6, lane = threadIdx.x & 63;
  int node = blockIdx.x*4 + w;
  int g = lane >> 5, li = lane & 31;
  int beg = rowptr[node], end = rend[node];
  float adv = aD2[node];
  float den = 0.f, a0 = 0.f, a1 = 0.f;
  int total = end - beg + 1;
  for(int c0=0; c0<total; c0+=CHUNK){
    int n = min(CHUNK, total - c0);
    for(int i=lane; i<n; i+=64){
      int e = beg + c0 + i;
      int src = (e < end) ? adj[e] : node;
      float ev = aS2[src] + adv; ev = ev>0.f?ev:SLOPE*ev;
      float wg = exp2f(fminf(ev,110.f));
      lsrc[w][i] = src;
      lw[w][i] = wg;
      den += wg;
    }
    asm volatile("s_waitcnt lgkmcnt(0)" ::: "memory");
    #pragma unroll 2
    for(int i=0; i<n; i+=2){
      int e = i + g;
      bool ok = e < n;
      int s = ok ? lsrc[w][e] : node;
      float wg = ok ? lw[w][e] : 0.f;
      if(li < 20){
        u32 pv = *(const u32*)&h2p[(size_t)s*NC + li*2];
        a0 += wg*__uint_as_float(pv << 16);
        a1 += wg*__uint_as_float(pv & 0xffff0000u);
      }
    }
  }
  #pragma unroll
  for(int off=1; off<64; off<<=1) den += __shfl_xor(den, off, 64);
  a0 += __shfl_xor(a0, 32, 64);
  a1 += __shfl_xor(a1, 32, 64);
  if(lane < 20){
    float inv = 1.f/(den + 1e-16f);
    int c = lane*2;
    float o0 = a0*inv + b2[c];
    float o1 = a1*inv + b2[c+1];
    *(float2*)&out[(size_t)node*NC + c] = make_float2(o0, o1);
  }
}

extern "C" void kernel_launch(void* const* d_in, const int* in_sizes, int n_in,
                              void* d_out, int out_size, void* d_ws, size_t ws_size,
                              hipStream_t stream){
  (void)in_sizes; (void)n_in; (void)out_size; (void)ws_size;
  const float* x   = (const float*)d_in[0];
  const int*   ei  = (const int*)d_in[1];
  const float* W1  = (const float*)d_in[2];
  const float* as1 = (const float*)d_in[3];
  const float* ad1 = (const float*)d_in[4];
  const float* b1  = (const float*)d_in[5];
  const float* g1  = (const float*)d_in[6];
  const float* be1 = (const float*)d_in[7];
  const float* mn1 = (const float*)d_in[8];
  const float* vr1 = (const float*)d_in[9];
  const float* W2  = (const float*)d_in[10];
  const float* as2 = (const float*)d_in[11];
  const float* ad2 = (const float*)d_in[12];
  const float* b2  = (const float*)d_in[13];

  char* ws = (char*)d_ws;
  u16*  h1b    = (u16*) (ws + 0);             // 25,600,000 (bf16 h1)
  u16*  h2b    = (u16*) (ws + 25600000);      // 25,600,000 (bf16 h2)
  // w1h/w1l alias h2p (dead before k_gemm2 writes h2p)
  u16*  h2p    = (u16*) (ws + 76800000);      //  4,000,000 (bf16)
  u16*  w1h    = (u16*) (ws + 76800000);      //    131,072
  u16*  w1l    = (u16*) (ws + 76931072);      //    131,072
  float* aS1   = (float*)(ws + 84800000);     //    800,000
  float* aD1   = (float*)(ws + 85600000);     //    800,000
  float* aS2   = (float*)(ws + 86400000);     //    200,000
  float* aD2   = (float*)(ws + 86600000);     //    200,000
  int*  rowptr = (int*)  (ws + 86800000);     //    200,000
  int*  rend   = (int*)  (ws + 87000016);     //    200,000
  int*  adj    = (int*)  (ws + 87200016);     //  7,056,000 (98*18000*4, fixed windows)
  u32*  bin    = (u32*)  (ws + 94300000);     //  7,056,000
  int*  cnt    = (int*)  (ws + 101356000);    //        392
  u16*  w2h    = (u16*)  (ws + 101357000);    //     24,576
  u16*  w2l    = (u16*)  (ws + 101382000);    //     24,576

  hipMemsetAsync(cnt, 0, NB2*sizeof(int), stream);
  k_prep  <<<NBIN+256+48, 256, 0, stream>>>(ei, cnt, bin, W1, w1h, w1l, W2, w2h, w2l);
  k_g1h   <<<NB2 + NG1, 256, 0, stream>>>(x, (const short*)w1h, (const short*)w1l,
                                          as1, ad1, h1b, aS1, aD1,
                                          cnt, bin, rowptr, rend, adj);
  k_agg1  <<<NN/4, 256, 0, stream>>>(h1b, aS1, aD1, rowptr, rend, adj, b1, g1, be1, mn1, vr1, h2b);
  k_gemm2 <<<(NN+63)/64, 256, 0, stream>>>((const short*)h2b, (const short*)w2h, (const short*)w2l,
                                           as2, ad2, h2p, aS2, aD2);
  k_agg2  <<<NN/4, 256, 0, stream>>>(h2p, aS2, aD2, rowptr, rend, adj, b2, (float*)d_out);
}